// Round 8
// baseline (1324.985 us; speedup 1.0000x reference)
//
#include <hip/hip_runtime.h>
#include <math.h>

typedef float f32x4 __attribute__((ext_vector_type(4)));
typedef short s16x8 __attribute__((ext_vector_type(8)));
typedef unsigned short u16x4 __attribute__((ext_vector_type(4)));

#define HW 4096
#define CCH 512
#define NK 64

// ---- ws layout (float offsets, R6-compatible) ----
#define OFF_H1   0
#define OFF_H2   8388608
#define OFF_X1B  0            // bf16 x1 NHWC, bytes [0, 67,108,864) — overlays dead h1+h2
#define OFF_YB   16777216     // bf16 y NCHW, bytes [67,108,864, 134,217,728)
#define OFF_A    33554432ULL
#define OFF_PE   37748736ULL
#define OFF_ASUM 39845888ULL
#define OFF_GAM  39846912ULL
#define OFF_MISC 39855104ULL
#define OFF_W1F  39859200ULL
#define OFF_W2F  39924736ULL
#define OFF_W3F  40072192ULL
#define OFF_WRF  40137728ULL
#define OFF_WLF  40399872ULL   // bf16 wl (262144 shorts)
// end = 40662016 floats = 162.6 MB (same as R6)

#define MS_S1 0
#define MS_T1 128
#define MS_S2 256
#define MS_T2 384
#define MS_S3 512
#define MS_T3 1024
#define MS_SR 1536
#define MS_TR 2048
#define MS_SL 2560
#define MS_TL 3072
#define MS_SE 3584
#define MS_TE 3648
#define MS_CSQ 3712

__device__ __forceinline__ float b2f(unsigned short u) {
  unsigned int x = ((unsigned int)u) << 16;
  return __builtin_bit_cast(float, x);
}
__device__ __forceinline__ unsigned short f2b(float f) {
  unsigned int i = __builtin_bit_cast(unsigned int, f);
  i += 0x7fffu + ((i >> 16) & 1u);
  return (unsigned short)(i >> 16);
}

// ---------------- prep: fold BN params, c_sq ----------------
__global__ void prep_kernel(
    const float* __restrict__ g1, const float* __restrict__ b1, const float* __restrict__ m1, const float* __restrict__ v1,
    const float* __restrict__ g2, const float* __restrict__ b2, const float* __restrict__ m2, const float* __restrict__ v2,
    const float* __restrict__ g3, const float* __restrict__ b3, const float* __restrict__ m3, const float* __restrict__ v3,
    const float* __restrict__ gr, const float* __restrict__ br, const float* __restrict__ mr, const float* __restrict__ vr,
    const float* __restrict__ gl, const float* __restrict__ bl, const float* __restrict__ ml, const float* __restrict__ vl,
    const float* __restrict__ ge, const float* __restrict__ be, const float* __restrict__ me, const float* __restrict__ ve,
    const float* __restrict__ cw, float* __restrict__ misc)
{
  const int t = threadIdx.x;
  if (t < 128) {
    float s = g1[t] * rsqrtf(v1[t] + 1e-6f);
    misc[MS_S1 + t] = s; misc[MS_T1 + t] = b1[t] - m1[t] * s;
    s = g2[t] * rsqrtf(v2[t] + 1e-6f);
    misc[MS_S2 + t] = s; misc[MS_T2 + t] = b2[t] - m2[t] * s;
  }
  for (int c = t; c < 512; c += 256) {
    float s = g3[c] * rsqrtf(v3[c] + 1e-6f);
    misc[MS_S3 + c] = s; misc[MS_T3 + c] = b3[c] - m3[c] * s;
    s = gr[c] * rsqrtf(vr[c] + 1e-6f);
    misc[MS_SR + c] = s; misc[MS_TR + c] = br[c] - mr[c] * s;
    s = gl[c] * rsqrtf(vl[c] + 1e-5f);
    misc[MS_SL + c] = s; misc[MS_TL + c] = bl[c] - ml[c] * s;
  }
  if (t < 64) {
    float s = ge[t] * rsqrtf(ve[t] + 1e-5f);
    misc[MS_SE + t] = s; misc[MS_TE + t] = be[t] - me[t] * s;
    float acc = 0.f;
    for (int c = 0; c < 512; ++c) { float v = cw[t * 512 + c]; acc += v * v; }
    misc[MS_CSQ + t] = acc;
  }
}

// ---------------- fold weights (fp32) ----------------
__global__ void fold_kernel(const float* __restrict__ w, const float* __restrict__ s,
                            float* __restrict__ out, int total, int kper)
{
  int i = blockIdx.x * 256 + threadIdx.x;
  if (i < total) out[i] = w[i] * s[i / kper];
}

// ---------------- fold weights -> bf16 ----------------
__global__ void fold_bf16_kernel(const float* __restrict__ w, const float* __restrict__ s,
                                 unsigned short* __restrict__ out, int total, int kper)
{
  int i = blockIdx.x * 256 + threadIdx.x;
  if (i < total) out[i] = f2b(w[i] * s[i / kper]);
}

// ---------------- f32 NCHW (512ch) -> bf16 NHWC (tiled transpose) ----------------
__global__ __launch_bounds__(256) void tr_kernel(const float* __restrict__ x,
                                                 unsigned short* __restrict__ xb)
{
  __shared__ float T[64][65];
  const int b = blockIdx.z, c0 = blockIdx.y * 64, n0 = blockIdx.x * 64;
  const int t = threadIdx.x;
  const int rr = t >> 4, cc = (t & 15) * 4;
#pragma unroll
  for (int rep = 0; rep < 4; ++rep) {
    const int cr = rep * 16 + rr;
    const float4 v = *(const float4*)(x + ((size_t)(b * 512 + c0 + cr)) * 4096 + n0 + cc);
    T[cr][cc + 0] = v.x; T[cr][cc + 1] = v.y; T[cr][cc + 2] = v.z; T[cr][cc + 3] = v.w;
  }
  __syncthreads();
#pragma unroll
  for (int rep = 0; rep < 4; ++rep) {
    const int nr = rep * 16 + rr;
    u16x4 o;
    o[0] = f2b(T[cc + 0][nr]); o[1] = f2b(T[cc + 1][nr]);
    o[2] = f2b(T[cc + 2][nr]); o[3] = f2b(T[cc + 3][nr]);
    *(u16x4*)(xb + ((size_t)(b * 4096 + n0 + nr)) * 512 + c0 + cc) = o;
  }
}

// ---------------- 1x1 conv GEMM fp32 (R1-verified) ----------------
template<bool DUAL, bool RELU_OUT>
__global__ __launch_bounds__(256) void gemm1x1_kernel(
    const float* __restrict__ X1, const float* __restrict__ W1, const float* __restrict__ bias1,
    const float* __restrict__ X2, const float* __restrict__ W2, const float* __restrict__ bias2,
    float* __restrict__ Y, int Cin1, int Cin2, int Cout)
{
  __shared__ __align__(16) float As[8][128];
  __shared__ __align__(16) float Bs[8][128];
  const int tid = threadIdx.x;
  const int b  = blockIdx.z;
  const int n0 = blockIdx.x * 128;
  const int m0 = blockIdx.y * 128;
  const int tr = tid >> 4, tc = tid & 15;
  const int la_m = tid >> 1, la_k = (tid & 1) * 4;
  const int lb_k = tid >> 5, lb_n = (tid & 31) * 4;

  float acc[8][8];
#pragma unroll
  for (int i = 0; i < 8; ++i)
#pragma unroll
    for (int j = 0; j < 8; ++j) acc[i][j] = 0.f;

  const int nphase = DUAL ? 2 : 1;
  for (int phase = 0; phase < nphase; ++phase) {
    const float* __restrict__ X = (phase == 0) ? X1 : X2;
    const float* __restrict__ W = (phase == 0) ? W1 : W2;
    const int K = (phase == 0) ? Cin1 : Cin2;
    const float* __restrict__ Xb = X + (size_t)b * K * HW;

    for (int kt = 0; kt < K; kt += 8) {
      const float4 av = *(const float4*)(W + (size_t)(m0 + la_m) * K + kt + la_k);
      const float4 bv = *(const float4*)(Xb + (size_t)(kt + lb_k) * HW + n0 + lb_n);
      __syncthreads();
      As[la_k + 0][la_m] = av.x;
      As[la_k + 1][la_m] = av.y;
      As[la_k + 2][la_m] = av.z;
      As[la_k + 3][la_m] = av.w;
      *(float4*)&Bs[lb_k][lb_n] = bv;
      __syncthreads();
#pragma unroll
      for (int kk = 0; kk < 8; ++kk) {
        const float4 a0 = *(const float4*)&As[kk][tr * 4];
        const float4 a1 = *(const float4*)&As[kk][64 + tr * 4];
        const float4 b0 = *(const float4*)&Bs[kk][tc * 4];
        const float4 b1 = *(const float4*)&Bs[kk][64 + tc * 4];
        const float am[8] = {a0.x, a0.y, a0.z, a0.w, a1.x, a1.y, a1.z, a1.w};
        const float bn_[8] = {b0.x, b0.y, b0.z, b0.w, b1.x, b1.y, b1.z, b1.w};
#pragma unroll
        for (int i = 0; i < 8; ++i)
#pragma unroll
          for (int j = 0; j < 8; ++j) acc[i][j] += am[i] * bn_[j];
      }
    }
    if (DUAL && phase == 0) {
#pragma unroll
      for (int i = 0; i < 8; ++i) {
        const int m = (i < 4) ? (tr * 4 + i) : (64 + tr * 4 + i - 4);
        const float bb = bias1[m0 + m];
#pragma unroll
        for (int j = 0; j < 8; ++j) acc[i][j] = fmaxf(acc[i][j] + bb, 0.f);
      }
    }
  }

  float* __restrict__ Yb = Y + (size_t)b * Cout * HW;
  const float* __restrict__ bias_f = DUAL ? bias2 : bias1;
#pragma unroll
  for (int i = 0; i < 8; ++i) {
    const int m = (i < 4) ? (tr * 4 + i) : (64 + tr * 4 + i - 4);
    const float bb = bias_f[m0 + m];
    float4 v0, v1;
    v0.x = acc[i][0] + bb; v0.y = acc[i][1] + bb; v0.z = acc[i][2] + bb; v0.w = acc[i][3] + bb;
    v1.x = acc[i][4] + bb; v1.y = acc[i][5] + bb; v1.z = acc[i][6] + bb; v1.w = acc[i][7] + bb;
    if (RELU_OUT) {
      v0.x = fmaxf(v0.x, 0.f); v0.y = fmaxf(v0.y, 0.f); v0.z = fmaxf(v0.z, 0.f); v0.w = fmaxf(v0.w, 0.f);
      v1.x = fmaxf(v1.x, 0.f); v1.y = fmaxf(v1.y, 0.f); v1.z = fmaxf(v1.z, 0.f); v1.w = fmaxf(v1.w, 0.f);
    }
    *(float4*)(Yb + (size_t)(m0 + m) * HW + n0 + tc * 4) = v0;
    *(float4*)(Yb + (size_t)(m0 + m) * HW + n0 + 64 + tc * 4) = v1;
  }
}

// ---------------- conv 3x3 fp32 (R1-verified) ----------------
__global__ __launch_bounds__(256) void conv3x3_kernel(
    const float* __restrict__ X, const float* __restrict__ Wf, const float* __restrict__ bias,
    float* __restrict__ Y)
{
  __shared__ __align__(16) float As[8][128];
  __shared__ __align__(16) float Bs[8][128];
  const int tid = threadIdx.x;
  const int b  = blockIdx.z;
  const int n0 = blockIdx.x * 128;
  const int h0 = n0 >> 6;
  const int tr = tid >> 4, tc = tid & 15;
  const int la_m = tid >> 1, la_k = (tid & 1) * 4;
  const int lb_k = tid >> 5, lb_nl = (tid & 31) * 4;
  const float* __restrict__ Xb = X + (size_t)b * 128 * HW;

  float acc[8][8];
#pragma unroll
  for (int i = 0; i < 8; ++i)
#pragma unroll
    for (int j = 0; j < 8; ++j) acc[i][j] = 0.f;

  for (int kt = 0; kt < 1152; kt += 8) {
    const float4 av = *(const float4*)(Wf + (size_t)la_m * 1152 + kt + la_k);
    const int kg = kt + lb_k;
    const int ci = kg / 9;
    const int r  = kg - ci * 9;
    const int ky = r / 3;
    const int kx = r - ky * 3;
    const int hh = h0 + (lb_nl >> 6) + ky - 1;
    float bvx = 0.f, bvy = 0.f, bvz = 0.f, bvw = 0.f;
    if ((unsigned)hh < 64u) {
      const float* rowp = Xb + (size_t)ci * HW + hh * 64;
      const int wb = (lb_nl & 63) + kx - 1;
      if ((unsigned)(wb + 0) < 64u) bvx = rowp[wb + 0];
      if ((unsigned)(wb + 1) < 64u) bvy = rowp[wb + 1];
      if ((unsigned)(wb + 2) < 64u) bvz = rowp[wb + 2];
      if ((unsigned)(wb + 3) < 64u) bvw = rowp[wb + 3];
    }
    __syncthreads();
    As[la_k + 0][la_m] = av.x;
    As[la_k + 1][la_m] = av.y;
    As[la_k + 2][la_m] = av.z;
    As[la_k + 3][la_m] = av.w;
    Bs[lb_k][lb_nl + 0] = bvx;
    Bs[lb_k][lb_nl + 1] = bvy;
    Bs[lb_k][lb_nl + 2] = bvz;
    Bs[lb_k][lb_nl + 3] = bvw;
    __syncthreads();
#pragma unroll
    for (int kk = 0; kk < 8; ++kk) {
      const float4 a0 = *(const float4*)&As[kk][tr * 4];
      const float4 a1 = *(const float4*)&As[kk][64 + tr * 4];
      const float4 b0 = *(const float4*)&Bs[kk][tc * 4];
      const float4 b1 = *(const float4*)&Bs[kk][64 + tc * 4];
      const float am[8] = {a0.x, a0.y, a0.z, a0.w, a1.x, a1.y, a1.z, a1.w};
      const float bn_[8] = {b0.x, b0.y, b0.z, b0.w, b1.x, b1.y, b1.z, b1.w};
#pragma unroll
      for (int i = 0; i < 8; ++i)
#pragma unroll
        for (int j = 0; j < 8; ++j) acc[i][j] += am[i] * bn_[j];
    }
  }

  float* __restrict__ Yb = Y + (size_t)b * 128 * HW;
#pragma unroll
  for (int i = 0; i < 8; ++i) {
    const int m = (i < 4) ? (tr * 4 + i) : (64 + tr * 4 + i - 4);
    const float bb = bias[m];
    float4 v0, v1;
    v0.x = fmaxf(acc[i][0] + bb, 0.f); v0.y = fmaxf(acc[i][1] + bb, 0.f);
    v0.z = fmaxf(acc[i][2] + bb, 0.f); v0.w = fmaxf(acc[i][3] + bb, 0.f);
    v1.x = fmaxf(acc[i][4] + bb, 0.f); v1.y = fmaxf(acc[i][5] + bb, 0.f);
    v1.z = fmaxf(acc[i][6] + bb, 0.f); v1.w = fmaxf(acc[i][7] + bb, 0.f);
    *(float4*)(Yb + (size_t)m * HW + n0 + tc * 4) = v0;
    *(float4*)(Yb + (size_t)m * HW + n0 + 64 + tc * 4) = v1;
  }
}

// ======== R7 shared machinery under test: templated no-LDS MFMA GEMM, NHWC B ========
template<int BMODE>
__device__ __forceinline__ void run_phase(
    const unsigned short* __restrict__ Wp,
    const unsigned short* __restrict__ Xb,
    const int K, const int tid, const int n0, f32x4 acc[4][4])
{
  const int lane = tid & 63;
  const int wv = tid >> 6, wm = wv >> 1, wn = wv & 1;
  const int q = lane >> 4, mm = lane & 15;

  const unsigned short* aP[4];
#pragma unroll
  for (int i = 0; i < 4; ++i)
    aP[i] = Wp + (size_t)(wm * 64 + i * 16 + mm) * K + q * 8;

  const unsigned short* bP[4];
#pragma unroll
  for (int j = 0; j < 4; ++j) {
    const int p = n0 + wn * 64 + j * 16 + mm;
    if constexpr (BMODE == 0) {
      bP[j] = Xb + (size_t)p * K + q * 8;
    } else {
      bP[j] = Xb + (size_t)((p >> 6) * 66 + (p & 63)) * 128 + q * 8;
    }
  }

  for (int kt = 0; kt < K; kt += 32) {
    s16x8 afr[4], bfr[4];
#pragma unroll
    for (int i = 0; i < 4; ++i) afr[i] = *(const s16x8*)(aP[i] + kt);
    if constexpr (BMODE == 0) {
#pragma unroll
      for (int j = 0; j < 4; ++j) bfr[j] = *(const s16x8*)(bP[j] + kt);
    } else {
      const int tap = kt >> 7;
      const int ky = tap / 3, kx = tap - ky * 3;
      const int off = (ky * 66 + kx) * 128 + (kt & 127);
#pragma unroll
      for (int j = 0; j < 4; ++j) bfr[j] = *(const s16x8*)(bP[j] + off);
    }
#pragma unroll
    for (int i = 0; i < 4; ++i)
#pragma unroll
      for (int j = 0; j < 4; ++j)
        acc[i][j] = __builtin_amdgcn_mfma_f32_16x16x32_bf16(afr[i], bfr[j], acc[i][j], 0, 0, 0);
  }
}

template<int BMODE, bool DUAL>
__global__ __launch_bounds__(256) void mgemm_kernel(
    const unsigned short* __restrict__ W0, const unsigned short* __restrict__ X0,
    const int K0, const long long xbs0,
    const unsigned short* __restrict__ W1, const unsigned short* __restrict__ X1,
    const int Kp1, const long long xbs1,
    const float* __restrict__ biasMid, const float* __restrict__ biasOut,
    const int omode, const int reluF, const int ldm,
    float* __restrict__ outF, unsigned short* __restrict__ outB,
    const long long obsF, const long long obsB)
{
  const int tid = threadIdx.x;
  const int b = blockIdx.z;
  const int n0 = blockIdx.x * 128;
  const int m0 = blockIdx.y * 128;
  const int lane = tid & 63, wv = tid >> 6, wm = wv >> 1, wn = wv & 1;
  const int q = lane >> 4, mm = lane & 15;

  f32x4 acc[4][4];
#pragma unroll
  for (int i = 0; i < 4; ++i)
#pragma unroll
    for (int j = 0; j < 4; ++j) acc[i][j] = (f32x4){0.f, 0.f, 0.f, 0.f};

  run_phase<BMODE>(W0 + (size_t)m0 * K0, X0 + (size_t)b * xbs0, K0, tid, n0, acc);

  if constexpr (DUAL) {
#pragma unroll
    for (int i = 0; i < 4; ++i) {
      const int mb = m0 + wm * 64 + i * 16 + q * 4;
#pragma unroll
      for (int r = 0; r < 4; ++r) {
        const float bm = biasMid[mb + r];
#pragma unroll
        for (int j = 0; j < 4; ++j) acc[i][j][r] = fmaxf(acc[i][j][r] + bm, 0.f);
      }
    }
    run_phase<0>(W1 + (size_t)m0 * Kp1, X1 + (size_t)b * xbs1, Kp1, tid, n0, acc);
  }

#pragma unroll
  for (int i = 0; i < 4; ++i) {
    const int mb = m0 + wm * 64 + i * 16 + q * 4;
    float bo[4];
#pragma unroll
    for (int r = 0; r < 4; ++r) bo[r] = biasOut[mb + r];
#pragma unroll
    for (int j = 0; j < 4; ++j) {
      const int n = n0 + wn * 64 + j * 16 + mm;
      float vv[4];
#pragma unroll
      for (int r = 0; r < 4; ++r) {
        float v = acc[i][j][r] + bo[r];
        if (reluF) v = fmaxf(v, 0.f);
        vv[r] = v;
      }
      if (omode == 0) {
        const int h = n >> 6, w = n & 63;
        u16x4 o;
#pragma unroll
        for (int r = 0; r < 4; ++r) o[r] = f2b(vv[r]);
        *(u16x4*)(outB + (size_t)b * obsB + ((size_t)(h + 1) * 66 + (w + 1)) * 128 + mb) = o;
      } else if (omode == 1) {
        u16x4 o;
#pragma unroll
        for (int r = 0; r < 4; ++r) o[r] = f2b(vv[r]);
        *(u16x4*)(outB + (size_t)b * obsB + (size_t)n * ldm + mb) = o;
      } else if (omode == 2) {
#pragma unroll
        for (int r = 0; r < 4; ++r)
          outF[(size_t)b * obsF + (size_t)(mb + r) * HW + n] = vv[r];
        u16x4 o;
#pragma unroll
        for (int r = 0; r < 4; ++r) o[r] = f2b(vv[r]);
        *(u16x4*)(outB + (size_t)b * obsB + (size_t)n * 512 + mb) = o;
      } else {
#pragma unroll
        for (int r = 0; r < 4; ++r)
          outB[(size_t)b * obsB + (size_t)(mb + r) * HW + n] = f2b(vv[r]);
      }
    }
  }
}

// ---------------- assignment (bf16 NCHW y) ----------------
__global__ __launch_bounds__(256) void assign_kernel(
    const unsigned short* __restrict__ Yv, const float* __restrict__ cw, const float* __restrict__ scale,
    const float* __restrict__ misc, float* __restrict__ A)
{
  __shared__ float Cs[16][64];
  __shared__ float Ys[16][64];
  __shared__ float dist[64][65];
  __shared__ float red[4][64];
  __shared__ float xsq[64];
  __shared__ float scl[64];
  __shared__ float csq[64];
  const int tid = threadIdx.x;
  const int b  = blockIdx.y;
  const int n0 = blockIdx.x * 64;
  if (tid < 64) { scl[tid] = scale[tid]; csq[tid] = misc[MS_CSQ + tid]; }
  const unsigned short* __restrict__ Yb = Yv + (size_t)b * CCH * HW;
  const int tr = tid >> 4, tc = tid & 15;
  const int lc_k = tid >> 2, lc_c = (tid & 3) * 4;
  const int ly_c0 = tid >> 6, ly_n = tid & 63;

  float acc[4][4];
#pragma unroll
  for (int i = 0; i < 4; ++i)
#pragma unroll
    for (int j = 0; j < 4; ++j) acc[i][j] = 0.f;
  float sq = 0.f;

  for (int c0 = 0; c0 < 512; c0 += 16) {
    const float4 cv = *(const float4*)(cw + (size_t)lc_k * 512 + c0 + lc_c);
    float yv[4];
#pragma unroll
    for (int rr = 0; rr < 4; ++rr)
      yv[rr] = b2f(Yb[(size_t)(c0 + ly_c0 + rr * 4) * HW + n0 + ly_n]);
    __syncthreads();
    Cs[lc_c + 0][lc_k] = cv.x;
    Cs[lc_c + 1][lc_k] = cv.y;
    Cs[lc_c + 2][lc_k] = cv.z;
    Cs[lc_c + 3][lc_k] = cv.w;
#pragma unroll
    for (int rr = 0; rr < 4; ++rr) {
      Ys[ly_c0 + rr * 4][ly_n] = yv[rr];
      sq += yv[rr] * yv[rr];
    }
    __syncthreads();
#pragma unroll
    for (int ct = 0; ct < 16; ++ct) {
      float rk[4], rn[4];
#pragma unroll
      for (int i = 0; i < 4; ++i) rk[i] = Cs[ct][tr * 4 + i];
#pragma unroll
      for (int j = 0; j < 4; ++j) rn[j] = Ys[ct][tc * 4 + j];
#pragma unroll
      for (int i = 0; i < 4; ++i)
#pragma unroll
        for (int j = 0; j < 4; ++j) acc[i][j] += rk[i] * rn[j];
    }
  }
  __syncthreads();
  red[ly_c0][ly_n] = sq;
  __syncthreads();
  if (tid < 64) xsq[tid] = red[0][tid] + red[1][tid] + red[2][tid] + red[3][tid];
  __syncthreads();
#pragma unroll
  for (int i = 0; i < 4; ++i)
#pragma unroll
    for (int j = 0; j < 4; ++j) {
      const int k = tr * 4 + i, n = tc * 4 + j;
      dist[k][n] = scl[k] * (xsq[n] - 2.f * acc[i][j] + csq[k]);
    }
  __syncthreads();
  const int qq = tid >> 6, n = tid & 63;
  float mx = -3.0e38f;
#pragma unroll
  for (int kk = 0; kk < 16; ++kk) mx = fmaxf(mx, dist[qq * 16 + kk][n]);
  red[qq][n] = mx;
  __syncthreads();
  mx = fmaxf(fmaxf(red[0][n], red[1][n]), fmaxf(red[2][n], red[3][n]));
  __syncthreads();
  float sum = 0.f;
#pragma unroll
  for (int kk = 0; kk < 16; ++kk) {
    const float e = __expf(dist[qq * 16 + kk][n] - mx);
    dist[qq * 16 + kk][n] = e;
    sum += e;
  }
  red[qq][n] = sum;
  __syncthreads();
  sum = red[0][n] + red[1][n] + red[2][n] + red[3][n];
  const float inv = 1.f / sum;
  float* __restrict__ Ab = A + (size_t)b * NK * HW + n0 + n;
#pragma unroll
  for (int kk = 0; kk < 16; ++kk)
    Ab[(size_t)(qq * 16 + kk) * HW] = dist[qq * 16 + kk][n] * inv;
}

// ---------------- asum ----------------
__global__ void asum_kernel(const float* __restrict__ A, float* __restrict__ asum)
{
  const int bk = blockIdx.x;
  const float* __restrict__ row = A + (size_t)bk * HW;
  const int t = threadIdx.x;
  float p = 0.f;
  for (int i = t * 4; i < HW; i += 1024) {
    const float4 v = *(const float4*)(row + i);
    p += v.x + v.y + v.z + v.w;
  }
  __shared__ float sm[256];
  sm[t] = p;
  __syncthreads();
  for (int s = 128; s > 0; s >>= 1) {
    if (t < s) sm[t] += sm[t + s];
    __syncthreads();
  }
  if (t == 0) asum[bk] = sm[0];
}

// ---------------- enc partial (bf16 NCHW y) ----------------
__global__ __launch_bounds__(256) void enc_kernel(
    const float* __restrict__ A, const unsigned short* __restrict__ Yv, float* __restrict__ pe)
{
  __shared__ float At[64][33];
  __shared__ float Yt[64][33];
  const int t = threadIdx.x;
  const int nc = blockIdx.x, ct = blockIdx.y, b = blockIdx.z;
  const int c0 = ct * 64;
  const float* __restrict__ Ab = A + (size_t)b * NK * HW + nc * 1024;
  const unsigned short* __restrict__ Yb = Yv + (size_t)b * CCH * HW + (size_t)c0 * HW + nc * 1024;
  const int lr = t >> 2, ln = (t & 3) * 8;
  const int tr = t >> 4, tc = t & 15;

  float acc[4][4];
#pragma unroll
  for (int i = 0; i < 4; ++i)
#pragma unroll
    for (int j = 0; j < 4; ++j) acc[i][j] = 0.f;

  for (int nb = 0; nb < 1024; nb += 32) {
    const float4 a0 = *(const float4*)(Ab + (size_t)lr * HW + nb + ln);
    const float4 a1 = *(const float4*)(Ab + (size_t)lr * HW + nb + ln + 4);
    s16x8 y8;
    __builtin_memcpy(&y8, Yb + (size_t)lr * HW + nb + ln, 16);
    __syncthreads();
    At[lr][ln + 0] = a0.x; At[lr][ln + 1] = a0.y; At[lr][ln + 2] = a0.z; At[lr][ln + 3] = a0.w;
    At[lr][ln + 4] = a1.x; At[lr][ln + 5] = a1.y; At[lr][ln + 6] = a1.z; At[lr][ln + 7] = a1.w;
#pragma unroll
    for (int qq = 0; qq < 8; ++qq) Yt[lr][ln + qq] = b2f((unsigned short)y8[qq]);
    __syncthreads();
#pragma unroll
    for (int nn = 0; nn < 32; ++nn) {
      float rk[4], ry[4];
#pragma unroll
      for (int i = 0; i < 4; ++i) rk[i] = At[tr * 4 + i][nn];
#pragma unroll
      for (int j = 0; j < 4; ++j) ry[j] = Yt[tc * 4 + j][nn];
#pragma unroll
      for (int i = 0; i < 4; ++i)
#pragma unroll
        for (int j = 0; j < 4; ++j) acc[i][j] += rk[i] * ry[j];
    }
  }
#pragma unroll
  for (int i = 0; i < 4; ++i) {
    const int k = tr * 4 + i;
    float4 v;
    v.x = acc[i][0]; v.y = acc[i][1]; v.z = acc[i][2]; v.w = acc[i][3];
    *(float4*)(pe + ((size_t)(b * 4 + nc) * NK + k) * CCH + c0 + tc * 4) = v;
  }
}

// ---------------- en + gate ----------------
__global__ __launch_bounds__(256) void engate_kernel(
    const float* __restrict__ pe, const float* __restrict__ asum, const float* __restrict__ cw,
    const float* __restrict__ misc, const float* __restrict__ wfc, const float* __restrict__ bfc,
    float* __restrict__ gam)
{
  const int b = blockIdx.x;
  const int t = threadIdx.x;
  __shared__ float asum_s[64], se_s[64], te_s[64];
  __shared__ __align__(16) float en_s[512];
  if (t < 64) {
    asum_s[t] = asum[b * 64 + t];
    se_s[t]   = misc[MS_SE + t];
    te_s[t]   = misc[MS_TE + t];
  }
  __syncthreads();
  for (int rep = 0; rep < 2; ++rep) {
    const int c = t + rep * 256;
    float en = 0.f;
    const float* __restrict__ peb = pe + (size_t)b * 4 * NK * CCH + c;
    for (int k = 0; k < 64; ++k) {
      const float ps = peb[(size_t)k * CCH] + peb[(size_t)(64 + k) * CCH] +
                       peb[(size_t)(128 + k) * CCH] + peb[(size_t)(192 + k) * CCH];
      float v = ps - asum_s[k] * cw[k * 512 + c];
      v = v * se_s[k] + te_s[k];
      en += fmaxf(v, 0.f);
    }
    en_s[c] = en * (1.f / 64.f);
  }
  __syncthreads();
  for (int rep = 0; rep < 2; ++rep) {
    const int i = t + rep * 256;
    float a = bfc[i];
    const float4* __restrict__ wrow = (const float4*)(wfc + (size_t)i * 512);
    const float4* __restrict__ ev = (const float4*)en_s;
    for (int j = 0; j < 128; ++j) {
      const float4 w4 = wrow[j];
      const float4 e4 = ev[j];
      a += w4.x * e4.x + w4.y * e4.y + w4.z * e4.z + w4.w * e4.w;
    }
    gam[b * 512 + i] = 1.f / (1.f + __expf(-a));
  }
}

// ---------------- final ----------------
__global__ void final_kernel(float* __restrict__ out, const float* __restrict__ gam)
{
  const size_t idx = (size_t)blockIdx.x * 256 + threadIdx.x;
  const size_t base = idx * 4;
  const int bc = (int)(base >> 12);
  const float g = 1.f + gam[bc];
  float4 v = *(float4*)(out + base);
  v.x = fmaxf(v.x * g, 0.f);
  v.y = fmaxf(v.y * g, 0.f);
  v.z = fmaxf(v.z * g, 0.f);
  v.w = fmaxf(v.w * g, 0.f);
  *(float4*)(out + base) = v;
}

extern "C" void kernel_launch(void* const* d_in, const int* in_sizes, int n_in,
                              void* d_out, int out_size, void* d_ws, size_t ws_size,
                              hipStream_t stream)
{
  const float* x  = (const float*)d_in[0];
  const float* w1 = (const float*)d_in[1];
  const float* g1 = (const float*)d_in[2];
  const float* b1 = (const float*)d_in[3];
  const float* m1 = (const float*)d_in[4];
  const float* v1 = (const float*)d_in[5];
  const float* w2 = (const float*)d_in[6];
  const float* g2 = (const float*)d_in[7];
  const float* b2 = (const float*)d_in[8];
  const float* m2 = (const float*)d_in[9];
  const float* v2 = (const float*)d_in[10];
  const float* w3 = (const float*)d_in[11];
  const float* g3 = (const float*)d_in[12];
  const float* b3 = (const float*)d_in[13];
  const float* m3 = (const float*)d_in[14];
  const float* v3 = (const float*)d_in[15];
  const float* wr = (const float*)d_in[16];
  const float* gr = (const float*)d_in[17];
  const float* br = (const float*)d_in[18];
  const float* mr = (const float*)d_in[19];
  const float* vr = (const float*)d_in[20];
  const float* wl = (const float*)d_in[21];
  const float* gl = (const float*)d_in[22];
  const float* bl = (const float*)d_in[23];
  const float* ml = (const float*)d_in[24];
  const float* vl = (const float*)d_in[25];
  const float* cw = (const float*)d_in[26];
  const float* scale = (const float*)d_in[27];
  const float* ge = (const float*)d_in[28];
  const float* be = (const float*)d_in[29];
  const float* me = (const float*)d_in[30];
  const float* ve = (const float*)d_in[31];
  const float* wfc = (const float*)d_in[32];
  const float* bfc = (const float*)d_in[33];

  float* ws = (float*)d_ws;
  float* h1   = ws + OFF_H1;
  float* h2   = ws + OFF_H2;
  unsigned short* x1b = (unsigned short*)(ws + OFF_X1B);  // overlays dead h1+h2
  unsigned short* yb  = (unsigned short*)(ws + OFF_YB);   // bf16 NCHW y
  float* A    = ws + OFF_A;
  float* pe   = ws + OFF_PE;
  float* asum = ws + OFF_ASUM;
  float* gam  = ws + OFF_GAM;
  float* misc = ws + OFF_MISC;
  float* w1f  = ws + OFF_W1F;
  float* w2f  = ws + OFF_W2F;
  float* w3f  = ws + OFF_W3F;
  float* wrf  = ws + OFF_WRF;
  unsigned short* wlb = (unsigned short*)(ws + OFF_WLF);
  float* x1   = (float*)d_out;

  prep_kernel<<<1, 256, 0, stream>>>(g1, b1, m1, v1, g2, b2, m2, v2, g3, b3, m3, v3,
                                     gr, br, mr, vr, gl, bl, ml, vl, ge, be, me, ve,
                                     cw, misc);
  fold_kernel<<<(65536 + 255) / 256, 256, 0, stream>>>(w1, misc + MS_S1, w1f, 65536, 512);
  fold_kernel<<<(147456 + 255) / 256, 256, 0, stream>>>(w2, misc + MS_S2, w2f, 147456, 1152);
  fold_kernel<<<(65536 + 255) / 256, 256, 0, stream>>>(w3, misc + MS_S3, w3f, 65536, 128);
  fold_kernel<<<(262144 + 255) / 256, 256, 0, stream>>>(wr, misc + MS_SR, wrf, 262144, 512);
  fold_bf16_kernel<<<1024, 256, 0, stream>>>(wl, misc + MS_SL, wlb, 262144, 512);

  // K1: h1 = relu(conv1x1(x, w1f) + t1)   (fp32, verified)
  gemm1x1_kernel<false, true><<<dim3(32, 1, 16), 256, 0, stream>>>(
      x, w1f, misc + MS_T1, nullptr, nullptr, nullptr, h1, 512, 0, 128);
  // K2: h2 = relu(conv3x3(h1, w2f) + t2)  (fp32, verified)
  conv3x3_kernel<<<dim3(32, 1, 16), 256, 0, stream>>>(h1, w2f, misc + MS_T2, h2);
  // K3: x1 = relu(conv1x1(h2, w3f) + t3) + conv1x1(x, wrf) + tr  (fp32, verified) -> d_out
  gemm1x1_kernel<true, false><<<dim3(32, 4, 16), 256, 0, stream>>>(
      h2, w3f, misc + MS_T3, x, wrf, misc + MS_TR, x1, 128, 512, 512);
  // NEW: x1 (f32 NCHW) -> x1b (bf16 NHWC)
  tr_kernel<<<dim3(64, 8, 16), 256, 0, stream>>>(x1, x1b);
  // NEW: K4 templated MFMA, NHWC B, omode=3 (bf16 NCHW y)
  mgemm_kernel<0, false><<<dim3(32, 4, 16), 256, 0, stream>>>(
      wlb, x1b, 512, 4096LL * 512, nullptr, nullptr, 0, 0,
      nullptr, misc + MS_TL, 3, 1, 0, nullptr, yb, 0, 512LL * 4096);
  // downstream (bf16-y readers)
  assign_kernel<<<dim3(64, 16), 256, 0, stream>>>(yb, cw, scale, misc, A);
  asum_kernel<<<1024, 256, 0, stream>>>(A, asum);
  enc_kernel<<<dim3(4, 8, 16), 256, 0, stream>>>(A, yb, pe);
  engate_kernel<<<16, 256, 0, stream>>>(pe, asum, cw, misc, wfc, bfc, gam);
  final_kernel<<<32768, 256, 0, stream>>>((float*)d_out, gam);
}

// Round 10
// 699.780 us; speedup vs baseline: 1.8934x; 1.8934x over previous
//
#include <hip/hip_runtime.h>
#include <math.h>

typedef float f32x4 __attribute__((ext_vector_type(4)));
typedef short s16x8 __attribute__((ext_vector_type(8)));
typedef unsigned short u16x4 __attribute__((ext_vector_type(4)));

#define HW 4096
#define CCH 512
#define NK 64

// ---- ws layout (BYTE offsets) — SIZE-AUDITED ----
// true sizes: bf16 (16,4096,512) = 67,108,864 B;  bf16 (16,4356,128) = 17,842,176 B;
//             bf16 (16,4096,128) = 16,777,216 B;  f32 (16,64,4096) = 16,777,216 B;
//             f32 (16,4,64,512) = 8,388,608 B.
// timeline: tr_x(x->xb) | K1(xb->h1p) | K2(h1p->h2) | K3(h2,xb->x1b) | K4(x1b->yb)
//           | assign(yb->A) | asum | enc(A,yb->pe) | engate(pe->gam) | fingate(x1b,gam->d_out)
#define C_XB   0ULL            // bf16 x NHWC      [0, 67,108,864)           dead after K3
#define C_H2   67108864ULL     // bf16 h2 NHWC     [67,108,864, 83,886,080)  dead after K3
#define C_H1P  83886080ULL     // bf16 h1 pad66    [83,886,080, 101,728,256) dead after K2
#define C_X1B  83886080ULL     // bf16 x1 NHWC     [83,886,080, 150,994,944) overlays dead h1p; live K3->fingate
#define C_YB   0ULL            // bf16 y NCHW      [0, 67,108,864)           overlays dead xb; live K4->enc
#define C_A    67108864ULL     // f32 A            [67,108,864, 83,886,080)  overlays dead h2; live assign->enc
#define C_ASUM 150994944ULL    // 4,096
#define C_GAM  150999040ULL    // 32,768
#define C_MISC 151031808ULL    // 16,384
#define C_W1F  151048192ULL    // bf16 w1 [128][512]  131,072
#define C_W2F  151179264ULL    // bf16 w2 tap-major [128][1152]  294,912
#define C_W3B  151474176ULL    // bf16 w3 [512][128]  131,072
#define C_WRB  151605248ULL    // bf16 wr [512][512]  524,288
#define C_WLB  152129536ULL    // bf16 wl [512][512]  524,288
#define C_PE   152653824ULL    // f32 pe 8,388,608 -> end 161,042,432  (< 162,648,064 proven)

#define MS_S1 0
#define MS_T1 128
#define MS_S2 256
#define MS_T2 384
#define MS_S3 512
#define MS_T3 1024
#define MS_SR 1536
#define MS_TR 2048
#define MS_SL 2560
#define MS_TL 3072
#define MS_SE 3584
#define MS_TE 3648
#define MS_CSQ 3712

__device__ __forceinline__ float b2f(unsigned short u) {
  unsigned int x = ((unsigned int)u) << 16;
  return __builtin_bit_cast(float, x);
}
__device__ __forceinline__ unsigned short f2b(float f) {
  unsigned int i = __builtin_bit_cast(unsigned int, f);
  i += 0x7fffu + ((i >> 16) & 1u);
  return (unsigned short)(i >> 16);
}

// ---------------- prep: fold BN params, c_sq ----------------
__global__ void prep_kernel(
    const float* __restrict__ g1, const float* __restrict__ b1, const float* __restrict__ m1, const float* __restrict__ v1,
    const float* __restrict__ g2, const float* __restrict__ b2, const float* __restrict__ m2, const float* __restrict__ v2,
    const float* __restrict__ g3, const float* __restrict__ b3, const float* __restrict__ m3, const float* __restrict__ v3,
    const float* __restrict__ gr, const float* __restrict__ br, const float* __restrict__ mr, const float* __restrict__ vr,
    const float* __restrict__ gl, const float* __restrict__ bl, const float* __restrict__ ml, const float* __restrict__ vl,
    const float* __restrict__ ge, const float* __restrict__ be, const float* __restrict__ me, const float* __restrict__ ve,
    const float* __restrict__ cw, float* __restrict__ misc)
{
  const int t = threadIdx.x;
  if (t < 128) {
    float s = g1[t] * rsqrtf(v1[t] + 1e-6f);
    misc[MS_S1 + t] = s; misc[MS_T1 + t] = b1[t] - m1[t] * s;
    s = g2[t] * rsqrtf(v2[t] + 1e-6f);
    misc[MS_S2 + t] = s; misc[MS_T2 + t] = b2[t] - m2[t] * s;
  }
  for (int c = t; c < 512; c += 256) {
    float s = g3[c] * rsqrtf(v3[c] + 1e-6f);
    misc[MS_S3 + c] = s; misc[MS_T3 + c] = b3[c] - m3[c] * s;
    s = gr[c] * rsqrtf(vr[c] + 1e-6f);
    misc[MS_SR + c] = s; misc[MS_TR + c] = br[c] - mr[c] * s;
    s = gl[c] * rsqrtf(vl[c] + 1e-5f);
    misc[MS_SL + c] = s; misc[MS_TL + c] = bl[c] - ml[c] * s;
  }
  if (t < 64) {
    float s = ge[t] * rsqrtf(ve[t] + 1e-5f);
    misc[MS_SE + t] = s; misc[MS_TE + t] = be[t] - me[t] * s;
    float acc = 0.f;
    for (int c = 0; c < 512; ++c) { float v = cw[t * 512 + c]; acc += v * v; }
    misc[MS_CSQ + t] = acc;
  }
}

// ---------------- fold weights -> bf16 ----------------
__global__ void fold_bf16_kernel(const float* __restrict__ w, const float* __restrict__ s,
                                 unsigned short* __restrict__ out, int total, int kper)
{
  int i = blockIdx.x * 256 + threadIdx.x;
  if (i < total) out[i] = f2b(w[i] * s[i / kper]);
}

// w2 reorder to tap-major: dst[m][tp*128 + ci] = w2[m][ci*9 + tp] * s2[m]
__global__ void fold_w2_kernel(const float* __restrict__ w2, const float* __restrict__ s,
                               unsigned short* __restrict__ out)
{
  int j = blockIdx.x * 256 + threadIdx.x;
  if (j < 147456) {
    int m = j / 1152, r = j - m * 1152;
    int tp = r >> 7, ci = r & 127;
    out[j] = f2b(w2[m * 1152 + ci * 9 + tp] * s[m]);
  }
}

// ---------------- f32 NCHW (512 ch) -> bf16 NHWC (tiled transpose; R8-verified) ----------------
__global__ __launch_bounds__(256) void tr_kernel(const float* __restrict__ x,
                                                 unsigned short* __restrict__ xb)
{
  __shared__ float T[64][65];
  const int b = blockIdx.z, c0 = blockIdx.y * 64, n0 = blockIdx.x * 64;
  const int t = threadIdx.x;
  const int rr = t >> 4, cc = (t & 15) * 4;
#pragma unroll
  for (int rep = 0; rep < 4; ++rep) {
    const int cr = rep * 16 + rr;
    const float4 v = *(const float4*)(x + ((size_t)(b * 512 + c0 + cr)) * 4096 + n0 + cc);
    T[cr][cc + 0] = v.x; T[cr][cc + 1] = v.y; T[cr][cc + 2] = v.z; T[cr][cc + 3] = v.w;
  }
  __syncthreads();
#pragma unroll
  for (int rep = 0; rep < 4; ++rep) {
    const int nr = rep * 16 + rr;
    u16x4 o;
    o[0] = f2b(T[cc + 0][nr]); o[1] = f2b(T[cc + 1][nr]);
    o[2] = f2b(T[cc + 2][nr]); o[3] = f2b(T[cc + 3][nr]);
    *(u16x4*)(xb + ((size_t)(b * 4096 + n0 + nr)) * 512 + c0 + cc) = o;
  }
}

// ======== MFMA GEMM (no LDS; core + omode1/3 + param-template verified R6/R8) ========
template<int BMODE>
__device__ __forceinline__ void run_phase(
    const unsigned short* __restrict__ Wp,
    const unsigned short* __restrict__ Xb,
    const int K, const int tid, const int n0, f32x4 acc[4][4])
{
  const int lane = tid & 63;
  const int wv = tid >> 6, wm = wv >> 1, wn = wv & 1;
  const int q = lane >> 4, mm = lane & 15;

  const unsigned short* aP[4];
#pragma unroll
  for (int i = 0; i < 4; ++i)
    aP[i] = Wp + (size_t)(wm * 64 + i * 16 + mm) * K + q * 8;

  const unsigned short* bP[4];
#pragma unroll
  for (int j = 0; j < 4; ++j) {
    const int p = n0 + wn * 64 + j * 16 + mm;
    if constexpr (BMODE == 0) {
      bP[j] = Xb + (size_t)p * K + q * 8;
    } else {
      bP[j] = Xb + (size_t)((p >> 6) * 66 + (p & 63)) * 128 + q * 8;
    }
  }

  for (int kt = 0; kt < K; kt += 32) {
    s16x8 afr[4], bfr[4];
#pragma unroll
    for (int i = 0; i < 4; ++i) afr[i] = *(const s16x8*)(aP[i] + kt);
    if constexpr (BMODE == 0) {
#pragma unroll
      for (int j = 0; j < 4; ++j) bfr[j] = *(const s16x8*)(bP[j] + kt);
    } else {
      const int tap = kt >> 7;                 // k = tap*128 + ci; 32-chunks never cross taps
      const int ky = tap / 3, kx = tap - ky * 3;
      const int off = (ky * 66 + kx) * 128 + (kt & 127);
#pragma unroll
      for (int j = 0; j < 4; ++j) bfr[j] = *(const s16x8*)(bP[j] + off);
    }
#pragma unroll
    for (int i = 0; i < 4; ++i)
#pragma unroll
      for (int j = 0; j < 4; ++j)
        acc[i][j] = __builtin_amdgcn_mfma_f32_16x16x32_bf16(afr[i], bfr[j], acc[i][j], 0, 0, 0);
  }
}

template<int BMODE, bool DUAL>
__global__ __launch_bounds__(256) void mgemm_kernel(
    const unsigned short* __restrict__ W0, const unsigned short* __restrict__ X0,
    const int K0, const long long xbs0,
    const unsigned short* __restrict__ W1, const unsigned short* __restrict__ X1,
    const int Kp1, const long long xbs1,
    const float* __restrict__ biasMid, const float* __restrict__ biasOut,
    const int omode,  // 0: bf16 padded-66 NHWC(128); 1: bf16 NHWC (ldm); 3: bf16 NCHW
    const int reluF, const int ldm,
    unsigned short* __restrict__ outB, const long long obsB)
{
  const int tid = threadIdx.x;
  const int b = blockIdx.z;
  const int n0 = blockIdx.x * 128;
  const int m0 = blockIdx.y * 128;
  const int lane = tid & 63, wv = tid >> 6, wm = wv >> 1, wn = wv & 1;
  const int q = lane >> 4, mm = lane & 15;

  f32x4 acc[4][4];
#pragma unroll
  for (int i = 0; i < 4; ++i)
#pragma unroll
    for (int j = 0; j < 4; ++j) acc[i][j] = (f32x4){0.f, 0.f, 0.f, 0.f};

  run_phase<BMODE>(W0 + (size_t)m0 * K0, X0 + (size_t)b * xbs0, K0, tid, n0, acc);

  if constexpr (DUAL) {
#pragma unroll
    for (int i = 0; i < 4; ++i) {
      const int mb = m0 + wm * 64 + i * 16 + q * 4;
#pragma unroll
      for (int r = 0; r < 4; ++r) {
        const float bm = biasMid[mb + r];
#pragma unroll
        for (int j = 0; j < 4; ++j) acc[i][j][r] = fmaxf(acc[i][j][r] + bm, 0.f);
      }
    }
    run_phase<0>(W1 + (size_t)m0 * Kp1, X1 + (size_t)b * xbs1, Kp1, tid, n0, acc);
  }

#pragma unroll
  for (int i = 0; i < 4; ++i) {
    const int mb = m0 + wm * 64 + i * 16 + q * 4;
    float bo[4];
#pragma unroll
    for (int r = 0; r < 4; ++r) bo[r] = biasOut[mb + r];
#pragma unroll
    for (int j = 0; j < 4; ++j) {
      const int n = n0 + wn * 64 + j * 16 + mm;
      float vv[4];
#pragma unroll
      for (int r = 0; r < 4; ++r) {
        float v = acc[i][j][r] + bo[r];
        if (reluF) v = fmaxf(v, 0.f);
        vv[r] = v;
      }
      if (omode == 0) {
        const int h = n >> 6, w = n & 63;
        u16x4 o;
#pragma unroll
        for (int r = 0; r < 4; ++r) o[r] = f2b(vv[r]);
        *(u16x4*)(outB + (size_t)b * obsB + ((size_t)(h + 1) * 66 + (w + 1)) * 128 + mb) = o;
      } else if (omode == 1) {
        u16x4 o;
#pragma unroll
        for (int r = 0; r < 4; ++r) o[r] = f2b(vv[r]);
        *(u16x4*)(outB + (size_t)b * obsB + (size_t)n * ldm + mb) = o;
      } else {   // omode 3: bf16 NCHW
#pragma unroll
        for (int r = 0; r < 4; ++r)
          outB[(size_t)b * obsB + (size_t)(mb + r) * HW + n] = f2b(vv[r]);
      }
    }
  }
}

// ---------------- assignment (bf16 NCHW y; R8-verified) ----------------
__global__ __launch_bounds__(256) void assign_kernel(
    const unsigned short* __restrict__ Yv, const float* __restrict__ cw, const float* __restrict__ scale,
    const float* __restrict__ misc, float* __restrict__ A)
{
  __shared__ float Cs[16][64];
  __shared__ float Ys[16][64];
  __shared__ float dist[64][65];
  __shared__ float red[4][64];
  __shared__ float xsq[64];
  __shared__ float scl[64];
  __shared__ float csq[64];
  const int tid = threadIdx.x;
  const int b  = blockIdx.y;
  const int n0 = blockIdx.x * 64;
  if (tid < 64) { scl[tid] = scale[tid]; csq[tid] = misc[MS_CSQ + tid]; }
  const unsigned short* __restrict__ Yb = Yv + (size_t)b * CCH * HW;
  const int tr = tid >> 4, tc = tid & 15;
  const int lc_k = tid >> 2, lc_c = (tid & 3) * 4;
  const int ly_c0 = tid >> 6, ly_n = tid & 63;

  float acc[4][4];
#pragma unroll
  for (int i = 0; i < 4; ++i)
#pragma unroll
    for (int j = 0; j < 4; ++j) acc[i][j] = 0.f;
  float sq = 0.f;

  for (int c0 = 0; c0 < 512; c0 += 16) {
    const float4 cv = *(const float4*)(cw + (size_t)lc_k * 512 + c0 + lc_c);
    float yv[4];
#pragma unroll
    for (int rr = 0; rr < 4; ++rr)
      yv[rr] = b2f(Yb[(size_t)(c0 + ly_c0 + rr * 4) * HW + n0 + ly_n]);
    __syncthreads();
    Cs[lc_c + 0][lc_k] = cv.x;
    Cs[lc_c + 1][lc_k] = cv.y;
    Cs[lc_c + 2][lc_k] = cv.z;
    Cs[lc_c + 3][lc_k] = cv.w;
#pragma unroll
    for (int rr = 0; rr < 4; ++rr) {
      Ys[ly_c0 + rr * 4][ly_n] = yv[rr];
      sq += yv[rr] * yv[rr];
    }
    __syncthreads();
#pragma unroll
    for (int ct = 0; ct < 16; ++ct) {
      float rk[4], rn[4];
#pragma unroll
      for (int i = 0; i < 4; ++i) rk[i] = Cs[ct][tr * 4 + i];
#pragma unroll
      for (int j = 0; j < 4; ++j) rn[j] = Ys[ct][tc * 4 + j];
#pragma unroll
      for (int i = 0; i < 4; ++i)
#pragma unroll
        for (int j = 0; j < 4; ++j) acc[i][j] += rk[i] * rn[j];
    }
  }
  __syncthreads();
  red[ly_c0][ly_n] = sq;
  __syncthreads();
  if (tid < 64) xsq[tid] = red[0][tid] + red[1][tid] + red[2][tid] + red[3][tid];
  __syncthreads();
#pragma unroll
  for (int i = 0; i < 4; ++i)
#pragma unroll
    for (int j = 0; j < 4; ++j) {
      const int k = tr * 4 + i, n = tc * 4 + j;
      dist[k][n] = scl[k] * (xsq[n] - 2.f * acc[i][j] + csq[k]);
    }
  __syncthreads();
  const int qq = tid >> 6, n = tid & 63;
  float mx = -3.0e38f;
#pragma unroll
  for (int kk = 0; kk < 16; ++kk) mx = fmaxf(mx, dist[qq * 16 + kk][n]);
  red[qq][n] = mx;
  __syncthreads();
  mx = fmaxf(fmaxf(red[0][n], red[1][n]), fmaxf(red[2][n], red[3][n]));
  __syncthreads();
  float sum = 0.f;
#pragma unroll
  for (int kk = 0; kk < 16; ++kk) {
    const float e = __expf(dist[qq * 16 + kk][n] - mx);
    dist[qq * 16 + kk][n] = e;
    sum += e;
  }
  red[qq][n] = sum;
  __syncthreads();
  sum = red[0][n] + red[1][n] + red[2][n] + red[3][n];
  const float inv = 1.f / sum;
  float* __restrict__ Ab = A + (size_t)b * NK * HW + n0 + n;
#pragma unroll
  for (int kk = 0; kk < 16; ++kk)
    Ab[(size_t)(qq * 16 + kk) * HW] = dist[qq * 16 + kk][n] * inv;
}

// ---------------- asum ----------------
__global__ void asum_kernel(const float* __restrict__ A, float* __restrict__ asum)
{
  const int bk = blockIdx.x;
  const float* __restrict__ row = A + (size_t)bk * HW;
  const int t = threadIdx.x;
  float p = 0.f;
  for (int i = t * 4; i < HW; i += 1024) {
    const float4 v = *(const float4*)(row + i);
    p += v.x + v.y + v.z + v.w;
  }
  __shared__ float sm[256];
  sm[t] = p;
  __syncthreads();
  for (int s = 128; s > 0; s >>= 1) {
    if (t < s) sm[t] += sm[t + s];
    __syncthreads();
  }
  if (t == 0) asum[bk] = sm[0];
}

// ---------------- enc partial (bf16 NCHW y; R8-verified) ----------------
__global__ __launch_bounds__(256) void enc_kernel(
    const float* __restrict__ A, const unsigned short* __restrict__ Yv, float* __restrict__ pe)
{
  __shared__ float At[64][33];
  __shared__ float Yt[64][33];
  const int t = threadIdx.x;
  const int nc = blockIdx.x, ct = blockIdx.y, b = blockIdx.z;
  const int c0 = ct * 64;
  const float* __restrict__ Ab = A + (size_t)b * NK * HW + nc * 1024;
  const unsigned short* __restrict__ Yb = Yv + (size_t)b * CCH * HW + (size_t)c0 * HW + nc * 1024;
  const int lr = t >> 2, ln = (t & 3) * 8;
  const int tr = t >> 4, tc = t & 15;

  float acc[4][4];
#pragma unroll
  for (int i = 0; i < 4; ++i)
#pragma unroll
    for (int j = 0; j < 4; ++j) acc[i][j] = 0.f;

  for (int nb = 0; nb < 1024; nb += 32) {
    const float4 a0 = *(const float4*)(Ab + (size_t)lr * HW + nb + ln);
    const float4 a1 = *(const float4*)(Ab + (size_t)lr * HW + nb + ln + 4);
    s16x8 y8;
    __builtin_memcpy(&y8, Yb + (size_t)lr * HW + nb + ln, 16);
    __syncthreads();
    At[lr][ln + 0] = a0.x; At[lr][ln + 1] = a0.y; At[lr][ln + 2] = a0.z; At[lr][ln + 3] = a0.w;
    At[lr][ln + 4] = a1.x; At[lr][ln + 5] = a1.y; At[lr][ln + 6] = a1.z; At[lr][ln + 7] = a1.w;
#pragma unroll
    for (int qq = 0; qq < 8; ++qq) Yt[lr][ln + qq] = b2f((unsigned short)y8[qq]);
    __syncthreads();
#pragma unroll
    for (int nn = 0; nn < 32; ++nn) {
      float rk[4], ry[4];
#pragma unroll
      for (int i = 0; i < 4; ++i) rk[i] = At[tr * 4 + i][nn];
#pragma unroll
      for (int j = 0; j < 4; ++j) ry[j] = Yt[tc * 4 + j][nn];
#pragma unroll
      for (int i = 0; i < 4; ++i)
#pragma unroll
        for (int j = 0; j < 4; ++j) acc[i][j] += rk[i] * ry[j];
    }
  }
#pragma unroll
  for (int i = 0; i < 4; ++i) {
    const int k = tr * 4 + i;
    float4 v;
    v.x = acc[i][0]; v.y = acc[i][1]; v.z = acc[i][2]; v.w = acc[i][3];
    *(float4*)(pe + ((size_t)(b * 4 + nc) * NK + k) * CCH + c0 + tc * 4) = v;
  }
}

// ---------------- en + gate ----------------
__global__ __launch_bounds__(256) void engate_kernel(
    const float* __restrict__ pe, const float* __restrict__ asum, const float* __restrict__ cw,
    const float* __restrict__ misc, const float* __restrict__ wfc, const float* __restrict__ bfc,
    float* __restrict__ gam)
{
  const int b = blockIdx.x;
  const int t = threadIdx.x;
  __shared__ float asum_s[64], se_s[64], te_s[64];
  __shared__ __align__(16) float en_s[512];
  if (t < 64) {
    asum_s[t] = asum[b * 64 + t];
    se_s[t]   = misc[MS_SE + t];
    te_s[t]   = misc[MS_TE + t];
  }
  __syncthreads();
  for (int rep = 0; rep < 2; ++rep) {
    const int c = t + rep * 256;
    float en = 0.f;
    const float* __restrict__ peb = pe + (size_t)b * 4 * NK * CCH + c;
    for (int k = 0; k < 64; ++k) {
      const float ps = peb[(size_t)k * CCH] + peb[(size_t)(64 + k) * CCH] +
                       peb[(size_t)(128 + k) * CCH] + peb[(size_t)(192 + k) * CCH];
      float v = ps - asum_s[k] * cw[k * 512 + c];
      v = v * se_s[k] + te_s[k];
      en += fmaxf(v, 0.f);
    }
    en_s[c] = en * (1.f / 64.f);
  }
  __syncthreads();
  for (int rep = 0; rep < 2; ++rep) {
    const int i = t + rep * 256;
    float a = bfc[i];
    const float4* __restrict__ wrow = (const float4*)(wfc + (size_t)i * 512);
    const float4* __restrict__ ev = (const float4*)en_s;
    for (int j = 0; j < 128; ++j) {
      const float4 w4 = wrow[j];
      const float4 e4 = ev[j];
      a += w4.x * e4.x + w4.y * e4.y + w4.z * e4.z + w4.w * e4.w;
    }
    gam[b * 512 + i] = 1.f / (1.f + __expf(-a));
  }
}

// ---------------- fingate: out(NCHW f32) = relu(x1 * (1 + gam)), x1 = bf16 NHWC ----------------
__global__ __launch_bounds__(256) void fingate_kernel(
    const unsigned short* __restrict__ x1b, const float* __restrict__ gam,
    float* __restrict__ out)
{
  __shared__ float T[64][65];
  const int b = blockIdx.z, c0 = blockIdx.y * 64, n0 = blockIdx.x * 64;
  const int t = threadIdx.x;
  const int rr = t >> 4, cc = (t & 15) * 4;
#pragma unroll
  for (int rep = 0; rep < 4; ++rep) {
    const int pr = rep * 16 + rr;   // pixel within tile
    u16x4 v = *(const u16x4*)(x1b + ((size_t)(b * 4096 + n0 + pr)) * 512 + c0 + cc);
    T[cc + 0][pr] = b2f(v[0]);
    T[cc + 1][pr] = b2f(v[1]);
    T[cc + 2][pr] = b2f(v[2]);
    T[cc + 3][pr] = b2f(v[3]);
  }
  __syncthreads();
#pragma unroll
  for (int rep = 0; rep < 4; ++rep) {
    const int cr = rep * 16 + rr;   // channel within tile
    const float g = 1.f + gam[b * 512 + c0 + cr];
    float4 o;
    o.x = fmaxf(T[cr][cc + 0] * g, 0.f);
    o.y = fmaxf(T[cr][cc + 1] * g, 0.f);
    o.z = fmaxf(T[cr][cc + 2] * g, 0.f);
    o.w = fmaxf(T[cr][cc + 3] * g, 0.f);
    *(float4*)(out + ((size_t)(b * 512 + c0 + cr)) * 4096 + n0 + cc) = o;
  }
}

extern "C" void kernel_launch(void* const* d_in, const int* in_sizes, int n_in,
                              void* d_out, int out_size, void* d_ws, size_t ws_size,
                              hipStream_t stream)
{
  const float* x  = (const float*)d_in[0];
  const float* w1 = (const float*)d_in[1];
  const float* g1 = (const float*)d_in[2];
  const float* b1 = (const float*)d_in[3];
  const float* m1 = (const float*)d_in[4];
  const float* v1 = (const float*)d_in[5];
  const float* w2 = (const float*)d_in[6];
  const float* g2 = (const float*)d_in[7];
  const float* b2 = (const float*)d_in[8];
  const float* m2 = (const float*)d_in[9];
  const float* v2 = (const float*)d_in[10];
  const float* w3 = (const float*)d_in[11];
  const float* g3 = (const float*)d_in[12];
  const float* b3 = (const float*)d_in[13];
  const float* m3 = (const float*)d_in[14];
  const float* v3 = (const float*)d_in[15];
  const float* wr = (const float*)d_in[16];
  const float* gr = (const float*)d_in[17];
  const float* br = (const float*)d_in[18];
  const float* mr = (const float*)d_in[19];
  const float* vr = (const float*)d_in[20];
  const float* wl = (const float*)d_in[21];
  const float* gl = (const float*)d_in[22];
  const float* bl = (const float*)d_in[23];
  const float* ml = (const float*)d_in[24];
  const float* vl = (const float*)d_in[25];
  const float* cw = (const float*)d_in[26];
  const float* scale = (const float*)d_in[27];
  const float* ge = (const float*)d_in[28];
  const float* be = (const float*)d_in[29];
  const float* me = (const float*)d_in[30];
  const float* ve = (const float*)d_in[31];
  const float* wfc = (const float*)d_in[32];
  const float* bfc = (const float*)d_in[33];

  char* wsb = (char*)d_ws;
  unsigned short* xb  = (unsigned short*)(wsb + C_XB);
  unsigned short* h2  = (unsigned short*)(wsb + C_H2);
  unsigned short* h1p = (unsigned short*)(wsb + C_H1P);
  unsigned short* x1b = (unsigned short*)(wsb + C_X1B);
  unsigned short* yb  = (unsigned short*)(wsb + C_YB);
  float* A    = (float*)(wsb + C_A);
  float* pe   = (float*)(wsb + C_PE);
  float* asum = (float*)(wsb + C_ASUM);
  float* gam  = (float*)(wsb + C_GAM);
  float* misc = (float*)(wsb + C_MISC);
  unsigned short* w1f = (unsigned short*)(wsb + C_W1F);
  unsigned short* w2f = (unsigned short*)(wsb + C_W2F);
  unsigned short* w3b = (unsigned short*)(wsb + C_W3B);
  unsigned short* wrb = (unsigned short*)(wsb + C_WRB);
  unsigned short* wlb = (unsigned short*)(wsb + C_WLB);

  prep_kernel<<<1, 256, 0, stream>>>(g1, b1, m1, v1, g2, b2, m2, v2, g3, b3, m3, v3,
                                     gr, br, mr, vr, gl, bl, ml, vl, ge, be, me, ve,
                                     cw, misc);
  fold_bf16_kernel<<<256, 256, 0, stream>>>(w1, misc + MS_S1, w1f, 65536, 512);
  fold_w2_kernel<<<576, 256, 0, stream>>>(w2, misc + MS_S2, w2f);
  fold_bf16_kernel<<<256, 256, 0, stream>>>(w3, misc + MS_S3, w3b, 65536, 128);
  fold_bf16_kernel<<<1024, 256, 0, stream>>>(wr, misc + MS_SR, wrb, 262144, 512);
  fold_bf16_kernel<<<1024, 256, 0, stream>>>(wl, misc + MS_SL, wlb, 262144, 512);

  // tr_x: x (f32 NCHW) -> xb (bf16 NHWC)
  tr_kernel<<<dim3(64, 8, 16), 256, 0, stream>>>(x, xb);
  // zero h1p padding every launch (x1b overlay destroys it between replays)
  hipMemsetAsync(h1p, 0, 17842176, stream);

  // K1: h1p = relu(conv1x1(xb, w1f) + t1) -> padded-66 NHWC bf16 (omode 0)
  mgemm_kernel<0, false><<<dim3(32, 1, 16), 256, 0, stream>>>(
      w1f, xb, 512, 4096LL * 512, nullptr, nullptr, 0, 0,
      nullptr, misc + MS_T1, 0, 1, 128, h1p, 4356LL * 128);
  // K2: h2 = relu(conv3x3(h1p, w2f) + t2) -> flat NHWC bf16 (BMODE 1, omode 1)
  mgemm_kernel<1, false><<<dim3(32, 1, 16), 256, 0, stream>>>(
      w2f, h1p, 1152, 4356LL * 128, nullptr, nullptr, 0, 0,
      nullptr, misc + MS_T2, 1, 1, 128, h2, 4096LL * 128);
  // K3: x1b = relu(conv1x1(h2,w3b)+t3) + conv1x1(xb,wrb)+tr -> NHWC bf16 (DUAL, omode 1)
  mgemm_kernel<0, true><<<dim3(32, 4, 16), 256, 0, stream>>>(
      w3b, h2, 128, 4096LL * 128, wrb, xb, 512, 4096LL * 512,
      misc + MS_T3, misc + MS_TR, 1, 0, 512, x1b, 4096LL * 512);
  // K4: yb = relu(conv1x1(x1b, wlb) + tl) -> bf16 NCHW (omode 3; R8-verified config)
  mgemm_kernel<0, false><<<dim3(32, 4, 16), 256, 0, stream>>>(
      wlb, x1b, 512, 4096LL * 512, nullptr, nullptr, 0, 0,
      nullptr, misc + MS_TL, 3, 1, 0, yb, 512LL * 4096);

  // downstream (R8-verified)
  assign_kernel<<<dim3(64, 16), 256, 0, stream>>>(yb, cw, scale, misc, A);
  asum_kernel<<<1024, 256, 0, stream>>>(A, asum);
  enc_kernel<<<dim3(4, 8, 16), 256, 0, stream>>>(A, yb, pe);
  engate_kernel<<<16, 256, 0, stream>>>(pe, asum, cw, misc, wfc, bfc, gam);
  // fingate: d_out = relu(x1 * (1 + gam)) with NHWC->NCHW transpose
  fingate_kernel<<<dim3(64, 8, 16), 256, 0, stream>>>(x1b, gam, (float*)d_out);
}

// Round 11
// 553.241 us; speedup vs baseline: 2.3949x; 1.2649x over previous
//
#include <hip/hip_runtime.h>
#include <math.h>

typedef float f32x4 __attribute__((ext_vector_type(4)));
typedef short s16x8 __attribute__((ext_vector_type(8)));
typedef unsigned short u16x4 __attribute__((ext_vector_type(4)));

#define HW 4096
#define CCH 512
#define NK 64
#define EPAD 136   // epilogue LDS row pitch (ushorts): 272B, 16B-aligned, ~2-way banks

// ---- ws layout (BYTE offsets) — SIZE-AUDITED (same as R10) ----
#define C_XB   0ULL
#define C_H2   67108864ULL
#define C_H1P  83886080ULL
#define C_X1B  83886080ULL
#define C_YB   0ULL
#define C_A    67108864ULL
#define C_ASUM 150994944ULL
#define C_GAM  150999040ULL
#define C_MISC 151031808ULL
#define C_W1F  151048192ULL
#define C_W2F  151179264ULL
#define C_W3B  151474176ULL
#define C_WRB  151605248ULL
#define C_WLB  152129536ULL
#define C_PE   152653824ULL    // -> end 161,042,432

#define MS_S1 0
#define MS_T1 128
#define MS_S2 256
#define MS_T2 384
#define MS_S3 512
#define MS_T3 1024
#define MS_SR 1536
#define MS_TR 2048
#define MS_SL 2560
#define MS_TL 3072
#define MS_SE 3584
#define MS_TE 3648
#define MS_CSQ 3712

__device__ __forceinline__ float b2f(unsigned short u) {
  unsigned int x = ((unsigned int)u) << 16;
  return __builtin_bit_cast(float, x);
}
__device__ __forceinline__ unsigned short f2b(float f) {
  unsigned int i = __builtin_bit_cast(unsigned int, f);
  i += 0x7fffu + ((i >> 16) & 1u);
  return (unsigned short)(i >> 16);
}

// ---------------- prep: fold BN params, c_sq ----------------
__global__ void prep_kernel(
    const float* __restrict__ g1, const float* __restrict__ b1, const float* __restrict__ m1, const float* __restrict__ v1,
    const float* __restrict__ g2, const float* __restrict__ b2, const float* __restrict__ m2, const float* __restrict__ v2,
    const float* __restrict__ g3, const float* __restrict__ b3, const float* __restrict__ m3, const float* __restrict__ v3,
    const float* __restrict__ gr, const float* __restrict__ br, const float* __restrict__ mr, const float* __restrict__ vr,
    const float* __restrict__ gl, const float* __restrict__ bl, const float* __restrict__ ml, const float* __restrict__ vl,
    const float* __restrict__ ge, const float* __restrict__ be, const float* __restrict__ me, const float* __restrict__ ve,
    const float* __restrict__ cw, float* __restrict__ misc)
{
  const int t = threadIdx.x;
  if (t < 128) {
    float s = g1[t] * rsqrtf(v1[t] + 1e-6f);
    misc[MS_S1 + t] = s; misc[MS_T1 + t] = b1[t] - m1[t] * s;
    s = g2[t] * rsqrtf(v2[t] + 1e-6f);
    misc[MS_S2 + t] = s; misc[MS_T2 + t] = b2[t] - m2[t] * s;
  }
  for (int c = t; c < 512; c += 256) {
    float s = g3[c] * rsqrtf(v3[c] + 1e-6f);
    misc[MS_S3 + c] = s; misc[MS_T3 + c] = b3[c] - m3[c] * s;
    s = gr[c] * rsqrtf(vr[c] + 1e-6f);
    misc[MS_SR + c] = s; misc[MS_TR + c] = br[c] - mr[c] * s;
    s = gl[c] * rsqrtf(vl[c] + 1e-5f);
    misc[MS_SL + c] = s; misc[MS_TL + c] = bl[c] - ml[c] * s;
  }
  if (t < 64) {
    float s = ge[t] * rsqrtf(ve[t] + 1e-5f);
    misc[MS_SE + t] = s; misc[MS_TE + t] = be[t] - me[t] * s;
    float acc = 0.f;
    for (int c = 0; c < 512; ++c) { float v = cw[t * 512 + c]; acc += v * v; }
    misc[MS_CSQ + t] = acc;
  }
}

// ---------------- fold weights -> bf16 ----------------
__global__ void fold_bf16_kernel(const float* __restrict__ w, const float* __restrict__ s,
                                 unsigned short* __restrict__ out, int total, int kper)
{
  int i = blockIdx.x * 256 + threadIdx.x;
  if (i < total) out[i] = f2b(w[i] * s[i / kper]);
}

// w2 reorder to tap-major: dst[m][tp*128 + ci] = w2[m][ci*9 + tp] * s2[m]
__global__ void fold_w2_kernel(const float* __restrict__ w2, const float* __restrict__ s,
                               unsigned short* __restrict__ out)
{
  int j = blockIdx.x * 256 + threadIdx.x;
  if (j < 147456) {
    int m = j / 1152, r = j - m * 1152;
    int tp = r >> 7, ci = r & 127;
    out[j] = f2b(w2[m * 1152 + ci * 9 + tp] * s[m]);
  }
}

// ---------------- f32 NCHW (512 ch) -> bf16 NHWC ----------------
__global__ __launch_bounds__(256) void tr_kernel(const float* __restrict__ x,
                                                 unsigned short* __restrict__ xb)
{
  __shared__ float T[64][65];
  const int b = blockIdx.z, c0 = blockIdx.y * 64, n0 = blockIdx.x * 64;
  const int t = threadIdx.x;
  const int rr = t >> 4, cc = (t & 15) * 4;
#pragma unroll
  for (int rep = 0; rep < 4; ++rep) {
    const int cr = rep * 16 + rr;
    const float4 v = *(const float4*)(x + ((size_t)(b * 512 + c0 + cr)) * 4096 + n0 + cc);
    T[cr][cc + 0] = v.x; T[cr][cc + 1] = v.y; T[cr][cc + 2] = v.z; T[cr][cc + 3] = v.w;
  }
  __syncthreads();
#pragma unroll
  for (int rep = 0; rep < 4; ++rep) {
    const int nr = rep * 16 + rr;
    u16x4 o;
    o[0] = f2b(T[cc + 0][nr]); o[1] = f2b(T[cc + 1][nr]);
    o[2] = f2b(T[cc + 2][nr]); o[3] = f2b(T[cc + 3][nr]);
    *(u16x4*)(xb + ((size_t)(b * 4096 + n0 + nr)) * 512 + c0 + cc) = o;
  }
}

// ======== MFMA GEMM v2: reg-staged LDS tiles (swizzle-on-write, linear-read) ========
// Fragment-slot contract (verified R6/R8): slot s (16B) holds T[row=(s>>6)*16+(s&15)][k=((s>>4)&3)*8..+8].
// Staging chunk (r, ko) -> slot (r>>4)*64 + ko*16 + (r&15); global source is row-contiguous
// (64B per row per BK=32), so waves issue 16x 64B cache-line segments.
// Fragment read: 16B at slot (w*4+i)*64 + lane  -> 1024B linear per quarter, 2-way banks (free).

template<int BMODE>
__device__ __forceinline__ void run_phase(
    const unsigned short* __restrict__ Wp,
    const unsigned short* __restrict__ Xb,
    const int K, const int tid, const int n0,
    unsigned short* __restrict__ As, unsigned short* __restrict__ Bs,
    f32x4 acc[4][4])
{
  const int lane = tid & 63;
  const int wv = tid >> 6, wm = wv >> 1, wn = wv & 1;

  const int ko = tid & 3;
  const int r0 = tid >> 2;        // 0..63
  const int r1 = 64 + r0;

  const unsigned short* aS0 = Wp + (size_t)r0 * K + ko * 8;
  const unsigned short* aS1 = Wp + (size_t)r1 * K + ko * 8;
  unsigned short* aD0 = As + (size_t)(((r0 >> 4) * 64) + ko * 16 + (r0 & 15)) * 8;
  unsigned short* aD1 = As + (size_t)(((r1 >> 4) * 64) + ko * 16 + (r1 & 15)) * 8;

  const unsigned short* bS0 = nullptr;
  const unsigned short* bS1 = nullptr;
  size_t bBase0 = 0, bBase1 = 0;
  if constexpr (BMODE == 0) {
    bS0 = Xb + (size_t)(n0 + r0) * K + ko * 8;
    bS1 = Xb + (size_t)(n0 + r1) * K + ko * 8;
  } else {
    const int pg0 = n0 + r0, pg1 = n0 + r1;
    bBase0 = (size_t)((pg0 >> 6) * 66 + (pg0 & 63)) * 128 + ko * 8;
    bBase1 = (size_t)((pg1 >> 6) * 66 + (pg1 & 63)) * 128 + ko * 8;
  }
  unsigned short* bD0 = Bs + (size_t)(((r0 >> 4) * 64) + ko * 16 + (r0 & 15)) * 8;
  unsigned short* bD1 = Bs + (size_t)(((r1 >> 4) * 64) + ko * 16 + (r1 & 15)) * 8;

  for (int kt = 0; kt < K; kt += 32) {
    s16x8 a0, a1, b0, b1;
    __builtin_memcpy(&a0, aS0 + kt, 16);
    __builtin_memcpy(&a1, aS1 + kt, 16);
    if constexpr (BMODE == 0) {
      __builtin_memcpy(&b0, bS0 + kt, 16);
      __builtin_memcpy(&b1, bS1 + kt, 16);
    } else {
      const int tap = kt >> 7;
      const int ky = tap / 3, kx = tap - ky * 3;
      const int off = (ky * 66 + kx) * 128 + (kt & 127);
      __builtin_memcpy(&b0, Xb + bBase0 + off, 16);
      __builtin_memcpy(&b1, Xb + bBase1 + off, 16);
    }
    __syncthreads();                // prior iteration's fragment reads complete
    *(s16x8*)aD0 = a0; *(s16x8*)aD1 = a1;
    *(s16x8*)bD0 = b0; *(s16x8*)bD1 = b1;
    __syncthreads();                // tile visible

    s16x8 afr[4], bfr[4];
#pragma unroll
    for (int i = 0; i < 4; ++i)
      afr[i] = *(const s16x8*)(As + (size_t)((wm * 4 + i) * 64 + lane) * 8);
#pragma unroll
    for (int j = 0; j < 4; ++j)
      bfr[j] = *(const s16x8*)(Bs + (size_t)((wn * 4 + j) * 64 + lane) * 8);
#pragma unroll
    for (int i = 0; i < 4; ++i)
#pragma unroll
      for (int j = 0; j < 4; ++j)
        acc[i][j] = __builtin_amdgcn_mfma_f32_16x16x32_bf16(afr[i], bfr[j], acc[i][j], 0, 0, 0);
  }
}

template<int BMODE, bool DUAL>
__global__ __launch_bounds__(256) void mgemm_kernel(
    const unsigned short* __restrict__ W0, const unsigned short* __restrict__ X0,
    const int K0, const long long xbs0,
    const unsigned short* __restrict__ W1, const unsigned short* __restrict__ X1,
    const int Kp1, const long long xbs1,
    const float* __restrict__ biasMid, const float* __restrict__ biasOut,
    const int omode,  // 0: bf16 padded-66 NHWC(128); 1: bf16 NHWC (ldm); 3: bf16 NCHW
    const int reluF, const int ldm,
    unsigned short* __restrict__ outB, const long long obsB)
{
  __shared__ __align__(16) unsigned short smem[128 * EPAD];  // 34,816B; staging uses first 16KB
  unsigned short* As = smem;
  unsigned short* Bs = smem + 4096;

  const int tid = threadIdx.x;
  const int b = blockIdx.z;
  const int n0 = blockIdx.x * 128;
  const int m0 = blockIdx.y * 128;
  const int lane = tid & 63, wv = tid >> 6, wm = wv >> 1, wn = wv & 1;
  const int q = lane >> 4, mm = lane & 15;

  f32x4 acc[4][4];
#pragma unroll
  for (int i = 0; i < 4; ++i)
#pragma unroll
    for (int j = 0; j < 4; ++j) acc[i][j] = (f32x4){0.f, 0.f, 0.f, 0.f};

  run_phase<BMODE>(W0 + (size_t)m0 * K0, X0 + (size_t)b * xbs0, K0, tid, n0, As, Bs, acc);

  if constexpr (DUAL) {
#pragma unroll
    for (int i = 0; i < 4; ++i) {
      const int mb = m0 + wm * 64 + i * 16 + q * 4;
#pragma unroll
      for (int r = 0; r < 4; ++r) {
        const float bm = biasMid[mb + r];
#pragma unroll
        for (int j = 0; j < 4; ++j) acc[i][j][r] = fmaxf(acc[i][j][r] + bm, 0.f);
      }
    }
    run_phase<0>(W1 + (size_t)m0 * Kp1, X1 + (size_t)b * xbs1, Kp1, tid, n0, As, Bs, acc);
  }

  // ---- epilogue via LDS (coalesced 128B stores) ----
  __syncthreads();   // all fragment reads done before smem reuse
  if (omode == 3) {
    // CH-major tile [128 ch][EPAD]
#pragma unroll
    for (int i = 0; i < 4; ++i) {
      const int chb = wm * 64 + i * 16 + q * 4;
#pragma unroll
      for (int r = 0; r < 4; ++r) {
        const float bo = biasOut[m0 + chb + r];
#pragma unroll
        for (int j = 0; j < 4; ++j) {
          const int px = wn * 64 + j * 16 + mm;
          float v = acc[i][j][r] + bo;
          if (reluF) v = fmaxf(v, 0.f);
          smem[(size_t)(chb + r) * EPAD + px] = f2b(v);
        }
      }
    }
    __syncthreads();
    const int ch = tid >> 1, half = tid & 1;
    const unsigned short* src = smem + (size_t)ch * EPAD + half * 64;
    unsigned short* dst = outB + (size_t)b * obsB + (size_t)(m0 + ch) * HW + n0 + half * 64;
#pragma unroll
    for (int r = 0; r < 8; ++r) {
      s16x8 v;
      __builtin_memcpy(&v, src + r * 8, 16);
      *(s16x8*)(dst + r * 8) = v;
    }
  } else {
    // PX-major tile [128 px][EPAD]
#pragma unroll
    for (int i = 0; i < 4; ++i) {
      const int chb = wm * 64 + i * 16 + q * 4;
      float bo[4];
#pragma unroll
      for (int r = 0; r < 4; ++r) bo[r] = biasOut[m0 + chb + r];
#pragma unroll
      for (int j = 0; j < 4; ++j) {
        const int px = wn * 64 + j * 16 + mm;
        u16x4 o;
#pragma unroll
        for (int r = 0; r < 4; ++r) {
          float v = acc[i][j][r] + bo[r];
          if (reluF) v = fmaxf(v, 0.f);
          o[r] = f2b(v);
        }
        *(u16x4*)(smem + (size_t)px * EPAD + chb) = o;
      }
    }
    __syncthreads();
    const int px = tid >> 1, half = tid & 1;
    const unsigned short* src = smem + (size_t)px * EPAD + half * 64;
    size_t dstoff;
    if (omode == 1) {
      dstoff = (size_t)b * obsB + (size_t)(n0 + px) * ldm + m0 + half * 64;
    } else {
      const int hp = ((n0 + px) >> 6) + 1, wp = ((n0 + px) & 63) + 1;
      dstoff = (size_t)b * obsB + ((size_t)hp * 66 + wp) * 128 + m0 + half * 64;
    }
    unsigned short* dst = outB + dstoff;
#pragma unroll
    for (int r = 0; r < 8; ++r) {
      s16x8 v;
      __builtin_memcpy(&v, src + r * 8, 16);
      *(s16x8*)(dst + r * 8) = v;
    }
  }
}

// ---------------- assignment (bf16 NCHW y; R8-verified) ----------------
__global__ __launch_bounds__(256) void assign_kernel(
    const unsigned short* __restrict__ Yv, const float* __restrict__ cw, const float* __restrict__ scale,
    const float* __restrict__ misc, float* __restrict__ A)
{
  __shared__ float Cs[16][64];
  __shared__ float Ys[16][64];
  __shared__ float dist[64][65];
  __shared__ float red[4][64];
  __shared__ float xsq[64];
  __shared__ float scl[64];
  __shared__ float csq[64];
  const int tid = threadIdx.x;
  const int b  = blockIdx.y;
  const int n0 = blockIdx.x * 64;
  if (tid < 64) { scl[tid] = scale[tid]; csq[tid] = misc[MS_CSQ + tid]; }
  const unsigned short* __restrict__ Yb = Yv + (size_t)b * CCH * HW;
  const int tr = tid >> 4, tc = tid & 15;
  const int lc_k = tid >> 2, lc_c = (tid & 3) * 4;
  const int ly_c0 = tid >> 6, ly_n = tid & 63;

  float acc[4][4];
#pragma unroll
  for (int i = 0; i < 4; ++i)
#pragma unroll
    for (int j = 0; j < 4; ++j) acc[i][j] = 0.f;
  float sq = 0.f;

  for (int c0 = 0; c0 < 512; c0 += 16) {
    const float4 cv = *(const float4*)(cw + (size_t)lc_k * 512 + c0 + lc_c);
    float yv[4];
#pragma unroll
    for (int rr = 0; rr < 4; ++rr)
      yv[rr] = b2f(Yb[(size_t)(c0 + ly_c0 + rr * 4) * HW + n0 + ly_n]);
    __syncthreads();
    Cs[lc_c + 0][lc_k] = cv.x;
    Cs[lc_c + 1][lc_k] = cv.y;
    Cs[lc_c + 2][lc_k] = cv.z;
    Cs[lc_c + 3][lc_k] = cv.w;
#pragma unroll
    for (int rr = 0; rr < 4; ++rr) {
      Ys[ly_c0 + rr * 4][ly_n] = yv[rr];
      sq += yv[rr] * yv[rr];
    }
    __syncthreads();
#pragma unroll
    for (int ct = 0; ct < 16; ++ct) {
      float rk[4], rn[4];
#pragma unroll
      for (int i = 0; i < 4; ++i) rk[i] = Cs[ct][tr * 4 + i];
#pragma unroll
      for (int j = 0; j < 4; ++j) rn[j] = Ys[ct][tc * 4 + j];
#pragma unroll
      for (int i = 0; i < 4; ++i)
#pragma unroll
        for (int j = 0; j < 4; ++j) acc[i][j] += rk[i] * rn[j];
    }
  }
  __syncthreads();
  red[ly_c0][ly_n] = sq;
  __syncthreads();
  if (tid < 64) xsq[tid] = red[0][tid] + red[1][tid] + red[2][tid] + red[3][tid];
  __syncthreads();
#pragma unroll
  for (int i = 0; i < 4; ++i)
#pragma unroll
    for (int j = 0; j < 4; ++j) {
      const int k = tr * 4 + i, n = tc * 4 + j;
      dist[k][n] = scl[k] * (xsq[n] - 2.f * acc[i][j] + csq[k]);
    }
  __syncthreads();
  const int qq = tid >> 6, n = tid & 63;
  float mx = -3.0e38f;
#pragma unroll
  for (int kk = 0; kk < 16; ++kk) mx = fmaxf(mx, dist[qq * 16 + kk][n]);
  red[qq][n] = mx;
  __syncthreads();
  mx = fmaxf(fmaxf(red[0][n], red[1][n]), fmaxf(red[2][n], red[3][n]));
  __syncthreads();
  float sum = 0.f;
#pragma unroll
  for (int kk = 0; kk < 16; ++kk) {
    const float e = __expf(dist[qq * 16 + kk][n] - mx);
    dist[qq * 16 + kk][n] = e;
    sum += e;
  }
  red[qq][n] = sum;
  __syncthreads();
  sum = red[0][n] + red[1][n] + red[2][n] + red[3][n];
  const float inv = 1.f / sum;
  float* __restrict__ Ab = A + (size_t)b * NK * HW + n0 + n;
#pragma unroll
  for (int kk = 0; kk < 16; ++kk)
    Ab[(size_t)(qq * 16 + kk) * HW] = dist[qq * 16 + kk][n] * inv;
}

// ---------------- asum ----------------
__global__ void asum_kernel(const float* __restrict__ A, float* __restrict__ asum)
{
  const int bk = blockIdx.x;
  const float* __restrict__ row = A + (size_t)bk * HW;
  const int t = threadIdx.x;
  float p = 0.f;
  for (int i = t * 4; i < HW; i += 1024) {
    const float4 v = *(const float4*)(row + i);
    p += v.x + v.y + v.z + v.w;
  }
  __shared__ float sm[256];
  sm[t] = p;
  __syncthreads();
  for (int s = 128; s > 0; s >>= 1) {
    if (t < s) sm[t] += sm[t + s];
    __syncthreads();
  }
  if (t == 0) asum[bk] = sm[0];
}

// ---------------- enc partial (bf16 NCHW y; R8-verified) ----------------
__global__ __launch_bounds__(256) void enc_kernel(
    const float* __restrict__ A, const unsigned short* __restrict__ Yv, float* __restrict__ pe)
{
  __shared__ float At[64][33];
  __shared__ float Yt[64][33];
  const int t = threadIdx.x;
  const int nc = blockIdx.x, ct = blockIdx.y, b = blockIdx.z;
  const int c0 = ct * 64;
  const float* __restrict__ Ab = A + (size_t)b * NK * HW + nc * 1024;
  const unsigned short* __restrict__ Yb = Yv + (size_t)b * CCH * HW + (size_t)c0 * HW + nc * 1024;
  const int lr = t >> 2, ln = (t & 3) * 8;
  const int tr = t >> 4, tc = t & 15;

  float acc[4][4];
#pragma unroll
  for (int i = 0; i < 4; ++i)
#pragma unroll
    for (int j = 0; j < 4; ++j) acc[i][j] = 0.f;

  for (int nb = 0; nb < 1024; nb += 32) {
    const float4 a0 = *(const float4*)(Ab + (size_t)lr * HW + nb + ln);
    const float4 a1 = *(const float4*)(Ab + (size_t)lr * HW + nb + ln + 4);
    s16x8 y8;
    __builtin_memcpy(&y8, Yb + (size_t)lr * HW + nb + ln, 16);
    __syncthreads();
    At[lr][ln + 0] = a0.x; At[lr][ln + 1] = a0.y; At[lr][ln + 2] = a0.z; At[lr][ln + 3] = a0.w;
    At[lr][ln + 4] = a1.x; At[lr][ln + 5] = a1.y; At[lr][ln + 6] = a1.z; At[lr][ln + 7] = a1.w;
#pragma unroll
    for (int qq = 0; qq < 8; ++qq) Yt[lr][ln + qq] = b2f((unsigned short)y8[qq]);
    __syncthreads();
#pragma unroll
    for (int nn = 0; nn < 32; ++nn) {
      float rk[4], ry[4];
#pragma unroll
      for (int i = 0; i < 4; ++i) rk[i] = At[tr * 4 + i][nn];
#pragma unroll
      for (int j = 0; j < 4; ++j) ry[j] = Yt[tc * 4 + j][nn];
#pragma unroll
      for (int i = 0; i < 4; ++i)
#pragma unroll
        for (int j = 0; j < 4; ++j) acc[i][j] += rk[i] * ry[j];
    }
  }
#pragma unroll
  for (int i = 0; i < 4; ++i) {
    const int k = tr * 4 + i;
    float4 v;
    v.x = acc[i][0]; v.y = acc[i][1]; v.z = acc[i][2]; v.w = acc[i][3];
    *(float4*)(pe + ((size_t)(b * 4 + nc) * NK + k) * CCH + c0 + tc * 4) = v;
  }
}

// ---------------- en + gate ----------------
__global__ __launch_bounds__(256) void engate_kernel(
    const float* __restrict__ pe, const float* __restrict__ asum, const float* __restrict__ cw,
    const float* __restrict__ misc, const float* __restrict__ wfc, const float* __restrict__ bfc,
    float* __restrict__ gam)
{
  const int b = blockIdx.x;
  const int t = threadIdx.x;
  __shared__ float asum_s[64], se_s[64], te_s[64];
  __shared__ __align__(16) float en_s[512];
  if (t < 64) {
    asum_s[t] = asum[b * 64 + t];
    se_s[t]   = misc[MS_SE + t];
    te_s[t]   = misc[MS_TE + t];
  }
  __syncthreads();
  for (int rep = 0; rep < 2; ++rep) {
    const int c = t + rep * 256;
    float en = 0.f;
    const float* __restrict__ peb = pe + (size_t)b * 4 * NK * CCH + c;
    for (int k = 0; k < 64; ++k) {
      const float ps = peb[(size_t)k * CCH] + peb[(size_t)(64 + k) * CCH] +
                       peb[(size_t)(128 + k) * CCH] + peb[(size_t)(192 + k) * CCH];
      float v = ps - asum_s[k] * cw[k * 512 + c];
      v = v * se_s[k] + te_s[k];
      en += fmaxf(v, 0.f);
    }
    en_s[c] = en * (1.f / 64.f);
  }
  __syncthreads();
  for (int rep = 0; rep < 2; ++rep) {
    const int i = t + rep * 256;
    float a = bfc[i];
    const float4* __restrict__ wrow = (const float4*)(wfc + (size_t)i * 512);
    const float4* __restrict__ ev = (const float4*)en_s;
    for (int j = 0; j < 128; ++j) {
      const float4 w4 = wrow[j];
      const float4 e4 = ev[j];
      a += w4.x * e4.x + w4.y * e4.y + w4.z * e4.z + w4.w * e4.w;
    }
    gam[b * 512 + i] = 1.f / (1.f + __expf(-a));
  }
}

// ---------------- fingate: out(NCHW f32) = relu(x1 * (1 + gam)), x1 = bf16 NHWC ----------------
__global__ __launch_bounds__(256) void fingate_kernel(
    const unsigned short* __restrict__ x1b, const float* __restrict__ gam,
    float* __restrict__ out)
{
  __shared__ float T[64][65];
  const int b = blockIdx.z, c0 = blockIdx.y * 64, n0 = blockIdx.x * 64;
  const int t = threadIdx.x;
  const int rr = t >> 4, cc = (t & 15) * 4;
#pragma unroll
  for (int rep = 0; rep < 4; ++rep) {
    const int pr = rep * 16 + rr;
    u16x4 v = *(const u16x4*)(x1b + ((size_t)(b * 4096 + n0 + pr)) * 512 + c0 + cc);
    T[cc + 0][pr] = b2f(v[0]);
    T[cc + 1][pr] = b2f(v[1]);
    T[cc + 2][pr] = b2f(v[2]);
    T[cc + 3][pr] = b2f(v[3]);
  }
  __syncthreads();
#pragma unroll
  for (int rep = 0; rep < 4; ++rep) {
    const int cr = rep * 16 + rr;
    const float g = 1.f + gam[b * 512 + c0 + cr];
    float4 o;
    o.x = fmaxf(T[cr][cc + 0] * g, 0.f);
    o.y = fmaxf(T[cr][cc + 1] * g, 0.f);
    o.z = fmaxf(T[cr][cc + 2] * g, 0.f);
    o.w = fmaxf(T[cr][cc + 3] * g, 0.f);
    *(float4*)(out + ((size_t)(b * 512 + c0 + cr)) * 4096 + n0 + cc) = o;
  }
}

extern "C" void kernel_launch(void* const* d_in, const int* in_sizes, int n_in,
                              void* d_out, int out_size, void* d_ws, size_t ws_size,
                              hipStream_t stream)
{
  const float* x  = (const float*)d_in[0];
  const float* w1 = (const float*)d_in[1];
  const float* g1 = (const float*)d_in[2];
  const float* b1 = (const float*)d_in[3];
  const float* m1 = (const float*)d_in[4];
  const float* v1 = (const float*)d_in[5];
  const float* w2 = (const float*)d_in[6];
  const float* g2 = (const float*)d_in[7];
  const float* b2 = (const float*)d_in[8];
  const float* m2 = (const float*)d_in[9];
  const float* v2 = (const float*)d_in[10];
  const float* w3 = (const float*)d_in[11];
  const float* g3 = (const float*)d_in[12];
  const float* b3 = (const float*)d_in[13];
  const float* m3 = (const float*)d_in[14];
  const float* v3 = (const float*)d_in[15];
  const float* wr = (const float*)d_in[16];
  const float* gr = (const float*)d_in[17];
  const float* br = (const float*)d_in[18];
  const float* mr = (const float*)d_in[19];
  const float* vr = (const float*)d_in[20];
  const float* wl = (const float*)d_in[21];
  const float* gl = (const float*)d_in[22];
  const float* bl = (const float*)d_in[23];
  const float* ml = (const float*)d_in[24];
  const float* vl = (const float*)d_in[25];
  const float* cw = (const float*)d_in[26];
  const float* scale = (const float*)d_in[27];
  const float* ge = (const float*)d_in[28];
  const float* be = (const float*)d_in[29];
  const float* me = (const float*)d_in[30];
  const float* ve = (const float*)d_in[31];
  const float* wfc = (const float*)d_in[32];
  const float* bfc = (const float*)d_in[33];

  char* wsb = (char*)d_ws;
  unsigned short* xb  = (unsigned short*)(wsb + C_XB);
  unsigned short* h2  = (unsigned short*)(wsb + C_H2);
  unsigned short* h1p = (unsigned short*)(wsb + C_H1P);
  unsigned short* x1b = (unsigned short*)(wsb + C_X1B);
  unsigned short* yb  = (unsigned short*)(wsb + C_YB);
  float* A    = (float*)(wsb + C_A);
  float* pe   = (float*)(wsb + C_PE);
  float* asum = (float*)(wsb + C_ASUM);
  float* gam  = (float*)(wsb + C_GAM);
  float* misc = (float*)(wsb + C_MISC);
  unsigned short* w1f = (unsigned short*)(wsb + C_W1F);
  unsigned short* w2f = (unsigned short*)(wsb + C_W2F);
  unsigned short* w3b = (unsigned short*)(wsb + C_W3B);
  unsigned short* wrb = (unsigned short*)(wsb + C_WRB);
  unsigned short* wlb = (unsigned short*)(wsb + C_WLB);

  prep_kernel<<<1, 256, 0, stream>>>(g1, b1, m1, v1, g2, b2, m2, v2, g3, b3, m3, v3,
                                     gr, br, mr, vr, gl, bl, ml, vl, ge, be, me, ve,
                                     cw, misc);
  fold_bf16_kernel<<<256, 256, 0, stream>>>(w1, misc + MS_S1, w1f, 65536, 512);
  fold_w2_kernel<<<576, 256, 0, stream>>>(w2, misc + MS_S2, w2f);
  fold_bf16_kernel<<<256, 256, 0, stream>>>(w3, misc + MS_S3, w3b, 65536, 128);
  fold_bf16_kernel<<<1024, 256, 0, stream>>>(wr, misc + MS_SR, wrb, 262144, 512);
  fold_bf16_kernel<<<1024, 256, 0, stream>>>(wl, misc + MS_SL, wlb, 262144, 512);

  tr_kernel<<<dim3(64, 8, 16), 256, 0, stream>>>(x, xb);
  hipMemsetAsync(h1p, 0, 17842176, stream);

  // K1: h1p = relu(conv1x1(xb, w1f) + t1) -> padded-66 NHWC bf16 (omode 0)
  mgemm_kernel<0, false><<<dim3(32, 1, 16), 256, 0, stream>>>(
      w1f, xb, 512, 4096LL * 512, nullptr, nullptr, 0, 0,
      nullptr, misc + MS_T1, 0, 1, 128, h1p, 4356LL * 128);
  // K2: h2 = relu(conv3x3(h1p, w2f) + t2) -> flat NHWC bf16 (BMODE 1, omode 1)
  mgemm_kernel<1, false><<<dim3(32, 1, 16), 256, 0, stream>>>(
      w2f, h1p, 1152, 4356LL * 128, nullptr, nullptr, 0, 0,
      nullptr, misc + MS_T2, 1, 1, 128, h2, 4096LL * 128);
  // K3: x1b = relu(conv1x1(h2,w3b)+t3) + conv1x1(xb,wrb)+tr -> NHWC bf16 (DUAL, omode 1)
  mgemm_kernel<0, true><<<dim3(32, 4, 16), 256, 0, stream>>>(
      w3b, h2, 128, 4096LL * 128, wrb, xb, 512, 4096LL * 512,
      misc + MS_T3, misc + MS_TR, 1, 0, 512, x1b, 4096LL * 512);
  // K4: yb = relu(conv1x1(x1b, wlb) + tl) -> bf16 NCHW (omode 3)
  mgemm_kernel<0, false><<<dim3(32, 4, 16), 256, 0, stream>>>(
      wlb, x1b, 512, 4096LL * 512, nullptr, nullptr, 0, 0,
      nullptr, misc + MS_TL, 3, 1, 0, yb, 512LL * 4096);

  assign_kernel<<<dim3(64, 16), 256, 0, stream>>>(yb, cw, scale, misc, A);
  asum_kernel<<<1024, 256, 0, stream>>>(A, asum);
  enc_kernel<<<dim3(4, 8, 16), 256, 0, stream>>>(A, yb, pe);
  engate_kernel<<<16, 256, 0, stream>>>(pe, asum, cw, misc, wfc, bfc, gam);
  fingate_kernel<<<dim3(64, 8, 16), 256, 0, stream>>>(x1b, gam, (float*)d_out);
}

// Round 12
// 483.065 us; speedup vs baseline: 2.7429x; 1.1453x over previous
//
#include <hip/hip_runtime.h>
#include <math.h>

typedef float f32x4 __attribute__((ext_vector_type(4)));
typedef short s16x8 __attribute__((ext_vector_type(8)));
typedef unsigned short u16x4 __attribute__((ext_vector_type(4)));

#define HW 4096
#define CCH 512
#define NK 64
#define EPAD 136   // epilogue LDS row pitch (ushorts)

// ---- ws layout (BYTE offsets) — SIZE-AUDITED ----
#define C_XB   0ULL
#define C_H2   67108864ULL
#define C_H1P  83886080ULL
#define C_X1B  83886080ULL
#define C_YB   0ULL
#define C_AHI  67108864ULL     // bf16 A-hi [16][64][4096] = 8,388,608 (overlays dead h2)
#define C_ALO  75497472ULL     // bf16 A-lo 8,388,608
#define C_ASUM 150994944ULL
#define C_GAM  150999040ULL
#define C_MISC 151031808ULL
#define C_W1F  151048192ULL
#define C_W2F  151179264ULL
#define C_W3B  151474176ULL
#define C_WRB  151605248ULL
#define C_WLB  152129536ULL
#define C_PE   152653824ULL    // -> end 161,042,432

#define MS_S1 0
#define MS_T1 128
#define MS_S2 256
#define MS_T2 384
#define MS_S3 512
#define MS_T3 1024
#define MS_SR 1536
#define MS_TR 2048
#define MS_SL 2560
#define MS_TL 3072
#define MS_SE 3584
#define MS_TE 3648
#define MS_CSQ 3712

__device__ __forceinline__ float b2f(unsigned short u) {
  unsigned int x = ((unsigned int)u) << 16;
  return __builtin_bit_cast(float, x);
}
__device__ __forceinline__ unsigned short f2b(float f) {
  unsigned int i = __builtin_bit_cast(unsigned int, f);
  i += 0x7fffu + ((i >> 16) & 1u);
  return (unsigned short)(i >> 16);
}

// ---------------- prep ----------------
__global__ void prep_kernel(
    const float* __restrict__ g1, const float* __restrict__ b1, const float* __restrict__ m1, const float* __restrict__ v1,
    const float* __restrict__ g2, const float* __restrict__ b2, const float* __restrict__ m2, const float* __restrict__ v2,
    const float* __restrict__ g3, const float* __restrict__ b3, const float* __restrict__ m3, const float* __restrict__ v3,
    const float* __restrict__ gr, const float* __restrict__ br, const float* __restrict__ mr, const float* __restrict__ vr,
    const float* __restrict__ gl, const float* __restrict__ bl, const float* __restrict__ ml, const float* __restrict__ vl,
    const float* __restrict__ ge, const float* __restrict__ be, const float* __restrict__ me, const float* __restrict__ ve,
    const float* __restrict__ cw, float* __restrict__ misc)
{
  const int t = threadIdx.x;
  if (t < 128) {
    float s = g1[t] * rsqrtf(v1[t] + 1e-6f);
    misc[MS_S1 + t] = s; misc[MS_T1 + t] = b1[t] - m1[t] * s;
    s = g2[t] * rsqrtf(v2[t] + 1e-6f);
    misc[MS_S2 + t] = s; misc[MS_T2 + t] = b2[t] - m2[t] * s;
  }
  for (int c = t; c < 512; c += 256) {
    float s = g3[c] * rsqrtf(v3[c] + 1e-6f);
    misc[MS_S3 + c] = s; misc[MS_T3 + c] = b3[c] - m3[c] * s;
    s = gr[c] * rsqrtf(vr[c] + 1e-6f);
    misc[MS_SR + c] = s; misc[MS_TR + c] = br[c] - mr[c] * s;
    s = gl[c] * rsqrtf(vl[c] + 1e-5f);
    misc[MS_SL + c] = s; misc[MS_TL + c] = bl[c] - ml[c] * s;
  }
  if (t < 64) {
    float s = ge[t] * rsqrtf(ve[t] + 1e-5f);
    misc[MS_SE + t] = s; misc[MS_TE + t] = be[t] - me[t] * s;
    float acc = 0.f;
    for (int c = 0; c < 512; ++c) { float v = cw[t * 512 + c]; acc += v * v; }
    misc[MS_CSQ + t] = acc;
  }
}

// ---------------- fold weights -> bf16 ----------------
__global__ void fold_bf16_kernel(const float* __restrict__ w, const float* __restrict__ s,
                                 unsigned short* __restrict__ out, int total, int kper)
{
  int i = blockIdx.x * 256 + threadIdx.x;
  if (i < total) out[i] = f2b(w[i] * s[i / kper]);
}

__global__ void fold_w2_kernel(const float* __restrict__ w2, const float* __restrict__ s,
                               unsigned short* __restrict__ out)
{
  int j = blockIdx.x * 256 + threadIdx.x;
  if (j < 147456) {
    int m = j / 1152, r = j - m * 1152;
    int tp = r >> 7, ci = r & 127;
    out[j] = f2b(w2[m * 1152 + ci * 9 + tp] * s[m]);
  }
}

// ---------------- f32 NCHW (512 ch) -> bf16 NHWC ----------------
__global__ __launch_bounds__(256) void tr_kernel(const float* __restrict__ x,
                                                 unsigned short* __restrict__ xb)
{
  __shared__ float T[64][65];
  const int b = blockIdx.z, c0 = blockIdx.y * 64, n0 = blockIdx.x * 64;
  const int t = threadIdx.x;
  const int rr = t >> 4, cc = (t & 15) * 4;
#pragma unroll
  for (int rep = 0; rep < 4; ++rep) {
    const int cr = rep * 16 + rr;
    const float4 v = *(const float4*)(x + ((size_t)(b * 512 + c0 + cr)) * 4096 + n0 + cc);
    T[cr][cc + 0] = v.x; T[cr][cc + 1] = v.y; T[cr][cc + 2] = v.z; T[cr][cc + 3] = v.w;
  }
  __syncthreads();
#pragma unroll
  for (int rep = 0; rep < 4; ++rep) {
    const int nr = rep * 16 + rr;
    u16x4 o;
    o[0] = f2b(T[cc + 0][nr]); o[1] = f2b(T[cc + 1][nr]);
    o[2] = f2b(T[cc + 2][nr]); o[3] = f2b(T[cc + 3][nr]);
    *(u16x4*)(xb + ((size_t)(b * 4096 + n0 + nr)) * 512 + c0 + cc) = o;
  }
}

// ======== MFMA GEMM v2 (R11-verified) ========
template<int BMODE>
__device__ __forceinline__ void run_phase(
    const unsigned short* __restrict__ Wp,
    const unsigned short* __restrict__ Xb,
    const int K, const int tid, const int n0,
    unsigned short* __restrict__ As, unsigned short* __restrict__ Bs,
    f32x4 acc[4][4])
{
  const int lane = tid & 63;
  const int wv = tid >> 6, wm = wv >> 1, wn = wv & 1;

  const int ko = tid & 3;
  const int r0 = tid >> 2;
  const int r1 = 64 + r0;

  const unsigned short* aS0 = Wp + (size_t)r0 * K + ko * 8;
  const unsigned short* aS1 = Wp + (size_t)r1 * K + ko * 8;
  unsigned short* aD0 = As + (size_t)(((r0 >> 4) * 64) + ko * 16 + (r0 & 15)) * 8;
  unsigned short* aD1 = As + (size_t)(((r1 >> 4) * 64) + ko * 16 + (r1 & 15)) * 8;

  const unsigned short* bS0 = nullptr;
  const unsigned short* bS1 = nullptr;
  size_t bBase0 = 0, bBase1 = 0;
  if constexpr (BMODE == 0) {
    bS0 = Xb + (size_t)(n0 + r0) * K + ko * 8;
    bS1 = Xb + (size_t)(n0 + r1) * K + ko * 8;
  } else {
    const int pg0 = n0 + r0, pg1 = n0 + r1;
    bBase0 = (size_t)((pg0 >> 6) * 66 + (pg0 & 63)) * 128 + ko * 8;
    bBase1 = (size_t)((pg1 >> 6) * 66 + (pg1 & 63)) * 128 + ko * 8;
  }
  unsigned short* bD0 = Bs + (size_t)(((r0 >> 4) * 64) + ko * 16 + (r0 & 15)) * 8;
  unsigned short* bD1 = Bs + (size_t)(((r1 >> 4) * 64) + ko * 16 + (r1 & 15)) * 8;

  for (int kt = 0; kt < K; kt += 32) {
    s16x8 a0, a1, b0, b1;
    __builtin_memcpy(&a0, aS0 + kt, 16);
    __builtin_memcpy(&a1, aS1 + kt, 16);
    if constexpr (BMODE == 0) {
      __builtin_memcpy(&b0, bS0 + kt, 16);
      __builtin_memcpy(&b1, bS1 + kt, 16);
    } else {
      const int tap = kt >> 7;
      const int ky = tap / 3, kx = tap - ky * 3;
      const int off = (ky * 66 + kx) * 128 + (kt & 127);
      __builtin_memcpy(&b0, Xb + bBase0 + off, 16);
      __builtin_memcpy(&b1, Xb + bBase1 + off, 16);
    }
    __syncthreads();
    *(s16x8*)aD0 = a0; *(s16x8*)aD1 = a1;
    *(s16x8*)bD0 = b0; *(s16x8*)bD1 = b1;
    __syncthreads();

    s16x8 afr[4], bfr[4];
#pragma unroll
    for (int i = 0; i < 4; ++i)
      afr[i] = *(const s16x8*)(As + (size_t)((wm * 4 + i) * 64 + lane) * 8);
#pragma unroll
    for (int j = 0; j < 4; ++j)
      bfr[j] = *(const s16x8*)(Bs + (size_t)((wn * 4 + j) * 64 + lane) * 8);
#pragma unroll
    for (int i = 0; i < 4; ++i)
#pragma unroll
      for (int j = 0; j < 4; ++j)
        acc[i][j] = __builtin_amdgcn_mfma_f32_16x16x32_bf16(afr[i], bfr[j], acc[i][j], 0, 0, 0);
  }
}

template<int BMODE, bool DUAL>
__global__ __launch_bounds__(256) void mgemm_kernel(
    const unsigned short* __restrict__ W0, const unsigned short* __restrict__ X0,
    const int K0, const long long xbs0,
    const unsigned short* __restrict__ W1, const unsigned short* __restrict__ X1,
    const int Kp1, const long long xbs1,
    const float* __restrict__ biasMid, const float* __restrict__ biasOut,
    const int omode, const int reluF, const int ldm,
    unsigned short* __restrict__ outB, const long long obsB)
{
  __shared__ __align__(16) unsigned short smem[128 * EPAD];
  unsigned short* As = smem;
  unsigned short* Bs = smem + 4096;

  const int tid = threadIdx.x;
  const int b = blockIdx.z;
  const int n0 = blockIdx.x * 128;
  const int m0 = blockIdx.y * 128;
  const int lane = tid & 63, wv = tid >> 6, wm = wv >> 1, wn = wv & 1;
  const int q = lane >> 4, mm = lane & 15;

  f32x4 acc[4][4];
#pragma unroll
  for (int i = 0; i < 4; ++i)
#pragma unroll
    for (int j = 0; j < 4; ++j) acc[i][j] = (f32x4){0.f, 0.f, 0.f, 0.f};

  run_phase<BMODE>(W0 + (size_t)m0 * K0, X0 + (size_t)b * xbs0, K0, tid, n0, As, Bs, acc);

  if constexpr (DUAL) {
#pragma unroll
    for (int i = 0; i < 4; ++i) {
      const int mb = m0 + wm * 64 + i * 16 + q * 4;
#pragma unroll
      for (int r = 0; r < 4; ++r) {
        const float bm = biasMid[mb + r];
#pragma unroll
        for (int j = 0; j < 4; ++j) acc[i][j][r] = fmaxf(acc[i][j][r] + bm, 0.f);
      }
    }
    run_phase<0>(W1 + (size_t)m0 * Kp1, X1 + (size_t)b * xbs1, Kp1, tid, n0, As, Bs, acc);
  }

  __syncthreads();
  if (omode == 3) {
#pragma unroll
    for (int i = 0; i < 4; ++i) {
      const int chb = wm * 64 + i * 16 + q * 4;
#pragma unroll
      for (int r = 0; r < 4; ++r) {
        const float bo = biasOut[m0 + chb + r];
#pragma unroll
        for (int j = 0; j < 4; ++j) {
          const int px = wn * 64 + j * 16 + mm;
          float v = acc[i][j][r] + bo;
          if (reluF) v = fmaxf(v, 0.f);
          smem[(size_t)(chb + r) * EPAD + px] = f2b(v);
        }
      }
    }
    __syncthreads();
    const int ch = tid >> 1, half = tid & 1;
    const unsigned short* src = smem + (size_t)ch * EPAD + half * 64;
    unsigned short* dst = outB + (size_t)b * obsB + (size_t)(m0 + ch) * HW + n0 + half * 64;
#pragma unroll
    for (int r = 0; r < 8; ++r) {
      s16x8 v;
      __builtin_memcpy(&v, src + r * 8, 16);
      *(s16x8*)(dst + r * 8) = v;
    }
  } else {
#pragma unroll
    for (int i = 0; i < 4; ++i) {
      const int chb = wm * 64 + i * 16 + q * 4;
      float bo[4];
#pragma unroll
      for (int r = 0; r < 4; ++r) bo[r] = biasOut[m0 + chb + r];
#pragma unroll
      for (int j = 0; j < 4; ++j) {
        const int px = wn * 64 + j * 16 + mm;
        u16x4 o;
#pragma unroll
        for (int r = 0; r < 4; ++r) {
          float v = acc[i][j][r] + bo[r];
          if (reluF) v = fmaxf(v, 0.f);
          o[r] = f2b(v);
        }
        *(u16x4*)(smem + (size_t)px * EPAD + chb) = o;
      }
    }
    __syncthreads();
    const int px = tid >> 1, half = tid & 1;
    const unsigned short* src = smem + (size_t)px * EPAD + half * 64;
    size_t dstoff;
    if (omode == 1) {
      dstoff = (size_t)b * obsB + (size_t)(n0 + px) * ldm + m0 + half * 64;
    } else {
      const int hp = ((n0 + px) >> 6) + 1, wp = ((n0 + px) & 63) + 1;
      dstoff = (size_t)b * obsB + ((size_t)hp * 66 + wp) * 128 + m0 + half * 64;
    }
    unsigned short* dst = outB + dstoff;
#pragma unroll
    for (int r = 0; r < 8; ++r) {
      s16x8 v;
      __builtin_memcpy(&v, src + r * 8, 16);
      *(s16x8*)(dst + r * 8) = v;
    }
  }
}

// ---------------- assignment -> A as bf16 hi/lo planes ----------------
__global__ __launch_bounds__(256) void assign_kernel(
    const unsigned short* __restrict__ Yv, const float* __restrict__ cw, const float* __restrict__ scale,
    const float* __restrict__ misc, unsigned short* __restrict__ Ahi, unsigned short* __restrict__ Alo)
{
  __shared__ float Cs[16][64];
  __shared__ float Ys[16][64];
  __shared__ float dist[64][65];
  __shared__ float red[4][64];
  __shared__ float xsq[64];
  __shared__ float scl[64];
  __shared__ float csq[64];
  const int tid = threadIdx.x;
  const int b  = blockIdx.y;
  const int n0 = blockIdx.x * 64;
  if (tid < 64) { scl[tid] = scale[tid]; csq[tid] = misc[MS_CSQ + tid]; }
  const unsigned short* __restrict__ Yb = Yv + (size_t)b * CCH * HW;
  const int tr = tid >> 4, tc = tid & 15;
  const int lc_k = tid >> 2, lc_c = (tid & 3) * 4;
  const int ly_c0 = tid >> 6, ly_n = tid & 63;

  float acc[4][4];
#pragma unroll
  for (int i = 0; i < 4; ++i)
#pragma unroll
    for (int j = 0; j < 4; ++j) acc[i][j] = 0.f;
  float sq = 0.f;

  for (int c0 = 0; c0 < 512; c0 += 16) {
    const float4 cv = *(const float4*)(cw + (size_t)lc_k * 512 + c0 + lc_c);
    float yv[4];
#pragma unroll
    for (int rr = 0; rr < 4; ++rr)
      yv[rr] = b2f(Yb[(size_t)(c0 + ly_c0 + rr * 4) * HW + n0 + ly_n]);
    __syncthreads();
    Cs[lc_c + 0][lc_k] = cv.x;
    Cs[lc_c + 1][lc_k] = cv.y;
    Cs[lc_c + 2][lc_k] = cv.z;
    Cs[lc_c + 3][lc_k] = cv.w;
#pragma unroll
    for (int rr = 0; rr < 4; ++rr) {
      Ys[ly_c0 + rr * 4][ly_n] = yv[rr];
      sq += yv[rr] * yv[rr];
    }
    __syncthreads();
#pragma unroll
    for (int ct = 0; ct < 16; ++ct) {
      float rk[4], rn[4];
#pragma unroll
      for (int i = 0; i < 4; ++i) rk[i] = Cs[ct][tr * 4 + i];
#pragma unroll
      for (int j = 0; j < 4; ++j) rn[j] = Ys[ct][tc * 4 + j];
#pragma unroll
      for (int i = 0; i < 4; ++i)
#pragma unroll
        for (int j = 0; j < 4; ++j) acc[i][j] += rk[i] * rn[j];
    }
  }
  __syncthreads();
  red[ly_c0][ly_n] = sq;
  __syncthreads();
  if (tid < 64) xsq[tid] = red[0][tid] + red[1][tid] + red[2][tid] + red[3][tid];
  __syncthreads();
#pragma unroll
  for (int i = 0; i < 4; ++i)
#pragma unroll
    for (int j = 0; j < 4; ++j) {
      const int k = tr * 4 + i, n = tc * 4 + j;
      dist[k][n] = scl[k] * (xsq[n] - 2.f * acc[i][j] + csq[k]);
    }
  __syncthreads();
  const int qq = tid >> 6, n = tid & 63;
  float mx = -3.0e38f;
#pragma unroll
  for (int kk = 0; kk < 16; ++kk) mx = fmaxf(mx, dist[qq * 16 + kk][n]);
  red[qq][n] = mx;
  __syncthreads();
  mx = fmaxf(fmaxf(red[0][n], red[1][n]), fmaxf(red[2][n], red[3][n]));
  __syncthreads();
  float sum = 0.f;
#pragma unroll
  for (int kk = 0; kk < 16; ++kk) {
    const float e = __expf(dist[qq * 16 + kk][n] - mx);
    dist[qq * 16 + kk][n] = e;
    sum += e;
  }
  red[qq][n] = sum;
  __syncthreads();
  sum = red[0][n] + red[1][n] + red[2][n] + red[3][n];
  const float inv = 1.f / sum;
  const size_t base = (size_t)b * NK * HW + n0 + n;
#pragma unroll
  for (int kk = 0; kk < 16; ++kk) {
    const float a = dist[qq * 16 + kk][n] * inv;
    const unsigned short hi = f2b(a);
    const float rem = a - b2f(hi);
    Ahi[base + (size_t)(qq * 16 + kk) * HW] = hi;
    Alo[base + (size_t)(qq * 16 + kk) * HW] = f2b(rem);
  }
}

// ---------------- asum from hi/lo planes ----------------
__global__ void asum_kernel(const unsigned short* __restrict__ Ahi,
                            const unsigned short* __restrict__ Alo, float* __restrict__ asum)
{
  const int bk = blockIdx.x;
  const unsigned short* __restrict__ rh = Ahi + (size_t)bk * HW;
  const unsigned short* __restrict__ rl = Alo + (size_t)bk * HW;
  const int t = threadIdx.x;
  float p = 0.f;
  for (int i = t * 8; i < HW; i += 2048) {
    s16x8 h, l;
    __builtin_memcpy(&h, rh + i, 16);
    __builtin_memcpy(&l, rl + i, 16);
#pragma unroll
    for (int e = 0; e < 8; ++e)
      p += b2f((unsigned short)h[e]) + b2f((unsigned short)l[e]);
  }
  __shared__ float sm[256];
  sm[t] = p;
  __syncthreads();
  for (int s = 128; s > 0; s >>= 1) {
    if (t < s) sm[t] += sm[t + s];
    __syncthreads();
  }
  if (t == 0) asum[bk] = sm[0];
}

// ---------------- enc via MFMA: pe[b][nc][k][c] = sum_n (Ahi+Alo)[k][n] * y[c][n] ----------------
// Tile: 64 k-rows x 128 c-cols, contraction = 1024 pixels (chunk nc).
// Slot contract (R11-verified): chunk (r,ko) -> slot (r>>4)*64 + ko*16 + (r&15);
// fragment read = contiguous 16B at slot (f*64 + lane).
__global__ __launch_bounds__(256) void enc_mfma_kernel(
    const unsigned short* __restrict__ Ahi, const unsigned short* __restrict__ Alo,
    const unsigned short* __restrict__ Yv, float* __restrict__ pe)
{
  __shared__ __align__(16) unsigned short AHs[2048];  // 64 rows x 32 px
  __shared__ __align__(16) unsigned short ALs[2048];
  __shared__ __align__(16) unsigned short Bs[4096];   // 128 c x 32 px
  const int tid = threadIdx.x;
  const int ncol = blockIdx.x, nc = blockIdx.y, b = blockIdx.z;
  const int lane = tid & 63, wv = tid >> 6;
  const int q = lane >> 4, mm = lane & 15;

  const int ko = tid & 3;
  const int r  = tid >> 2;                 // 0..63
  const size_t aoff = ((size_t)b * NK + r) * HW + nc * 1024 + ko * 8;
  const unsigned short* ahS = Ahi + aoff;
  const unsigned short* alS = Alo + aoff;
  const int slotA = (((r >> 4) * 64) + ko * 16 + (r & 15)) * 8;
  const unsigned short* b0S = Yv + ((size_t)b * CCH + ncol * 128 + r) * HW + nc * 1024 + ko * 8;
  const unsigned short* b1S = b0S + (size_t)64 * HW;
  const int slotB0 = (((r >> 4) * 64) + ko * 16 + (r & 15)) * 8;
  const int slotB1 = ((((r + 64) >> 4) * 64) + ko * 16 + (r & 15)) * 8;

  f32x4 acc[4][2];
#pragma unroll
  for (int i = 0; i < 4; ++i)
#pragma unroll
    for (int j = 0; j < 2; ++j) acc[i][j] = (f32x4){0.f, 0.f, 0.f, 0.f};

  for (int kt = 0; kt < 1024; kt += 32) {
    s16x8 ah, al, y0, y1;
    __builtin_memcpy(&ah, ahS + kt, 16);
    __builtin_memcpy(&al, alS + kt, 16);
    __builtin_memcpy(&y0, b0S + kt, 16);
    __builtin_memcpy(&y1, b1S + kt, 16);
    __syncthreads();
    *(s16x8*)(AHs + slotA) = ah;
    *(s16x8*)(ALs + slotA) = al;
    *(s16x8*)(Bs + slotB0) = y0;
    *(s16x8*)(Bs + slotB1) = y1;
    __syncthreads();

    s16x8 afh[4], afl[4], bfr[2];
#pragma unroll
    for (int i = 0; i < 4; ++i) {
      afh[i] = *(const s16x8*)(AHs + (size_t)(i * 64 + lane) * 8);
      afl[i] = *(const s16x8*)(ALs + (size_t)(i * 64 + lane) * 8);
    }
#pragma unroll
    for (int j = 0; j < 2; ++j)
      bfr[j] = *(const s16x8*)(Bs + (size_t)((wv * 2 + j) * 64 + lane) * 8);
#pragma unroll
    for (int i = 0; i < 4; ++i)
#pragma unroll
      for (int j = 0; j < 2; ++j) {
        acc[i][j] = __builtin_amdgcn_mfma_f32_16x16x32_bf16(afh[i], bfr[j], acc[i][j], 0, 0, 0);
        acc[i][j] = __builtin_amdgcn_mfma_f32_16x16x32_bf16(afl[i], bfr[j], acc[i][j], 0, 0, 0);
      }
  }

  // epilogue: k = i*16 + q*4 + rr, c = ncol*128 + (wv*2+j)*16 + mm  (C/D map HW-verified)
  float* __restrict__ peb = pe + ((size_t)(b * 4 + nc) * NK) * CCH;
#pragma unroll
  for (int i = 0; i < 4; ++i)
#pragma unroll
    for (int j = 0; j < 2; ++j) {
      const int c = ncol * 128 + (wv * 2 + j) * 16 + mm;
#pragma unroll
      for (int rr = 0; rr < 4; ++rr) {
        const int k = i * 16 + q * 4 + rr;
        peb[(size_t)k * CCH + c] = acc[i][j][rr];
      }
    }
}

// ---------------- en + gate ----------------
__global__ __launch_bounds__(256) void engate_kernel(
    const float* __restrict__ pe, const float* __restrict__ asum, const float* __restrict__ cw,
    const float* __restrict__ misc, const float* __restrict__ wfc, const float* __restrict__ bfc,
    float* __restrict__ gam)
{
  const int b = blockIdx.x;
  const int t = threadIdx.x;
  __shared__ float asum_s[64], se_s[64], te_s[64];
  __shared__ __align__(16) float en_s[512];
  if (t < 64) {
    asum_s[t] = asum[b * 64 + t];
    se_s[t]   = misc[MS_SE + t];
    te_s[t]   = misc[MS_TE + t];
  }
  __syncthreads();
  for (int rep = 0; rep < 2; ++rep) {
    const int c = t + rep * 256;
    float en = 0.f;
    const float* __restrict__ peb = pe + (size_t)b * 4 * NK * CCH + c;
    for (int k = 0; k < 64; ++k) {
      const float ps = peb[(size_t)k * CCH] + peb[(size_t)(64 + k) * CCH] +
                       peb[(size_t)(128 + k) * CCH] + peb[(size_t)(192 + k) * CCH];
      float v = ps - asum_s[k] * cw[k * 512 + c];
      v = v * se_s[k] + te_s[k];
      en += fmaxf(v, 0.f);
    }
    en_s[c] = en * (1.f / 64.f);
  }
  __syncthreads();
  for (int rep = 0; rep < 2; ++rep) {
    const int i = t + rep * 256;
    float a = bfc[i];
    const float4* __restrict__ wrow = (const float4*)(wfc + (size_t)i * 512);
    const float4* __restrict__ ev = (const float4*)en_s;
    for (int j = 0; j < 128; ++j) {
      const float4 w4 = wrow[j];
      const float4 e4 = ev[j];
      a += w4.x * e4.x + w4.y * e4.y + w4.z * e4.z + w4.w * e4.w;
    }
    gam[b * 512 + i] = 1.f / (1.f + __expf(-a));
  }
}

// ---------------- fingate ----------------
__global__ __launch_bounds__(256) void fingate_kernel(
    const unsigned short* __restrict__ x1b, const float* __restrict__ gam,
    float* __restrict__ out)
{
  __shared__ float T[64][65];
  const int b = blockIdx.z, c0 = blockIdx.y * 64, n0 = blockIdx.x * 64;
  const int t = threadIdx.x;
  const int rr = t >> 4, cc = (t & 15) * 4;
#pragma unroll
  for (int rep = 0; rep < 4; ++rep) {
    const int pr = rep * 16 + rr;
    u16x4 v = *(const u16x4*)(x1b + ((size_t)(b * 4096 + n0 + pr)) * 512 + c0 + cc);
    T[cc + 0][pr] = b2f(v[0]);
    T[cc + 1][pr] = b2f(v[1]);
    T[cc + 2][pr] = b2f(v[2]);
    T[cc + 3][pr] = b2f(v[3]);
  }
  __syncthreads();
#pragma unroll
  for (int rep = 0; rep < 4; ++rep) {
    const int cr = rep * 16 + rr;
    const float g = 1.f + gam[b * 512 + c0 + cr];
    float4 o;
    o.x = fmaxf(T[cr][cc + 0] * g, 0.f);
    o.y = fmaxf(T[cr][cc + 1] * g, 0.f);
    o.z = fmaxf(T[cr][cc + 2] * g, 0.f);
    o.w = fmaxf(T[cr][cc + 3] * g, 0.f);
    *(float4*)(out + ((size_t)(b * 512 + c0 + cr)) * 4096 + n0 + cc) = o;
  }
}

extern "C" void kernel_launch(void* const* d_in, const int* in_sizes, int n_in,
                              void* d_out, int out_size, void* d_ws, size_t ws_size,
                              hipStream_t stream)
{
  const float* x  = (const float*)d_in[0];
  const float* w1 = (const float*)d_in[1];
  const float* g1 = (const float*)d_in[2];
  const float* b1 = (const float*)d_in[3];
  const float* m1 = (const float*)d_in[4];
  const float* v1 = (const float*)d_in[5];
  const float* w2 = (const float*)d_in[6];
  const float* g2 = (const float*)d_in[7];
  const float* b2 = (const float*)d_in[8];
  const float* m2 = (const float*)d_in[9];
  const float* v2 = (const float*)d_in[10];
  const float* w3 = (const float*)d_in[11];
  const float* g3 = (const float*)d_in[12];
  const float* b3 = (const float*)d_in[13];
  const float* m3 = (const float*)d_in[14];
  const float* v3 = (const float*)d_in[15];
  const float* wr = (const float*)d_in[16];
  const float* gr = (const float*)d_in[17];
  const float* br = (const float*)d_in[18];
  const float* mr = (const float*)d_in[19];
  const float* vr = (const float*)d_in[20];
  const float* wl = (const float*)d_in[21];
  const float* gl = (const float*)d_in[22];
  const float* bl = (const float*)d_in[23];
  const float* ml = (const float*)d_in[24];
  const float* vl = (const float*)d_in[25];
  const float* cw = (const float*)d_in[26];
  const float* scale = (const float*)d_in[27];
  const float* ge = (const float*)d_in[28];
  const float* be = (const float*)d_in[29];
  const float* me = (const float*)d_in[30];
  const float* ve = (const float*)d_in[31];
  const float* wfc = (const float*)d_in[32];
  const float* bfc = (const float*)d_in[33];

  char* wsb = (char*)d_ws;
  unsigned short* xb  = (unsigned short*)(wsb + C_XB);
  unsigned short* h2  = (unsigned short*)(wsb + C_H2);
  unsigned short* h1p = (unsigned short*)(wsb + C_H1P);
  unsigned short* x1b = (unsigned short*)(wsb + C_X1B);
  unsigned short* yb  = (unsigned short*)(wsb + C_YB);
  unsigned short* Ahi = (unsigned short*)(wsb + C_AHI);
  unsigned short* Alo = (unsigned short*)(wsb + C_ALO);
  float* pe   = (float*)(wsb + C_PE);
  float* asum = (float*)(wsb + C_ASUM);
  float* gam  = (float*)(wsb + C_GAM);
  float* misc = (float*)(wsb + C_MISC);
  unsigned short* w1f = (unsigned short*)(wsb + C_W1F);
  unsigned short* w2f = (unsigned short*)(wsb + C_W2F);
  unsigned short* w3b = (unsigned short*)(wsb + C_W3B);
  unsigned short* wrb = (unsigned short*)(wsb + C_WRB);
  unsigned short* wlb = (unsigned short*)(wsb + C_WLB);

  prep_kernel<<<1, 256, 0, stream>>>(g1, b1, m1, v1, g2, b2, m2, v2, g3, b3, m3, v3,
                                     gr, br, mr, vr, gl, bl, ml, vl, ge, be, me, ve,
                                     cw, misc);
  fold_bf16_kernel<<<256, 256, 0, stream>>>(w1, misc + MS_S1, w1f, 65536, 512);
  fold_w2_kernel<<<576, 256, 0, stream>>>(w2, misc + MS_S2, w2f);
  fold_bf16_kernel<<<256, 256, 0, stream>>>(w3, misc + MS_S3, w3b, 65536, 128);
  fold_bf16_kernel<<<1024, 256, 0, stream>>>(wr, misc + MS_SR, wrb, 262144, 512);
  fold_bf16_kernel<<<1024, 256, 0, stream>>>(wl, misc + MS_SL, wlb, 262144, 512);

  tr_kernel<<<dim3(64, 8, 16), 256, 0, stream>>>(x, xb);
  hipMemsetAsync(h1p, 0, 17842176, stream);

  mgemm_kernel<0, false><<<dim3(32, 1, 16), 256, 0, stream>>>(
      w1f, xb, 512, 4096LL * 512, nullptr, nullptr, 0, 0,
      nullptr, misc + MS_T1, 0, 1, 128, h1p, 4356LL * 128);
  mgemm_kernel<1, false><<<dim3(32, 1, 16), 256, 0, stream>>>(
      w2f, h1p, 1152, 4356LL * 128, nullptr, nullptr, 0, 0,
      nullptr, misc + MS_T2, 1, 1, 128, h2, 4096LL * 128);
  mgemm_kernel<0, true><<<dim3(32, 4, 16), 256, 0, stream>>>(
      w3b, h2, 128, 4096LL * 128, wrb, xb, 512, 4096LL * 512,
      misc + MS_T3, misc + MS_TR, 1, 0, 512, x1b, 4096LL * 512);
  mgemm_kernel<0, false><<<dim3(32, 4, 16), 256, 0, stream>>>(
      wlb, x1b, 512, 4096LL * 512, nullptr, nullptr, 0, 0,
      nullptr, misc + MS_TL, 3, 1, 0, yb, 512LL * 4096);

  assign_kernel<<<dim3(64, 16), 256, 0, stream>>>(yb, cw, scale, misc, Ahi, Alo);
  asum_kernel<<<1024, 256, 0, stream>>>(Ahi, Alo, asum);
  enc_mfma_kernel<<<dim3(4, 4, 16), 256, 0, stream>>>(Ahi, Alo, yb, pe);
  engate_kernel<<<16, 256, 0, stream>>>(pe, asum, cw, misc, wfc, bfc, gam);
  fingate_kernel<<<dim3(64, 8, 16), 256, 0, stream>>>(x1b, gam, (float*)d_out);
}

// Round 13
// 461.197 us; speedup vs baseline: 2.8729x; 1.0474x over previous
//
#include <hip/hip_runtime.h>
#include <math.h>

typedef float f32x4 __attribute__((ext_vector_type(4)));
typedef short s16x8 __attribute__((ext_vector_type(8)));
typedef unsigned short u16x4 __attribute__((ext_vector_type(4)));

#define HW 4096
#define CCH 512
#define NK 64
#define EPAD 136   // epilogue LDS row pitch (ushorts)

// ---- ws layout (BYTE offsets) — SIZE-AUDITED ----
#define C_XB   0ULL
#define C_H2   67108864ULL
#define C_H1P  83886080ULL
#define C_X1B  83886080ULL
#define C_YB   0ULL
#define C_AHI  67108864ULL
#define C_ALO  75497472ULL
#define C_ASUM 150994944ULL
#define C_GAM  150999040ULL
#define C_MISC 151031808ULL
#define C_W1F  151048192ULL
#define C_W2F  151179264ULL
#define C_W3B  151474176ULL
#define C_WRB  151605248ULL
#define C_WLB  152129536ULL
#define C_PE   152653824ULL    // -> end 161,042,432

#define MS_S1 0
#define MS_T1 128
#define MS_S2 256
#define MS_T2 384
#define MS_S3 512
#define MS_T3 1024
#define MS_SR 1536
#define MS_TR 2048
#define MS_SL 2560
#define MS_TL 3072
#define MS_SE 3584
#define MS_TE 3648
#define MS_CSQ 3712

__device__ __forceinline__ float b2f(unsigned short u) {
  unsigned int x = ((unsigned int)u) << 16;
  return __builtin_bit_cast(float, x);
}
__device__ __forceinline__ unsigned short f2b(float f) {
  unsigned int i = __builtin_bit_cast(unsigned int, f);
  i += 0x7fffu + ((i >> 16) & 1u);
  return (unsigned short)(i >> 16);
}

// ---------------- prep ----------------
__global__ void prep_kernel(
    const float* __restrict__ g1, const float* __restrict__ b1, const float* __restrict__ m1, const float* __restrict__ v1,
    const float* __restrict__ g2, const float* __restrict__ b2, const float* __restrict__ m2, const float* __restrict__ v2,
    const float* __restrict__ g3, const float* __restrict__ b3, const float* __restrict__ m3, const float* __restrict__ v3,
    const float* __restrict__ gr, const float* __restrict__ br, const float* __restrict__ mr, const float* __restrict__ vr,
    const float* __restrict__ gl, const float* __restrict__ bl, const float* __restrict__ ml, const float* __restrict__ vl,
    const float* __restrict__ ge, const float* __restrict__ be, const float* __restrict__ me, const float* __restrict__ ve,
    const float* __restrict__ cw, float* __restrict__ misc)
{
  const int t = threadIdx.x;
  if (t < 128) {
    float s = g1[t] * rsqrtf(v1[t] + 1e-6f);
    misc[MS_S1 + t] = s; misc[MS_T1 + t] = b1[t] - m1[t] * s;
    s = g2[t] * rsqrtf(v2[t] + 1e-6f);
    misc[MS_S2 + t] = s; misc[MS_T2 + t] = b2[t] - m2[t] * s;
  }
  for (int c = t; c < 512; c += 256) {
    float s = g3[c] * rsqrtf(v3[c] + 1e-6f);
    misc[MS_S3 + c] = s; misc[MS_T3 + c] = b3[c] - m3[c] * s;
    s = gr[c] * rsqrtf(vr[c] + 1e-6f);
    misc[MS_SR + c] = s; misc[MS_TR + c] = br[c] - mr[c] * s;
    s = gl[c] * rsqrtf(vl[c] + 1e-5f);
    misc[MS_SL + c] = s; misc[MS_TL + c] = bl[c] - ml[c] * s;
  }
  if (t < 64) {
    float s = ge[t] * rsqrtf(ve[t] + 1e-5f);
    misc[MS_SE + t] = s; misc[MS_TE + t] = be[t] - me[t] * s;
    float acc = 0.f;
    for (int c = 0; c < 512; ++c) { float v = cw[t * 512 + c]; acc += v * v; }
    misc[MS_CSQ + t] = acc;
  }
}

// ---------------- fold weights -> bf16 ----------------
__global__ void fold_bf16_kernel(const float* __restrict__ w, const float* __restrict__ s,
                                 unsigned short* __restrict__ out, int total, int kper)
{
  int i = blockIdx.x * 256 + threadIdx.x;
  if (i < total) out[i] = f2b(w[i] * s[i / kper]);
}

__global__ void fold_w2_kernel(const float* __restrict__ w2, const float* __restrict__ s,
                               unsigned short* __restrict__ out)
{
  int j = blockIdx.x * 256 + threadIdx.x;
  if (j < 147456) {
    int m = j / 1152, r = j - m * 1152;
    int tp = r >> 7, ci = r & 127;
    out[j] = f2b(w2[m * 1152 + ci * 9 + tp] * s[m]);
  }
}

// ---------------- f32 NCHW (512 ch) -> bf16 NHWC ----------------
__global__ __launch_bounds__(256) void tr_kernel(const float* __restrict__ x,
                                                 unsigned short* __restrict__ xb)
{
  __shared__ float T[64][65];
  const int b = blockIdx.z, c0 = blockIdx.y * 64, n0 = blockIdx.x * 64;
  const int t = threadIdx.x;
  const int rr = t >> 4, cc = (t & 15) * 4;
#pragma unroll
  for (int rep = 0; rep < 4; ++rep) {
    const int cr = rep * 16 + rr;
    const float4 v = *(const float4*)(x + ((size_t)(b * 512 + c0 + cr)) * 4096 + n0 + cc);
    T[cr][cc + 0] = v.x; T[cr][cc + 1] = v.y; T[cr][cc + 2] = v.z; T[cr][cc + 3] = v.w;
  }
  __syncthreads();
#pragma unroll
  for (int rep = 0; rep < 4; ++rep) {
    const int nr = rep * 16 + rr;
    u16x4 o;
    o[0] = f2b(T[cc + 0][nr]); o[1] = f2b(T[cc + 1][nr]);
    o[2] = f2b(T[cc + 2][nr]); o[3] = f2b(T[cc + 3][nr]);
    *(u16x4*)(xb + ((size_t)(b * 4096 + n0 + nr)) * 512 + c0 + cc) = o;
  }
}

// ======== MFMA GEMM v3: double-buffered LDS, 1 barrier per K-step (T3-lite) ========
// Fragment-slot contract (R11-verified): slot s (16B) holds T[row=(s>>6)*16+(s&15)][k=((s>>4)&3)*8..+8].
// Per step: issue global loads for kt+32 | MFMA from buf[cur] | ds_write buf[cur^1] | barrier.
// As/Bs are each TWO 4096-short (8KB) buffers.

template<int BMODE>
__device__ __forceinline__ void run_phase(
    const unsigned short* __restrict__ Wp,
    const unsigned short* __restrict__ Xb,
    const int K, const int tid, const int n0,
    unsigned short* __restrict__ As, unsigned short* __restrict__ Bs,
    f32x4 acc[4][4])
{
  const int lane = tid & 63;
  const int wv = tid >> 6, wm = wv >> 1, wn = wv & 1;

  const int ko = tid & 3;
  const int r0 = tid >> 2;
  const int r1 = 64 + r0;

  const unsigned short* aS0 = Wp + (size_t)r0 * K + ko * 8;
  const unsigned short* aS1 = Wp + (size_t)r1 * K + ko * 8;
  const int slot0 = (((r0 >> 4) * 64) + ko * 16 + (r0 & 15)) * 8;
  const int slot1 = (((r1 >> 4) * 64) + ko * 16 + (r1 & 15)) * 8;

  const unsigned short* bS0 = nullptr;
  const unsigned short* bS1 = nullptr;
  size_t bBase0 = 0, bBase1 = 0;
  if constexpr (BMODE == 0) {
    bS0 = Xb + (size_t)(n0 + r0) * K + ko * 8;
    bS1 = Xb + (size_t)(n0 + r1) * K + ko * 8;
  } else {
    const int pg0 = n0 + r0, pg1 = n0 + r1;
    bBase0 = (size_t)((pg0 >> 6) * 66 + (pg0 & 63)) * 128 + ko * 8;
    bBase1 = (size_t)((pg1 >> 6) * 66 + (pg1 & 63)) * 128 + ko * 8;
  }

  s16x8 a0, a1, b0, b1;
  auto LOADC = [&](int kt) {
    __builtin_memcpy(&a0, aS0 + kt, 16);
    __builtin_memcpy(&a1, aS1 + kt, 16);
    if constexpr (BMODE == 0) {
      __builtin_memcpy(&b0, bS0 + kt, 16);
      __builtin_memcpy(&b1, bS1 + kt, 16);
    } else {
      const int tap = kt >> 7;                 // k = tap*128 + ci; 32-chunks never cross taps
      const int ky = tap / 3, kx = tap - ky * 3;
      const int off = (ky * 66 + kx) * 128 + (kt & 127);
      __builtin_memcpy(&b0, Xb + bBase0 + off, 16);
      __builtin_memcpy(&b1, Xb + bBase1 + off, 16);
    }
  };

  // prologue: stage chunk 0 into buf 0
  LOADC(0);
  *(s16x8*)(As + slot0) = a0; *(s16x8*)(As + slot1) = a1;
  *(s16x8*)(Bs + slot0) = b0; *(s16x8*)(Bs + slot1) = b1;
  __syncthreads();

  int cur = 0;
  for (int kt = 0; kt < K; kt += 32) {
    const bool more = (kt + 32) < K;
    if (more) LOADC(kt + 32);

    const unsigned short* Ac = As + cur * 4096;
    const unsigned short* Bc = Bs + cur * 4096;
    s16x8 afr[4], bfr[4];
#pragma unroll
    for (int i = 0; i < 4; ++i)
      afr[i] = *(const s16x8*)(Ac + (size_t)((wm * 4 + i) * 64 + lane) * 8);
#pragma unroll
    for (int j = 0; j < 4; ++j)
      bfr[j] = *(const s16x8*)(Bc + (size_t)((wn * 4 + j) * 64 + lane) * 8);
#pragma unroll
    for (int i = 0; i < 4; ++i)
#pragma unroll
      for (int j = 0; j < 4; ++j)
        acc[i][j] = __builtin_amdgcn_mfma_f32_16x16x32_bf16(afr[i], bfr[j], acc[i][j], 0, 0, 0);

    if (more) {
      const int nx = (cur ^ 1) * 4096;
      *(s16x8*)(As + nx + slot0) = a0; *(s16x8*)(As + nx + slot1) = a1;
      *(s16x8*)(Bs + nx + slot0) = b0; *(s16x8*)(Bs + nx + slot1) = b1;
    }
    __syncthreads();
    cur ^= 1;
  }
}

template<int BMODE, bool DUAL>
__global__ __launch_bounds__(256) void mgemm_kernel(
    const unsigned short* __restrict__ W0, const unsigned short* __restrict__ X0,
    const int K0, const long long xbs0,
    const unsigned short* __restrict__ W1, const unsigned short* __restrict__ X1,
    const int Kp1, const long long xbs1,
    const float* __restrict__ biasMid, const float* __restrict__ biasOut,
    const int omode, const int reluF, const int ldm,
    unsigned short* __restrict__ outB, const long long obsB)
{
  __shared__ __align__(16) unsigned short smem[128 * EPAD];  // 34,816B; staging = first 32KB
  unsigned short* As = smem;          // 2 x 4096 shorts
  unsigned short* Bs = smem + 8192;   // 2 x 4096 shorts

  const int tid = threadIdx.x;
  const int b = blockIdx.z;
  const int n0 = blockIdx.x * 128;
  const int m0 = blockIdx.y * 128;
  const int lane = tid & 63, wv = tid >> 6, wm = wv >> 1, wn = wv & 1;
  const int q = lane >> 4, mm = lane & 15;

  f32x4 acc[4][4];
#pragma unroll
  for (int i = 0; i < 4; ++i)
#pragma unroll
    for (int j = 0; j < 4; ++j) acc[i][j] = (f32x4){0.f, 0.f, 0.f, 0.f};

  run_phase<BMODE>(W0 + (size_t)m0 * K0, X0 + (size_t)b * xbs0, K0, tid, n0, As, Bs, acc);

  if constexpr (DUAL) {
#pragma unroll
    for (int i = 0; i < 4; ++i) {
      const int mb = m0 + wm * 64 + i * 16 + q * 4;
#pragma unroll
      for (int r = 0; r < 4; ++r) {
        const float bm = biasMid[mb + r];
#pragma unroll
        for (int j = 0; j < 4; ++j) acc[i][j][r] = fmaxf(acc[i][j][r] + bm, 0.f);
      }
    }
    run_phase<0>(W1 + (size_t)m0 * Kp1, X1 + (size_t)b * xbs1, Kp1, tid, n0, As, Bs, acc);
  }

  __syncthreads();
  if (omode == 3) {
#pragma unroll
    for (int i = 0; i < 4; ++i) {
      const int chb = wm * 64 + i * 16 + q * 4;
#pragma unroll
      for (int r = 0; r < 4; ++r) {
        const float bo = biasOut[m0 + chb + r];
#pragma unroll
        for (int j = 0; j < 4; ++j) {
          const int px = wn * 64 + j * 16 + mm;
          float v = acc[i][j][r] + bo;
          if (reluF) v = fmaxf(v, 0.f);
          smem[(size_t)(chb + r) * EPAD + px] = f2b(v);
        }
      }
    }
    __syncthreads();
    const int ch = tid >> 1, half = tid & 1;
    const unsigned short* src = smem + (size_t)ch * EPAD + half * 64;
    unsigned short* dst = outB + (size_t)b * obsB + (size_t)(m0 + ch) * HW + n0 + half * 64;
#pragma unroll
    for (int r = 0; r < 8; ++r) {
      s16x8 v;
      __builtin_memcpy(&v, src + r * 8, 16);
      *(s16x8*)(dst + r * 8) = v;
    }
  } else {
#pragma unroll
    for (int i = 0; i < 4; ++i) {
      const int chb = wm * 64 + i * 16 + q * 4;
      float bo[4];
#pragma unroll
      for (int r = 0; r < 4; ++r) bo[r] = biasOut[m0 + chb + r];
#pragma unroll
      for (int j = 0; j < 4; ++j) {
        const int px = wn * 64 + j * 16 + mm;
        u16x4 o;
#pragma unroll
        for (int r = 0; r < 4; ++r) {
          float v = acc[i][j][r] + bo[r];
          if (reluF) v = fmaxf(v, 0.f);
          o[r] = f2b(v);
        }
        *(u16x4*)(smem + (size_t)px * EPAD + chb) = o;
      }
    }
    __syncthreads();
    const int px = tid >> 1, half = tid & 1;
    const unsigned short* src = smem + (size_t)px * EPAD + half * 64;
    size_t dstoff;
    if (omode == 1) {
      dstoff = (size_t)b * obsB + (size_t)(n0 + px) * ldm + m0 + half * 64;
    } else {
      const int hp = ((n0 + px) >> 6) + 1, wp = ((n0 + px) & 63) + 1;
      dstoff = (size_t)b * obsB + ((size_t)hp * 66 + wp) * 128 + m0 + half * 64;
    }
    unsigned short* dst = outB + dstoff;
#pragma unroll
    for (int r = 0; r < 8; ++r) {
      s16x8 v;
      __builtin_memcpy(&v, src + r * 8, 16);
      *(s16x8*)(dst + r * 8) = v;
    }
  }
}

// ---------------- assignment -> A as bf16 hi/lo planes ----------------
__global__ __launch_bounds__(256) void assign_kernel(
    const unsigned short* __restrict__ Yv, const float* __restrict__ cw, const float* __restrict__ scale,
    const float* __restrict__ misc, unsigned short* __restrict__ Ahi, unsigned short* __restrict__ Alo)
{
  __shared__ float Cs[16][64];
  __shared__ float Ys[16][64];
  __shared__ float dist[64][65];
  __shared__ float red[4][64];
  __shared__ float xsq[64];
  __shared__ float scl[64];
  __shared__ float csq[64];
  const int tid = threadIdx.x;
  const int b  = blockIdx.y;
  const int n0 = blockIdx.x * 64;
  if (tid < 64) { scl[tid] = scale[tid]; csq[tid] = misc[MS_CSQ + tid]; }
  const unsigned short* __restrict__ Yb = Yv + (size_t)b * CCH * HW;
  const int tr = tid >> 4, tc = tid & 15;
  const int lc_k = tid >> 2, lc_c = (tid & 3) * 4;
  const int ly_c0 = tid >> 6, ly_n = tid & 63;

  float acc[4][4];
#pragma unroll
  for (int i = 0; i < 4; ++i)
#pragma unroll
    for (int j = 0; j < 4; ++j) acc[i][j] = 0.f;
  float sq = 0.f;

  for (int c0 = 0; c0 < 512; c0 += 16) {
    const float4 cv = *(const float4*)(cw + (size_t)lc_k * 512 + c0 + lc_c);
    float yv[4];
#pragma unroll
    for (int rr = 0; rr < 4; ++rr)
      yv[rr] = b2f(Yb[(size_t)(c0 + ly_c0 + rr * 4) * HW + n0 + ly_n]);
    __syncthreads();
    Cs[lc_c + 0][lc_k] = cv.x;
    Cs[lc_c + 1][lc_k] = cv.y;
    Cs[lc_c + 2][lc_k] = cv.z;
    Cs[lc_c + 3][lc_k] = cv.w;
#pragma unroll
    for (int rr = 0; rr < 4; ++rr) {
      Ys[ly_c0 + rr * 4][ly_n] = yv[rr];
      sq += yv[rr] * yv[rr];
    }
    __syncthreads();
#pragma unroll
    for (int ct = 0; ct < 16; ++ct) {
      float rk[4], rn[4];
#pragma unroll
      for (int i = 0; i < 4; ++i) rk[i] = Cs[ct][tr * 4 + i];
#pragma unroll
      for (int j = 0; j < 4; ++j) rn[j] = Ys[ct][tc * 4 + j];
#pragma unroll
      for (int i = 0; i < 4; ++i)
#pragma unroll
        for (int j = 0; j < 4; ++j) acc[i][j] += rk[i] * rn[j];
    }
  }
  __syncthreads();
  red[ly_c0][ly_n] = sq;
  __syncthreads();
  if (tid < 64) xsq[tid] = red[0][tid] + red[1][tid] + red[2][tid] + red[3][tid];
  __syncthreads();
#pragma unroll
  for (int i = 0; i < 4; ++i)
#pragma unroll
    for (int j = 0; j < 4; ++j) {
      const int k = tr * 4 + i, n = tc * 4 + j;
      dist[k][n] = scl[k] * (xsq[n] - 2.f * acc[i][j] + csq[k]);
    }
  __syncthreads();
  const int qq = tid >> 6, n = tid & 63;
  float mx = -3.0e38f;
#pragma unroll
  for (int kk = 0; kk < 16; ++kk) mx = fmaxf(mx, dist[qq * 16 + kk][n]);
  red[qq][n] = mx;
  __syncthreads();
  mx = fmaxf(fmaxf(red[0][n], red[1][n]), fmaxf(red[2][n], red[3][n]));
  __syncthreads();
  float sum = 0.f;
#pragma unroll
  for (int kk = 0; kk < 16; ++kk) {
    const float e = __expf(dist[qq * 16 + kk][n] - mx);
    dist[qq * 16 + kk][n] = e;
    sum += e;
  }
  red[qq][n] = sum;
  __syncthreads();
  sum = red[0][n] + red[1][n] + red[2][n] + red[3][n];
  const float inv = 1.f / sum;
  const size_t base = (size_t)b * NK * HW + n0 + n;
#pragma unroll
  for (int kk = 0; kk < 16; ++kk) {
    const float a = dist[qq * 16 + kk][n] * inv;
    const unsigned short hi = f2b(a);
    const float rem = a - b2f(hi);
    Ahi[base + (size_t)(qq * 16 + kk) * HW] = hi;
    Alo[base + (size_t)(qq * 16 + kk) * HW] = f2b(rem);
  }
}

// ---------------- asum from hi/lo planes ----------------
__global__ void asum_kernel(const unsigned short* __restrict__ Ahi,
                            const unsigned short* __restrict__ Alo, float* __restrict__ asum)
{
  const int bk = blockIdx.x;
  const unsigned short* __restrict__ rh = Ahi + (size_t)bk * HW;
  const unsigned short* __restrict__ rl = Alo + (size_t)bk * HW;
  const int t = threadIdx.x;
  float p = 0.f;
  for (int i = t * 8; i < HW; i += 2048) {
    s16x8 h, l;
    __builtin_memcpy(&h, rh + i, 16);
    __builtin_memcpy(&l, rl + i, 16);
#pragma unroll
    for (int e = 0; e < 8; ++e)
      p += b2f((unsigned short)h[e]) + b2f((unsigned short)l[e]);
  }
  __shared__ float sm[256];
  sm[t] = p;
  __syncthreads();
  for (int s = 128; s > 0; s >>= 1) {
    if (t < s) sm[t] += sm[t + s];
    __syncthreads();
  }
  if (t == 0) asum[bk] = sm[0];
}

// ---------------- enc via MFMA (R12-verified) ----------------
__global__ __launch_bounds__(256) void enc_mfma_kernel(
    const unsigned short* __restrict__ Ahi, const unsigned short* __restrict__ Alo,
    const unsigned short* __restrict__ Yv, float* __restrict__ pe)
{
  __shared__ __align__(16) unsigned short AHs[2048];
  __shared__ __align__(16) unsigned short ALs[2048];
  __shared__ __align__(16) unsigned short Bs[4096];
  const int tid = threadIdx.x;
  const int ncol = blockIdx.x, nc = blockIdx.y, b = blockIdx.z;
  const int lane = tid & 63, wv = tid >> 6;
  const int q = lane >> 4, mm = lane & 15;

  const int ko = tid & 3;
  const int r  = tid >> 2;
  const size_t aoff = ((size_t)b * NK + r) * HW + nc * 1024 + ko * 8;
  const unsigned short* ahS = Ahi + aoff;
  const unsigned short* alS = Alo + aoff;
  const int slotA = (((r >> 4) * 64) + ko * 16 + (r & 15)) * 8;
  const unsigned short* b0S = Yv + ((size_t)b * CCH + ncol * 128 + r) * HW + nc * 1024 + ko * 8;
  const unsigned short* b1S = b0S + (size_t)64 * HW;
  const int slotB0 = (((r >> 4) * 64) + ko * 16 + (r & 15)) * 8;
  const int slotB1 = ((((r + 64) >> 4) * 64) + ko * 16 + (r & 15)) * 8;

  f32x4 acc[4][2];
#pragma unroll
  for (int i = 0; i < 4; ++i)
#pragma unroll
    for (int j = 0; j < 2; ++j) acc[i][j] = (f32x4){0.f, 0.f, 0.f, 0.f};

  for (int kt = 0; kt < 1024; kt += 32) {
    s16x8 ah, al, y0, y1;
    __builtin_memcpy(&ah, ahS + kt, 16);
    __builtin_memcpy(&al, alS + kt, 16);
    __builtin_memcpy(&y0, b0S + kt, 16);
    __builtin_memcpy(&y1, b1S + kt, 16);
    __syncthreads();
    *(s16x8*)(AHs + slotA) = ah;
    *(s16x8*)(ALs + slotA) = al;
    *(s16x8*)(Bs + slotB0) = y0;
    *(s16x8*)(Bs + slotB1) = y1;
    __syncthreads();

    s16x8 afh[4], afl[4], bfr[2];
#pragma unroll
    for (int i = 0; i < 4; ++i) {
      afh[i] = *(const s16x8*)(AHs + (size_t)(i * 64 + lane) * 8);
      afl[i] = *(const s16x8*)(ALs + (size_t)(i * 64 + lane) * 8);
    }
#pragma unroll
    for (int j = 0; j < 2; ++j)
      bfr[j] = *(const s16x8*)(Bs + (size_t)((wv * 2 + j) * 64 + lane) * 8);
#pragma unroll
    for (int i = 0; i < 4; ++i)
#pragma unroll
      for (int j = 0; j < 2; ++j) {
        acc[i][j] = __builtin_amdgcn_mfma_f32_16x16x32_bf16(afh[i], bfr[j], acc[i][j], 0, 0, 0);
        acc[i][j] = __builtin_amdgcn_mfma_f32_16x16x32_bf16(afl[i], bfr[j], acc[i][j], 0, 0, 0);
      }
  }

  float* __restrict__ peb = pe + ((size_t)(b * 4 + nc) * NK) * CCH;
#pragma unroll
  for (int i = 0; i < 4; ++i)
#pragma unroll
    for (int j = 0; j < 2; ++j) {
      const int c = ncol * 128 + (wv * 2 + j) * 16 + mm;
#pragma unroll
      for (int rr = 0; rr < 4; ++rr) {
        const int k = i * 16 + q * 4 + rr;
        peb[(size_t)k * CCH + c] = acc[i][j][rr];
      }
    }
}

// ---------------- en + gate ----------------
__global__ __launch_bounds__(256) void engate_kernel(
    const float* __restrict__ pe, const float* __restrict__ asum, const float* __restrict__ cw,
    const float* __restrict__ misc, const float* __restrict__ wfc, const float* __restrict__ bfc,
    float* __restrict__ gam)
{
  const int b = blockIdx.x;
  const int t = threadIdx.x;
  __shared__ float asum_s[64], se_s[64], te_s[64];
  __shared__ __align__(16) float en_s[512];
  if (t < 64) {
    asum_s[t] = asum[b * 64 + t];
    se_s[t]   = misc[MS_SE + t];
    te_s[t]   = misc[MS_TE + t];
  }
  __syncthreads();
  for (int rep = 0; rep < 2; ++rep) {
    const int c = t + rep * 256;
    float en = 0.f;
    const float* __restrict__ peb = pe + (size_t)b * 4 * NK * CCH + c;
    for (int k = 0; k < 64; ++k) {
      const float ps = peb[(size_t)k * CCH] + peb[(size_t)(64 + k) * CCH] +
                       peb[(size_t)(128 + k) * CCH] + peb[(size_t)(192 + k) * CCH];
      float v = ps - asum_s[k] * cw[k * 512 + c];
      v = v * se_s[k] + te_s[k];
      en += fmaxf(v, 0.f);
    }
    en_s[c] = en * (1.f / 64.f);
  }
  __syncthreads();
  for (int rep = 0; rep < 2; ++rep) {
    const int i = t + rep * 256;
    float a = bfc[i];
    const float4* __restrict__ wrow = (const float4*)(wfc + (size_t)i * 512);
    const float4* __restrict__ ev = (const float4*)en_s;
    for (int j = 0; j < 128; ++j) {
      const float4 w4 = wrow[j];
      const float4 e4 = ev[j];
      a += w4.x * e4.x + w4.y * e4.y + w4.z * e4.z + w4.w * e4.w;
    }
    gam[b * 512 + i] = 1.f / (1.f + __expf(-a));
  }
}

// ---------------- fingate ----------------
__global__ __launch_bounds__(256) void fingate_kernel(
    const unsigned short* __restrict__ x1b, const float* __restrict__ gam,
    float* __restrict__ out)
{
  __shared__ float T[64][65];
  const int b = blockIdx.z, c0 = blockIdx.y * 64, n0 = blockIdx.x * 64;
  const int t = threadIdx.x;
  const int rr = t >> 4, cc = (t & 15) * 4;
#pragma unroll
  for (int rep = 0; rep < 4; ++rep) {
    const int pr = rep * 16 + rr;
    u16x4 v = *(const u16x4*)(x1b + ((size_t)(b * 4096 + n0 + pr)) * 512 + c0 + cc);
    T[cc + 0][pr] = b2f(v[0]);
    T[cc + 1][pr] = b2f(v[1]);
    T[cc + 2][pr] = b2f(v[2]);
    T[cc + 3][pr] = b2f(v[3]);
  }
  __syncthreads();
#pragma unroll
  for (int rep = 0; rep < 4; ++rep) {
    const int cr = rep * 16 + rr;
    const float g = 1.f + gam[b * 512 + c0 + cr];
    float4 o;
    o.x = fmaxf(T[cr][cc + 0] * g, 0.f);
    o.y = fmaxf(T[cr][cc + 1] * g, 0.f);
    o.z = fmaxf(T[cr][cc + 2] * g, 0.f);
    o.w = fmaxf(T[cr][cc + 3] * g, 0.f);
    *(float4*)(out + ((size_t)(b * 512 + c0 + cr)) * 4096 + n0 + cc) = o;
  }
}

extern "C" void kernel_launch(void* const* d_in, const int* in_sizes, int n_in,
                              void* d_out, int out_size, void* d_ws, size_t ws_size,
                              hipStream_t stream)
{
  const float* x  = (const float*)d_in[0];
  const float* w1 = (const float*)d_in[1];
  const float* g1 = (const float*)d_in[2];
  const float* b1 = (const float*)d_in[3];
  const float* m1 = (const float*)d_in[4];
  const float* v1 = (const float*)d_in[5];
  const float* w2 = (const float*)d_in[6];
  const float* g2 = (const float*)d_in[7];
  const float* b2 = (const float*)d_in[8];
  const float* m2 = (const float*)d_in[9];
  const float* v2 = (const float*)d_in[10];
  const float* w3 = (const float*)d_in[11];
  const float* g3 = (const float*)d_in[12];
  const float* b3 = (const float*)d_in[13];
  const float* m3 = (const float*)d_in[14];
  const float* v3 = (const float*)d_in[15];
  const float* wr = (const float*)d_in[16];
  const float* gr = (const float*)d_in[17];
  const float* br = (const float*)d_in[18];
  const float* mr = (const float*)d_in[19];
  const float* vr = (const float*)d_in[20];
  const float* wl = (const float*)d_in[21];
  const float* gl = (const float*)d_in[22];
  const float* bl = (const float*)d_in[23];
  const float* ml = (const float*)d_in[24];
  const float* vl = (const float*)d_in[25];
  const float* cw = (const float*)d_in[26];
  const float* scale = (const float*)d_in[27];
  const float* ge = (const float*)d_in[28];
  const float* be = (const float*)d_in[29];
  const float* me = (const float*)d_in[30];
  const float* ve = (const float*)d_in[31];
  const float* wfc = (const float*)d_in[32];
  const float* bfc = (const float*)d_in[33];

  char* wsb = (char*)d_ws;
  unsigned short* xb  = (unsigned short*)(wsb + C_XB);
  unsigned short* h2  = (unsigned short*)(wsb + C_H2);
  unsigned short* h1p = (unsigned short*)(wsb + C_H1P);
  unsigned short* x1b = (unsigned short*)(wsb + C_X1B);
  unsigned short* yb  = (unsigned short*)(wsb + C_YB);
  unsigned short* Ahi = (unsigned short*)(wsb + C_AHI);
  unsigned short* Alo = (unsigned short*)(wsb + C_ALO);
  float* pe   = (float*)(wsb + C_PE);
  float* asum = (float*)(wsb + C_ASUM);
  float* gam  = (float*)(wsb + C_GAM);
  float* misc = (float*)(wsb + C_MISC);
  unsigned short* w1f = (unsigned short*)(wsb + C_W1F);
  unsigned short* w2f = (unsigned short*)(wsb + C_W2F);
  unsigned short* w3b = (unsigned short*)(wsb + C_W3B);
  unsigned short* wrb = (unsigned short*)(wsb + C_WRB);
  unsigned short* wlb = (unsigned short*)(wsb + C_WLB);

  prep_kernel<<<1, 256, 0, stream>>>(g1, b1, m1, v1, g2, b2, m2, v2, g3, b3, m3, v3,
                                     gr, br, mr, vr, gl, bl, ml, vl, ge, be, me, ve,
                                     cw, misc);
  fold_bf16_kernel<<<256, 256, 0, stream>>>(w1, misc + MS_S1, w1f, 65536, 512);
  fold_w2_kernel<<<576, 256, 0, stream>>>(w2, misc + MS_S2, w2f);
  fold_bf16_kernel<<<256, 256, 0, stream>>>(w3, misc + MS_S3, w3b, 65536, 128);
  fold_bf16_kernel<<<1024, 256, 0, stream>>>(wr, misc + MS_SR, wrb, 262144, 512);
  fold_bf16_kernel<<<1024, 256, 0, stream>>>(wl, misc + MS_SL, wlb, 262144, 512);

  tr_kernel<<<dim3(64, 8, 16), 256, 0, stream>>>(x, xb);
  hipMemsetAsync(h1p, 0, 17842176, stream);

  mgemm_kernel<0, false><<<dim3(32, 1, 16), 256, 0, stream>>>(
      w1f, xb, 512, 4096LL * 512, nullptr, nullptr, 0, 0,
      nullptr, misc + MS_T1, 0, 1, 128, h1p, 4356LL * 128);
  mgemm_kernel<1, false><<<dim3(32, 1, 16), 256, 0, stream>>>(
      w2f, h1p, 1152, 4356LL * 128, nullptr, nullptr, 0, 0,
      nullptr, misc + MS_T2, 1, 1, 128, h2, 4096LL * 128);
  mgemm_kernel<0, true><<<dim3(32, 4, 16), 256, 0, stream>>>(
      w3b, h2, 128, 4096LL * 128, wrb, xb, 512, 4096LL * 512,
      misc + MS_T3, misc + MS_TR, 1, 0, 512, x1b, 4096LL * 512);
  mgemm_kernel<0, false><<<dim3(32, 4, 16), 256, 0, stream>>>(
      wlb, x1b, 512, 4096LL * 512, nullptr, nullptr, 0, 0,
      nullptr, misc + MS_TL, 3, 1, 0, yb, 512LL * 4096);

  assign_kernel<<<dim3(64, 16), 256, 0, stream>>>(yb, cw, scale, misc, Ahi, Alo);
  asum_kernel<<<1024, 256, 0, stream>>>(Ahi, Alo, asum);
  enc_mfma_kernel<<<dim3(4, 4, 16), 256, 0, stream>>>(Ahi, Alo, yb, pe);
  engate_kernel<<<16, 256, 0, stream>>>(pe, asum, cw, misc, wfc, bfc, gam);
  fingate_kernel<<<dim3(64, 8, 16), 256, 0, stream>>>(x1b, gam, (float*)d_out);
}

// Round 14
// 460.471 us; speedup vs baseline: 2.8775x; 1.0016x over previous
//
#include <hip/hip_runtime.h>
#include <math.h>

typedef float f32x4 __attribute__((ext_vector_type(4)));
typedef short s16x8 __attribute__((ext_vector_type(8)));
typedef unsigned short u16x4 __attribute__((ext_vector_type(4)));

#define HW 4096
#define CCH 512
#define NK 64
#define EPAD 136   // epilogue LDS row pitch (ushorts)

// ---- ws layout (BYTE offsets) — SIZE-AUDITED ----
#define C_XB   0ULL
#define C_H2   67108864ULL
#define C_H1P  83886080ULL
#define C_X1B  83886080ULL
#define C_YB   0ULL
#define C_AHI  67108864ULL
#define C_ALO  75497472ULL
#define C_ASUM 150994944ULL
#define C_GAM  150999040ULL
#define C_MISC 151031808ULL
#define C_W1F  151048192ULL
#define C_W2F  151179264ULL
#define C_W3B  151474176ULL
#define C_WRB  151605248ULL
#define C_WLB  152129536ULL
#define C_PE   152653824ULL    // -> end 161,042,432

#define MS_S1 0
#define MS_T1 128
#define MS_S2 256
#define MS_T2 384
#define MS_S3 512
#define MS_T3 1024
#define MS_SR 1536
#define MS_TR 2048
#define MS_SL 2560
#define MS_TL 3072
#define MS_SE 3584
#define MS_TE 3648
#define MS_CSQ 3712

__device__ __forceinline__ float b2f(unsigned short u) {
  unsigned int x = ((unsigned int)u) << 16;
  return __builtin_bit_cast(float, x);
}
__device__ __forceinline__ unsigned short f2b(float f) {
  unsigned int i = __builtin_bit_cast(unsigned int, f);
  i += 0x7fffu + ((i >> 16) & 1u);
  return (unsigned short)(i >> 16);
}

// ---------------- prep ----------------
__global__ void prep_kernel(
    const float* __restrict__ g1, const float* __restrict__ b1, const float* __restrict__ m1, const float* __restrict__ v1,
    const float* __restrict__ g2, const float* __restrict__ b2, const float* __restrict__ m2, const float* __restrict__ v2,
    const float* __restrict__ g3, const float* __restrict__ b3, const float* __restrict__ m3, const float* __restrict__ v3,
    const float* __restrict__ gr, const float* __restrict__ br, const float* __restrict__ mr, const float* __restrict__ vr,
    const float* __restrict__ gl, const float* __restrict__ bl, const float* __restrict__ ml, const float* __restrict__ vl,
    const float* __restrict__ ge, const float* __restrict__ be, const float* __restrict__ me, const float* __restrict__ ve,
    const float* __restrict__ cw, float* __restrict__ misc)
{
  const int t = threadIdx.x;
  if (t < 128) {
    float s = g1[t] * rsqrtf(v1[t] + 1e-6f);
    misc[MS_S1 + t] = s; misc[MS_T1 + t] = b1[t] - m1[t] * s;
    s = g2[t] * rsqrtf(v2[t] + 1e-6f);
    misc[MS_S2 + t] = s; misc[MS_T2 + t] = b2[t] - m2[t] * s;
  }
  for (int c = t; c < 512; c += 256) {
    float s = g3[c] * rsqrtf(v3[c] + 1e-6f);
    misc[MS_S3 + c] = s; misc[MS_T3 + c] = b3[c] - m3[c] * s;
    s = gr[c] * rsqrtf(vr[c] + 1e-6f);
    misc[MS_SR + c] = s; misc[MS_TR + c] = br[c] - mr[c] * s;
    s = gl[c] * rsqrtf(vl[c] + 1e-5f);
    misc[MS_SL + c] = s; misc[MS_TL + c] = bl[c] - ml[c] * s;
  }
  if (t < 64) {
    float s = ge[t] * rsqrtf(ve[t] + 1e-5f);
    misc[MS_SE + t] = s; misc[MS_TE + t] = be[t] - me[t] * s;
    float acc = 0.f;
    for (int c = 0; c < 512; ++c) { float v = cw[t * 512 + c]; acc += v * v; }
    misc[MS_CSQ + t] = acc;
  }
}

// ---------------- fold weights -> bf16 ----------------
__global__ void fold_bf16_kernel(const float* __restrict__ w, const float* __restrict__ s,
                                 unsigned short* __restrict__ out, int total, int kper)
{
  int i = blockIdx.x * 256 + threadIdx.x;
  if (i < total) out[i] = f2b(w[i] * s[i / kper]);
}

__global__ void fold_w2_kernel(const float* __restrict__ w2, const float* __restrict__ s,
                               unsigned short* __restrict__ out)
{
  int j = blockIdx.x * 256 + threadIdx.x;
  if (j < 147456) {
    int m = j / 1152, r = j - m * 1152;
    int tp = r >> 7, ci = r & 127;
    out[j] = f2b(w2[m * 1152 + ci * 9 + tp] * s[m]);
  }
}

// ---------------- f32 NCHW (512 ch) -> bf16 NHWC ----------------
__global__ __launch_bounds__(256) void tr_kernel(const float* __restrict__ x,
                                                 unsigned short* __restrict__ xb)
{
  __shared__ float T[64][65];
  const int b = blockIdx.z, c0 = blockIdx.y * 64, n0 = blockIdx.x * 64;
  const int t = threadIdx.x;
  const int rr = t >> 4, cc = (t & 15) * 4;
#pragma unroll
  for (int rep = 0; rep < 4; ++rep) {
    const int cr = rep * 16 + rr;
    const float4 v = *(const float4*)(x + ((size_t)(b * 512 + c0 + cr)) * 4096 + n0 + cc);
    T[cr][cc + 0] = v.x; T[cr][cc + 1] = v.y; T[cr][cc + 2] = v.z; T[cr][cc + 3] = v.w;
  }
  __syncthreads();
#pragma unroll
  for (int rep = 0; rep < 4; ++rep) {
    const int nr = rep * 16 + rr;
    u16x4 o;
    o[0] = f2b(T[cc + 0][nr]); o[1] = f2b(T[cc + 1][nr]);
    o[2] = f2b(T[cc + 2][nr]); o[3] = f2b(T[cc + 3][nr]);
    *(u16x4*)(xb + ((size_t)(b * 4096 + n0 + nr)) * 512 + c0 + cc) = o;
  }
}

// ======== MFMA GEMM v4: double-buffered LDS + depth-2 register prefetch ========
// Fragment-slot contract (R11-verified): slot s (16B) holds T[row=(s>>6)*16+(s&15)][k=((s>>4)&3)*8..+8].
// Per chunk c: loads for c+2 issued | MFMA chunk c | ds_write chunk c+1 (loaded a full
// step earlier -> vmcnt slack = one MFMA block + barrier) | one barrier.

__device__ __forceinline__ void mfma_step(const unsigned short* __restrict__ Ac,
                                          const unsigned short* __restrict__ Bc,
                                          int lane, int wm, int wn, f32x4 acc[4][4])
{
  s16x8 afr[4], bfr[4];
#pragma unroll
  for (int i = 0; i < 4; ++i)
    afr[i] = *(const s16x8*)(Ac + (size_t)((wm * 4 + i) * 64 + lane) * 8);
#pragma unroll
  for (int j = 0; j < 4; ++j)
    bfr[j] = *(const s16x8*)(Bc + (size_t)((wn * 4 + j) * 64 + lane) * 8);
#pragma unroll
  for (int i = 0; i < 4; ++i)
#pragma unroll
    for (int j = 0; j < 4; ++j)
      acc[i][j] = __builtin_amdgcn_mfma_f32_16x16x32_bf16(afr[i], bfr[j], acc[i][j], 0, 0, 0);
}

template<int BMODE>
__device__ __forceinline__ void run_phase(
    const unsigned short* __restrict__ Wp,
    const unsigned short* __restrict__ Xb,
    const int K, const int tid, const int n0,
    unsigned short* __restrict__ As, unsigned short* __restrict__ Bs,
    f32x4 acc[4][4])
{
  const int lane = tid & 63;
  const int wv = tid >> 6, wm = wv >> 1, wn = wv & 1;

  const int ko = tid & 3;
  const int r0 = tid >> 2;
  const int r1 = 64 + r0;

  const unsigned short* aS0 = Wp + (size_t)r0 * K + ko * 8;
  const unsigned short* aS1 = Wp + (size_t)r1 * K + ko * 8;
  const int slot0 = (((r0 >> 4) * 64) + ko * 16 + (r0 & 15)) * 8;
  const int slot1 = (((r1 >> 4) * 64) + ko * 16 + (r1 & 15)) * 8;

  const unsigned short* bS0 = nullptr;
  const unsigned short* bS1 = nullptr;
  size_t bBase0 = 0, bBase1 = 0;
  if constexpr (BMODE == 0) {
    bS0 = Xb + (size_t)(n0 + r0) * K + ko * 8;
    bS1 = Xb + (size_t)(n0 + r1) * K + ko * 8;
  } else {
    const int pg0 = n0 + r0, pg1 = n0 + r1;
    bBase0 = (size_t)((pg0 >> 6) * 66 + (pg0 & 63)) * 128 + ko * 8;
    bBase1 = (size_t)((pg1 >> 6) * 66 + (pg1 & 63)) * 128 + ko * 8;
  }

#define LOADC(kt, A0, A1, B0, B1)                                  \
  {                                                                \
    __builtin_memcpy(&A0, aS0 + (kt), 16);                         \
    __builtin_memcpy(&A1, aS1 + (kt), 16);                         \
    if constexpr (BMODE == 0) {                                    \
      __builtin_memcpy(&B0, bS0 + (kt), 16);                       \
      __builtin_memcpy(&B1, bS1 + (kt), 16);                       \
    } else {                                                       \
      const int tap_ = (kt) >> 7;                                  \
      const int ky_ = tap_ / 3, kx_ = tap_ - ky_ * 3;              \
      const int off_ = (ky_ * 66 + kx_) * 128 + ((kt) & 127);      \
      __builtin_memcpy(&B0, Xb + bBase0 + off_, 16);               \
      __builtin_memcpy(&B1, Xb + bBase1 + off_, 16);               \
    }                                                              \
  }
#define WRITEC(bo, A0, A1, B0, B1)                                 \
  {                                                                \
    *(s16x8*)(As + (bo) + slot0) = A0;                             \
    *(s16x8*)(As + (bo) + slot1) = A1;                             \
    *(s16x8*)(Bs + (bo) + slot0) = B0;                             \
    *(s16x8*)(Bs + (bo) + slot1) = B1;                             \
  }

  s16x8 pA0, pA1, pB0, pB1;   // set p (even chunks)
  s16x8 qA0, qA1, qB0, qB1;   // set q (odd chunks)

  LOADC(0, pA0, pA1, pB0, pB1);
  LOADC(32, qA0, qA1, qB0, qB1);
  WRITEC(0, pA0, pA1, pB0, pB1);
  __syncthreads();

  // NC = K/32 is even for all uses (K in {128, 512, 1152})
  for (int kt = 0; kt < K; kt += 64) {
    if (kt + 64 < K) LOADC(kt + 64, pA0, pA1, pB0, pB1);
    mfma_step(As, Bs, lane, wm, wn, acc);
    WRITEC(4096, qA0, qA1, qB0, qB1);
    __syncthreads();

    if (kt + 96 < K) LOADC(kt + 96, qA0, qA1, qB0, qB1);
    mfma_step(As + 4096, Bs + 4096, lane, wm, wn, acc);
    if (kt + 64 < K) WRITEC(0, pA0, pA1, pB0, pB1);
    __syncthreads();
  }
#undef LOADC
#undef WRITEC
}

template<int BMODE, bool DUAL>
__global__ __launch_bounds__(256) void mgemm_kernel(
    const unsigned short* __restrict__ W0, const unsigned short* __restrict__ X0,
    const int K0, const long long xbs0,
    const unsigned short* __restrict__ W1, const unsigned short* __restrict__ X1,
    const int Kp1, const long long xbs1,
    const float* __restrict__ biasMid, const float* __restrict__ biasOut,
    const int omode, const int reluF, const int ldm,
    unsigned short* __restrict__ outB, const long long obsB)
{
  __shared__ __align__(16) unsigned short smem[128 * EPAD];  // 34,816B; staging = first 32KB
  unsigned short* As = smem;          // 2 x 4096 shorts
  unsigned short* Bs = smem + 8192;   // 2 x 4096 shorts

  const int tid = threadIdx.x;
  const int b = blockIdx.z;
  const int n0 = blockIdx.x * 128;
  const int m0 = blockIdx.y * 128;
  const int lane = tid & 63, wv = tid >> 6, wm = wv >> 1, wn = wv & 1;
  const int q = lane >> 4, mm = lane & 15;

  f32x4 acc[4][4];
#pragma unroll
  for (int i = 0; i < 4; ++i)
#pragma unroll
    for (int j = 0; j < 4; ++j) acc[i][j] = (f32x4){0.f, 0.f, 0.f, 0.f};

  run_phase<BMODE>(W0 + (size_t)m0 * K0, X0 + (size_t)b * xbs0, K0, tid, n0, As, Bs, acc);

  if constexpr (DUAL) {
#pragma unroll
    for (int i = 0; i < 4; ++i) {
      const int mb = m0 + wm * 64 + i * 16 + q * 4;
#pragma unroll
      for (int r = 0; r < 4; ++r) {
        const float bm = biasMid[mb + r];
#pragma unroll
        for (int j = 0; j < 4; ++j) acc[i][j][r] = fmaxf(acc[i][j][r] + bm, 0.f);
      }
    }
    run_phase<0>(W1 + (size_t)m0 * Kp1, X1 + (size_t)b * xbs1, Kp1, tid, n0, As, Bs, acc);
  }

  __syncthreads();
  if (omode == 3) {
#pragma unroll
    for (int i = 0; i < 4; ++i) {
      const int chb = wm * 64 + i * 16 + q * 4;
#pragma unroll
      for (int r = 0; r < 4; ++r) {
        const float bo = biasOut[m0 + chb + r];
#pragma unroll
        for (int j = 0; j < 4; ++j) {
          const int px = wn * 64 + j * 16 + mm;
          float v = acc[i][j][r] + bo;
          if (reluF) v = fmaxf(v, 0.f);
          smem[(size_t)(chb + r) * EPAD + px] = f2b(v);
        }
      }
    }
    __syncthreads();
    const int ch = tid >> 1, half = tid & 1;
    const unsigned short* src = smem + (size_t)ch * EPAD + half * 64;
    unsigned short* dst = outB + (size_t)b * obsB + (size_t)(m0 + ch) * HW + n0 + half * 64;
#pragma unroll
    for (int r = 0; r < 8; ++r) {
      s16x8 v;
      __builtin_memcpy(&v, src + r * 8, 16);
      *(s16x8*)(dst + r * 8) = v;
    }
  } else {
#pragma unroll
    for (int i = 0; i < 4; ++i) {
      const int chb = wm * 64 + i * 16 + q * 4;
      float bo[4];
#pragma unroll
      for (int r = 0; r < 4; ++r) bo[r] = biasOut[m0 + chb + r];
#pragma unroll
      for (int j = 0; j < 4; ++j) {
        const int px = wn * 64 + j * 16 + mm;
        u16x4 o;
#pragma unroll
        for (int r = 0; r < 4; ++r) {
          float v = acc[i][j][r] + bo[r];
          if (reluF) v = fmaxf(v, 0.f);
          o[r] = f2b(v);
        }
        *(u16x4*)(smem + (size_t)px * EPAD + chb) = o;
      }
    }
    __syncthreads();
    const int px = tid >> 1, half = tid & 1;
    const unsigned short* src = smem + (size_t)px * EPAD + half * 64;
    size_t dstoff;
    if (omode == 1) {
      dstoff = (size_t)b * obsB + (size_t)(n0 + px) * ldm + m0 + half * 64;
    } else {
      const int hp = ((n0 + px) >> 6) + 1, wp = ((n0 + px) & 63) + 1;
      dstoff = (size_t)b * obsB + ((size_t)hp * 66 + wp) * 128 + m0 + half * 64;
    }
    unsigned short* dst = outB + dstoff;
#pragma unroll
    for (int r = 0; r < 8; ++r) {
      s16x8 v;
      __builtin_memcpy(&v, src + r * 8, 16);
      *(s16x8*)(dst + r * 8) = v;
    }
  }
}

// ---------------- assignment -> A as bf16 hi/lo planes ----------------
__global__ __launch_bounds__(256) void assign_kernel(
    const unsigned short* __restrict__ Yv, const float* __restrict__ cw, const float* __restrict__ scale,
    const float* __restrict__ misc, unsigned short* __restrict__ Ahi, unsigned short* __restrict__ Alo)
{
  __shared__ float Cs[16][64];
  __shared__ float Ys[16][64];
  __shared__ float dist[64][65];
  __shared__ float red[4][64];
  __shared__ float xsq[64];
  __shared__ float scl[64];
  __shared__ float csq[64];
  const int tid = threadIdx.x;
  const int b  = blockIdx.y;
  const int n0 = blockIdx.x * 64;
  if (tid < 64) { scl[tid] = scale[tid]; csq[tid] = misc[MS_CSQ + tid]; }
  const unsigned short* __restrict__ Yb = Yv + (size_t)b * CCH * HW;
  const int tr = tid >> 4, tc = tid & 15;
  const int lc_k = tid >> 2, lc_c = (tid & 3) * 4;
  const int ly_c0 = tid >> 6, ly_n = tid & 63;

  float acc[4][4];
#pragma unroll
  for (int i = 0; i < 4; ++i)
#pragma unroll
    for (int j = 0; j < 4; ++j) acc[i][j] = 0.f;
  float sq = 0.f;

  for (int c0 = 0; c0 < 512; c0 += 16) {
    const float4 cv = *(const float4*)(cw + (size_t)lc_k * 512 + c0 + lc_c);
    float yv[4];
#pragma unroll
    for (int rr = 0; rr < 4; ++rr)
      yv[rr] = b2f(Yb[(size_t)(c0 + ly_c0 + rr * 4) * HW + n0 + ly_n]);
    __syncthreads();
    Cs[lc_c + 0][lc_k] = cv.x;
    Cs[lc_c + 1][lc_k] = cv.y;
    Cs[lc_c + 2][lc_k] = cv.z;
    Cs[lc_c + 3][lc_k] = cv.w;
#pragma unroll
    for (int rr = 0; rr < 4; ++rr) {
      Ys[ly_c0 + rr * 4][ly_n] = yv[rr];
      sq += yv[rr] * yv[rr];
    }
    __syncthreads();
#pragma unroll
    for (int ct = 0; ct < 16; ++ct) {
      float rk[4], rn[4];
#pragma unroll
      for (int i = 0; i < 4; ++i) rk[i] = Cs[ct][tr * 4 + i];
#pragma unroll
      for (int j = 0; j < 4; ++j) rn[j] = Ys[ct][tc * 4 + j];
#pragma unroll
      for (int i = 0; i < 4; ++i)
#pragma unroll
        for (int j = 0; j < 4; ++j) acc[i][j] += rk[i] * rn[j];
    }
  }
  __syncthreads();
  red[ly_c0][ly_n] = sq;
  __syncthreads();
  if (tid < 64) xsq[tid] = red[0][tid] + red[1][tid] + red[2][tid] + red[3][tid];
  __syncthreads();
#pragma unroll
  for (int i = 0; i < 4; ++i)
#pragma unroll
    for (int j = 0; j < 4; ++j) {
      const int k = tr * 4 + i, n = tc * 4 + j;
      dist[k][n] = scl[k] * (xsq[n] - 2.f * acc[i][j] + csq[k]);
    }
  __syncthreads();
  const int qq = tid >> 6, n = tid & 63;
  float mx = -3.0e38f;
#pragma unroll
  for (int kk = 0; kk < 16; ++kk) mx = fmaxf(mx, dist[qq * 16 + kk][n]);
  red[qq][n] = mx;
  __syncthreads();
  mx = fmaxf(fmaxf(red[0][n], red[1][n]), fmaxf(red[2][n], red[3][n]));
  __syncthreads();
  float sum = 0.f;
#pragma unroll
  for (int kk = 0; kk < 16; ++kk) {
    const float e = __expf(dist[qq * 16 + kk][n] - mx);
    dist[qq * 16 + kk][n] = e;
    sum += e;
  }
  red[qq][n] = sum;
  __syncthreads();
  sum = red[0][n] + red[1][n] + red[2][n] + red[3][n];
  const float inv = 1.f / sum;
  const size_t base = (size_t)b * NK * HW + n0 + n;
#pragma unroll
  for (int kk = 0; kk < 16; ++kk) {
    const float a = dist[qq * 16 + kk][n] * inv;
    const unsigned short hi = f2b(a);
    const float rem = a - b2f(hi);
    Ahi[base + (size_t)(qq * 16 + kk) * HW] = hi;
    Alo[base + (size_t)(qq * 16 + kk) * HW] = f2b(rem);
  }
}

// ---------------- asum from hi/lo planes ----------------
__global__ void asum_kernel(const unsigned short* __restrict__ Ahi,
                            const unsigned short* __restrict__ Alo, float* __restrict__ asum)
{
  const int bk = blockIdx.x;
  const unsigned short* __restrict__ rh = Ahi + (size_t)bk * HW;
  const unsigned short* __restrict__ rl = Alo + (size_t)bk * HW;
  const int t = threadIdx.x;
  float p = 0.f;
  for (int i = t * 8; i < HW; i += 2048) {
    s16x8 h, l;
    __builtin_memcpy(&h, rh + i, 16);
    __builtin_memcpy(&l, rl + i, 16);
#pragma unroll
    for (int e = 0; e < 8; ++e)
      p += b2f((unsigned short)h[e]) + b2f((unsigned short)l[e]);
  }
  __shared__ float sm[256];
  sm[t] = p;
  __syncthreads();
  for (int s = 128; s > 0; s >>= 1) {
    if (t < s) sm[t] += sm[t + s];
    __syncthreads();
  }
  if (t == 0) asum[bk] = sm[0];
}

// ---------------- enc via MFMA (R12-verified) ----------------
__global__ __launch_bounds__(256) void enc_mfma_kernel(
    const unsigned short* __restrict__ Ahi, const unsigned short* __restrict__ Alo,
    const unsigned short* __restrict__ Yv, float* __restrict__ pe)
{
  __shared__ __align__(16) unsigned short AHs[2048];
  __shared__ __align__(16) unsigned short ALs[2048];
  __shared__ __align__(16) unsigned short Bs[4096];
  const int tid = threadIdx.x;
  const int ncol = blockIdx.x, nc = blockIdx.y, b = blockIdx.z;
  const int lane = tid & 63, wv = tid >> 6;
  const int q = lane >> 4, mm = lane & 15;

  const int ko = tid & 3;
  const int r  = tid >> 2;
  const size_t aoff = ((size_t)b * NK + r) * HW + nc * 1024 + ko * 8;
  const unsigned short* ahS = Ahi + aoff;
  const unsigned short* alS = Alo + aoff;
  const int slotA = (((r >> 4) * 64) + ko * 16 + (r & 15)) * 8;
  const unsigned short* b0S = Yv + ((size_t)b * CCH + ncol * 128 + r) * HW + nc * 1024 + ko * 8;
  const unsigned short* b1S = b0S + (size_t)64 * HW;
  const int slotB0 = (((r >> 4) * 64) + ko * 16 + (r & 15)) * 8;
  const int slotB1 = ((((r + 64) >> 4) * 64) + ko * 16 + (r & 15)) * 8;

  f32x4 acc[4][2];
#pragma unroll
  for (int i = 0; i < 4; ++i)
#pragma unroll
    for (int j = 0; j < 2; ++j) acc[i][j] = (f32x4){0.f, 0.f, 0.f, 0.f};

  for (int kt = 0; kt < 1024; kt += 32) {
    s16x8 ah, al, y0, y1;
    __builtin_memcpy(&ah, ahS + kt, 16);
    __builtin_memcpy(&al, alS + kt, 16);
    __builtin_memcpy(&y0, b0S + kt, 16);
    __builtin_memcpy(&y1, b1S + kt, 16);
    __syncthreads();
    *(s16x8*)(AHs + slotA) = ah;
    *(s16x8*)(ALs + slotA) = al;
    *(s16x8*)(Bs + slotB0) = y0;
    *(s16x8*)(Bs + slotB1) = y1;
    __syncthreads();

    s16x8 afh[4], afl[4], bfr[2];
#pragma unroll
    for (int i = 0; i < 4; ++i) {
      afh[i] = *(const s16x8*)(AHs + (size_t)(i * 64 + lane) * 8);
      afl[i] = *(const s16x8*)(ALs + (size_t)(i * 64 + lane) * 8);
    }
#pragma unroll
    for (int j = 0; j < 2; ++j)
      bfr[j] = *(const s16x8*)(Bs + (size_t)((wv * 2 + j) * 64 + lane) * 8);
#pragma unroll
    for (int i = 0; i < 4; ++i)
#pragma unroll
      for (int j = 0; j < 2; ++j) {
        acc[i][j] = __builtin_amdgcn_mfma_f32_16x16x32_bf16(afh[i], bfr[j], acc[i][j], 0, 0, 0);
        acc[i][j] = __builtin_amdgcn_mfma_f32_16x16x32_bf16(afl[i], bfr[j], acc[i][j], 0, 0, 0);
      }
  }

  float* __restrict__ peb = pe + ((size_t)(b * 4 + nc) * NK) * CCH;
#pragma unroll
  for (int i = 0; i < 4; ++i)
#pragma unroll
    for (int j = 0; j < 2; ++j) {
      const int c = ncol * 128 + (wv * 2 + j) * 16 + mm;
#pragma unroll
      for (int rr = 0; rr < 4; ++rr) {
        const int k = i * 16 + q * 4 + rr;
        peb[(size_t)k * CCH + c] = acc[i][j][rr];
      }
    }
}

// ---------------- en + gate ----------------
__global__ __launch_bounds__(256) void engate_kernel(
    const float* __restrict__ pe, const float* __restrict__ asum, const float* __restrict__ cw,
    const float* __restrict__ misc, const float* __restrict__ wfc, const float* __restrict__ bfc,
    float* __restrict__ gam)
{
  const int b = blockIdx.x;
  const int t = threadIdx.x;
  __shared__ float asum_s[64], se_s[64], te_s[64];
  __shared__ __align__(16) float en_s[512];
  if (t < 64) {
    asum_s[t] = asum[b * 64 + t];
    se_s[t]   = misc[MS_SE + t];
    te_s[t]   = misc[MS_TE + t];
  }
  __syncthreads();
  for (int rep = 0; rep < 2; ++rep) {
    const int c = t + rep * 256;
    float en = 0.f;
    const float* __restrict__ peb = pe + (size_t)b * 4 * NK * CCH + c;
    for (int k = 0; k < 64; ++k) {
      const float ps = peb[(size_t)k * CCH] + peb[(size_t)(64 + k) * CCH] +
                       peb[(size_t)(128 + k) * CCH] + peb[(size_t)(192 + k) * CCH];
      float v = ps - asum_s[k] * cw[k * 512 + c];
      v = v * se_s[k] + te_s[k];
      en += fmaxf(v, 0.f);
    }
    en_s[c] = en * (1.f / 64.f);
  }
  __syncthreads();
  for (int rep = 0; rep < 2; ++rep) {
    const int i = t + rep * 256;
    float a = bfc[i];
    const float4* __restrict__ wrow = (const float4*)(wfc + (size_t)i * 512);
    const float4* __restrict__ ev = (const float4*)en_s;
    for (int j = 0; j < 128; ++j) {
      const float4 w4 = wrow[j];
      const float4 e4 = ev[j];
      a += w4.x * e4.x + w4.y * e4.y + w4.z * e4.z + w4.w * e4.w;
    }
    gam[b * 512 + i] = 1.f / (1.f + __expf(-a));
  }
}

// ---------------- fingate ----------------
__global__ __launch_bounds__(256) void fingate_kernel(
    const unsigned short* __restrict__ x1b, const float* __restrict__ gam,
    float* __restrict__ out)
{
  __shared__ float T[64][65];
  const int b = blockIdx.z, c0 = blockIdx.y * 64, n0 = blockIdx.x * 64;
  const int t = threadIdx.x;
  const int rr = t >> 4, cc = (t & 15) * 4;
#pragma unroll
  for (int rep = 0; rep < 4; ++rep) {
    const int pr = rep * 16 + rr;
    u16x4 v = *(const u16x4*)(x1b + ((size_t)(b * 4096 + n0 + pr)) * 512 + c0 + cc);
    T[cc + 0][pr] = b2f(v[0]);
    T[cc + 1][pr] = b2f(v[1]);
    T[cc + 2][pr] = b2f(v[2]);
    T[cc + 3][pr] = b2f(v[3]);
  }
  __syncthreads();
#pragma unroll
  for (int rep = 0; rep < 4; ++rep) {
    const int cr = rep * 16 + rr;
    const float g = 1.f + gam[b * 512 + c0 + cr];
    float4 o;
    o.x = fmaxf(T[cr][cc + 0] * g, 0.f);
    o.y = fmaxf(T[cr][cc + 1] * g, 0.f);
    o.z = fmaxf(T[cr][cc + 2] * g, 0.f);
    o.w = fmaxf(T[cr][cc + 3] * g, 0.f);
    *(float4*)(out + ((size_t)(b * 512 + c0 + cr)) * 4096 + n0 + cc) = o;
  }
}

extern "C" void kernel_launch(void* const* d_in, const int* in_sizes, int n_in,
                              void* d_out, int out_size, void* d_ws, size_t ws_size,
                              hipStream_t stream)
{
  const float* x  = (const float*)d_in[0];
  const float* w1 = (const float*)d_in[1];
  const float* g1 = (const float*)d_in[2];
  const float* b1 = (const float*)d_in[3];
  const float* m1 = (const float*)d_in[4];
  const float* v1 = (const float*)d_in[5];
  const float* w2 = (const float*)d_in[6];
  const float* g2 = (const float*)d_in[7];
  const float* b2 = (const float*)d_in[8];
  const float* m2 = (const float*)d_in[9];
  const float* v2 = (const float*)d_in[10];
  const float* w3 = (const float*)d_in[11];
  const float* g3 = (const float*)d_in[12];
  const float* b3 = (const float*)d_in[13];
  const float* m3 = (const float*)d_in[14];
  const float* v3 = (const float*)d_in[15];
  const float* wr = (const float*)d_in[16];
  const float* gr = (const float*)d_in[17];
  const float* br = (const float*)d_in[18];
  const float* mr = (const float*)d_in[19];
  const float* vr = (const float*)d_in[20];
  const float* wl = (const float*)d_in[21];
  const float* gl = (const float*)d_in[22];
  const float* bl = (const float*)d_in[23];
  const float* ml = (const float*)d_in[24];
  const float* vl = (const float*)d_in[25];
  const float* cw = (const float*)d_in[26];
  const float* scale = (const float*)d_in[27];
  const float* ge = (const float*)d_in[28];
  const float* be = (const float*)d_in[29];
  const float* me = (const float*)d_in[30];
  const float* ve = (const float*)d_in[31];
  const float* wfc = (const float*)d_in[32];
  const float* bfc = (const float*)d_in[33];

  char* wsb = (char*)d_ws;
  unsigned short* xb  = (unsigned short*)(wsb + C_XB);
  unsigned short* h2  = (unsigned short*)(wsb + C_H2);
  unsigned short* h1p = (unsigned short*)(wsb + C_H1P);
  unsigned short* x1b = (unsigned short*)(wsb + C_X1B);
  unsigned short* yb  = (unsigned short*)(wsb + C_YB);
  unsigned short* Ahi = (unsigned short*)(wsb + C_AHI);
  unsigned short* Alo = (unsigned short*)(wsb + C_ALO);
  float* pe   = (float*)(wsb + C_PE);
  float* asum = (float*)(wsb + C_ASUM);
  float* gam  = (float*)(wsb + C_GAM);
  float* misc = (float*)(wsb + C_MISC);
  unsigned short* w1f = (unsigned short*)(wsb + C_W1F);
  unsigned short* w2f = (unsigned short*)(wsb + C_W2F);
  unsigned short* w3b = (unsigned short*)(wsb + C_W3B);
  unsigned short* wrb = (unsigned short*)(wsb + C_WRB);
  unsigned short* wlb = (unsigned short*)(wsb + C_WLB);

  prep_kernel<<<1, 256, 0, stream>>>(g1, b1, m1, v1, g2, b2, m2, v2, g3, b3, m3, v3,
                                     gr, br, mr, vr, gl, bl, ml, vl, ge, be, me, ve,
                                     cw, misc);
  fold_bf16_kernel<<<256, 256, 0, stream>>>(w1, misc + MS_S1, w1f, 65536, 512);
  fold_w2_kernel<<<576, 256, 0, stream>>>(w2, misc + MS_S2, w2f);
  fold_bf16_kernel<<<256, 256, 0, stream>>>(w3, misc + MS_S3, w3b, 65536, 128);
  fold_bf16_kernel<<<1024, 256, 0, stream>>>(wr, misc + MS_SR, wrb, 262144, 512);
  fold_bf16_kernel<<<1024, 256, 0, stream>>>(wl, misc + MS_SL, wlb, 262144, 512);

  tr_kernel<<<dim3(64, 8, 16), 256, 0, stream>>>(x, xb);
  hipMemsetAsync(h1p, 0, 17842176, stream);

  mgemm_kernel<0, false><<<dim3(32, 1, 16), 256, 0, stream>>>(
      w1f, xb, 512, 4096LL * 512, nullptr, nullptr, 0, 0,
      nullptr, misc + MS_T1, 0, 1, 128, h1p, 4356LL * 128);
  mgemm_kernel<1, false><<<dim3(32, 1, 16), 256, 0, stream>>>(
      w2f, h1p, 1152, 4356LL * 128, nullptr, nullptr, 0, 0,
      nullptr, misc + MS_T2, 1, 1, 128, h2, 4096LL * 128);
  mgemm_kernel<0, true><<<dim3(32, 4, 16), 256, 0, stream>>>(
      w3b, h2, 128, 4096LL * 128, wrb, xb, 512, 4096LL * 512,
      misc + MS_T3, misc + MS_TR, 1, 0, 512, x1b, 4096LL * 512);
  mgemm_kernel<0, false><<<dim3(32, 4, 16), 256, 0, stream>>>(
      wlb, x1b, 512, 4096LL * 512, nullptr, nullptr, 0, 0,
      nullptr, misc + MS_TL, 3, 1, 0, yb, 512LL * 4096);

  assign_kernel<<<dim3(64, 16), 256, 0, stream>>>(yb, cw, scale, misc, Ahi, Alo);
  asum_kernel<<<1024, 256, 0, stream>>>(Ahi, Alo, asum);
  enc_mfma_kernel<<<dim3(4, 4, 16), 256, 0, stream>>>(Ahi, Alo, yb, pe);
  engate_kernel<<<16, 256, 0, stream>>>(pe, asum, cw, misc, wfc, bfc, gam);
  fingate_kernel<<<dim3(64, 8, 16), 256, 0, stream>>>(x1b, gam, (float*)d_out);
}